// Round 9
// baseline (4454.844 us; speedup 1.0000x reference)
//
#include <hip/hip_runtime.h>
#include <cstdint>
#include <cstddef>

// ---------------- static problem config ----------------
#define NN      10000   // nodes
#define NE      120000  // edges
#define NG      32      // graphs
#define FNODE   64
#define FEDGE   16
#define HID     128
#define NHEADS  4
#define NL      3
#define NR      4
#define IDDIM   32
#define RELDIM  8
#define FFNH    256
#define HEADH   128
#define NCLS    10

#define NCHUNK  128     // pooling stage-1 blocks

typedef __attribute__((ext_vector_type(8))) short short8;
typedef __attribute__((ext_vector_type(4))) float floatx4;

// ---------------- helpers ----------------
__device__ __forceinline__ float silu_f(float x) { return x / (1.f + expf(-x)); }
__device__ __forceinline__ ushort f2bf(float f) {   // round-to-nearest-even bf16
  unsigned u = __float_as_uint(f);
  return (ushort)((u + 0x7FFFu + ((u >> 16) & 1u)) >> 16);
}
__device__ __forceinline__ float bf2f(ushort h) { return __uint_as_float((unsigned)h << 16); }

// Cox–de Boor cubic bases on grid t_j = (j-3)*0.4 - 1 (GRID_SIZE=5, ORDER=3) -> 8 bases
__device__ __forceinline__ void kan_bases(float x, float* out8) {
  float bb[11];
#pragma unroll
  for (int j = 0; j < 11; ++j) {
    float t0 = (j - 3) * 0.4f - 1.f;
    float t1 = (j - 2) * 0.4f - 1.f;
    bb[j] = (x >= t0 && x < t1) ? 1.f : 0.f;
  }
  {
    const float inv = 1.f / 0.4f;
#pragma unroll
    for (int j = 0; j < 10; ++j) {
      float tj = (j - 3) * 0.4f - 1.f, tjp1 = (j - 1) * 0.4f - 1.f;
      bb[j] = ((x - tj) * bb[j] + (tjp1 - x) * bb[j + 1]) * inv;
    }
  }
  {
    const float inv = 1.f / 0.8f;
#pragma unroll
    for (int j = 0; j < 9; ++j) {
      float tj = (j - 3) * 0.4f - 1.f, tjp1 = (j) * 0.4f - 1.f;
      bb[j] = ((x - tj) * bb[j] + (tjp1 - x) * bb[j + 1]) * inv;
    }
  }
  {
    const float inv = 1.f / 1.2000001f;
#pragma unroll
    for (int j = 0; j < 8; ++j) {
      float tj = (j - 3) * 0.4f - 1.f, tjp1 = (j + 1) * 0.4f - 1.f;
      bb[j] = ((x - tj) * bb[j] + (tjp1 - x) * bb[j + 1]) * inv;
    }
  }
#pragma unroll
  for (int j = 0; j < 8; ++j) out8[j] = bb[j];
}

// ---------------- 3-term MFMA GEMM, operands pre-split bf16 hi/lo ----------------
__global__ __launch_bounds__(256) void gemm_bf3(
    const ushort* __restrict__ Ahg, const ushort* __restrict__ Alg,
    const ushort* __restrict__ Bhg, const ushort* __restrict__ Blg,
    const float* __restrict__ bias, float* __restrict__ C,
    int M, int K, int N) {
  constexpr int LDA = 68;
  __shared__ __align__(16) ushort Ah[128 * LDA];
  __shared__ __align__(16) ushort Al[128 * LDA];
  __shared__ __align__(16) ushort Bh[64 * LDA];
  __shared__ __align__(16) ushort Bl[64 * LDA];
  const int tid = threadIdx.x;
  const int lane = tid & 63, wave = tid >> 6;
  const int lrow = lane & 15, quad = lane >> 4;
  const int bm = blockIdx.y * 128, bn = blockIdx.x * 64;
  floatx4 acc[2][4] = {};
  for (int k0 = 0; k0 < K; k0 += 64) {
#pragma unroll
    for (int i = 0; i < 4; ++i) {
      int c = tid + i * 256;
      int row = c >> 3, col8 = c & 7;
      int gr = bm + row;
      uint4 vh = make_uint4(0, 0, 0, 0), vl = make_uint4(0, 0, 0, 0);
      if (gr < M) {
        vh = *(const uint4*)(Ahg + (size_t)gr * K + k0 + col8 * 8);
        vl = *(const uint4*)(Alg + (size_t)gr * K + k0 + col8 * 8);
      }
      *(uint4*)&Ah[row * LDA + col8 * 8] = vh;
      *(uint4*)&Al[row * LDA + col8 * 8] = vl;
    }
#pragma unroll
    for (int i = 0; i < 2; ++i) {
      int c = tid + i * 256;
      int row = c >> 3, col8 = c & 7;
      *(uint4*)&Bh[row * LDA + col8 * 8] = *(const uint4*)(Bhg + (size_t)(bn + row) * K + k0 + col8 * 8);
      *(uint4*)&Bl[row * LDA + col8 * 8] = *(const uint4*)(Blg + (size_t)(bn + row) * K + k0 + col8 * 8);
    }
    __syncthreads();
#pragma unroll
    for (int kk = 0; kk < 64; kk += 32) {
      int kof = kk + quad * 8;
      const int ra0 = (wave * 32 + lrow) * LDA + kof;
      const int ra1 = (wave * 32 + 16 + lrow) * LDA + kof;
      short8 ah0 = *(const short8*)&Ah[ra0];
      short8 ah1 = *(const short8*)&Ah[ra1];
      short8 al0 = *(const short8*)&Al[ra0];
      short8 al1 = *(const short8*)&Al[ra1];
      short8 bh[4], blo[4];
#pragma unroll
      for (int nt = 0; nt < 4; ++nt) {
        int rb = (nt * 16 + lrow) * LDA + kof;
        bh[nt]  = *(const short8*)&Bh[rb];
        blo[nt] = *(const short8*)&Bl[rb];
      }
#pragma unroll
      for (int nt = 0; nt < 4; ++nt) {
        acc[0][nt] = __builtin_amdgcn_mfma_f32_16x16x32_bf16(ah0, bh[nt],  acc[0][nt], 0, 0, 0);
        acc[1][nt] = __builtin_amdgcn_mfma_f32_16x16x32_bf16(ah1, bh[nt],  acc[1][nt], 0, 0, 0);
        acc[0][nt] = __builtin_amdgcn_mfma_f32_16x16x32_bf16(al0, bh[nt],  acc[0][nt], 0, 0, 0);
        acc[1][nt] = __builtin_amdgcn_mfma_f32_16x16x32_bf16(al1, bh[nt],  acc[1][nt], 0, 0, 0);
        acc[0][nt] = __builtin_amdgcn_mfma_f32_16x16x32_bf16(ah0, blo[nt], acc[0][nt], 0, 0, 0);
        acc[1][nt] = __builtin_amdgcn_mfma_f32_16x16x32_bf16(ah1, blo[nt], acc[1][nt], 0, 0, 0);
      }
    }
    __syncthreads();
  }
#pragma unroll
  for (int mt = 0; mt < 2; ++mt) {
#pragma unroll
    for (int nt = 0; nt < 4; ++nt) {
#pragma unroll
      for (int reg = 0; reg < 4; ++reg) {
        int row = bm + wave * 32 + mt * 16 + quad * 4 + reg;
        int col = bn + nt * 16 + lrow;
        if (row < M) {
          float v = acc[mt][nt][reg];
          if (bias) v += bias[col];
          C[(size_t)row * N + col] = v;
        }
      }
    }
  }
}

// ---------------- fused KAN GEMM w/ split-K: C += expand(A) @ BT^T ----------------
template<int BM, int SPLIT>
__global__ __launch_bounds__(256) void gemm_kan(
    const float* __restrict__ A, const ushort* __restrict__ Bhg, const ushort* __restrict__ Blg,
    float* __restrict__ C, int M, int In, int N) {
  const int K = In * 9;
  const int ntiles = K >> 6;
  const int per = (ntiles + SPLIT - 1) / SPLIT;
  const int kt0 = blockIdx.z * per;
  const int kt1 = (kt0 + per < ntiles) ? (kt0 + per) : ntiles;
  constexpr int LDA = 68;
  __shared__ __align__(16) ushort Ah[BM * LDA];
  __shared__ __align__(16) ushort Al[BM * LDA];
  __shared__ __align__(16) ushort Bh[64 * LDA];
  __shared__ __align__(16) ushort Bl[64 * LDA];
  const int tid = threadIdx.x;
  const int lane = tid & 63, wave = tid >> 6;
  const int lrow = lane & 15, quad = lane >> 4;
  const int bm = blockIdx.y * BM, bn = blockIdx.x * 64;
  constexpr int MT = BM / 64;
  floatx4 acc[MT][4] = {};
  for (int kt = kt0; kt < kt1; ++kt) {
    int k0 = kt << 6;
    if (k0 < In) {
#pragma unroll
      for (int i = 0; i < BM / 16; ++i) {
        int c = tid + i * 256;
        int row = c >> 4, col4 = c & 15;
        int gr = bm + row;
        float4 v = make_float4(0.f, 0.f, 0.f, 0.f);
        if (gr < M) v = *(const float4*)(A + (size_t)gr * In + k0 + col4 * 4);
        float vv[4] = {silu_f(v.x), silu_f(v.y), silu_f(v.z), silu_f(v.w)};
        ushort h0 = f2bf(vv[0]), h1 = f2bf(vv[1]), h2 = f2bf(vv[2]), h3 = f2bf(vv[3]);
        ushort l0 = f2bf(vv[0] - bf2f(h0)), l1 = f2bf(vv[1] - bf2f(h1));
        ushort l2 = f2bf(vv[2] - bf2f(h2)), l3 = f2bf(vv[3] - bf2f(h3));
        *(uint2*)&Ah[row * LDA + col4 * 4] =
          make_uint2((unsigned)h0 | ((unsigned)h1 << 16), (unsigned)h2 | ((unsigned)h3 << 16));
        *(uint2*)&Al[row * LDA + col4 * 4] =
          make_uint2((unsigned)l0 | ((unsigned)l1 << 16), (unsigned)l2 | ((unsigned)l3 << 16));
      }
    } else {
      int i0 = (k0 - In) >> 3;
      if (tid < BM * 2) {
        int row = tid >> 1, half = tid & 1;
        int gr = bm + row;
        float4 v = make_float4(0.f, 0.f, 0.f, 0.f);
        if (gr < M) v = *(const float4*)(A + (size_t)gr * In + i0 + half * 4);
        float vv[4] = {v.x, v.y, v.z, v.w};
#pragma unroll
        for (int jj = 0; jj < 4; ++jj) {
          float b8[8];
          kan_bases(vv[jj], b8);
          unsigned hu[4], lu[4];
#pragma unroll
          for (int q = 0; q < 4; ++q) {
            ushort ha = f2bf(b8[2 * q]), hb = f2bf(b8[2 * q + 1]);
            ushort la = f2bf(b8[2 * q] - bf2f(ha)), lb = f2bf(b8[2 * q + 1] - bf2f(hb));
            hu[q] = (unsigned)ha | ((unsigned)hb << 16);
            lu[q] = (unsigned)la | ((unsigned)lb << 16);
          }
          int cbase = (half * 4 + jj) * 8;
          *(uint4*)&Ah[row * LDA + cbase] = make_uint4(hu[0], hu[1], hu[2], hu[3]);
          *(uint4*)&Al[row * LDA + cbase] = make_uint4(lu[0], lu[1], lu[2], lu[3]);
        }
      }
    }
#pragma unroll
    for (int i = 0; i < 2; ++i) {
      int c = tid + i * 256;
      int row = c >> 3, col8 = c & 7;
      *(uint4*)&Bh[row * LDA + col8 * 8] = *(const uint4*)(Bhg + (size_t)(bn + row) * K + k0 + col8 * 8);
      *(uint4*)&Bl[row * LDA + col8 * 8] = *(const uint4*)(Blg + (size_t)(bn + row) * K + k0 + col8 * 8);
    }
    __syncthreads();
#pragma unroll
    for (int kk = 0; kk < 64; kk += 32) {
      int kof = kk + quad * 8;
      short8 ah[MT], al[MT];
#pragma unroll
      for (int mt = 0; mt < MT; ++mt) {
        int ra = (wave * (BM / 4) + mt * 16 + lrow) * LDA + kof;
        ah[mt] = *(const short8*)&Ah[ra];
        al[mt] = *(const short8*)&Al[ra];
      }
      short8 bh[4], blo[4];
#pragma unroll
      for (int nt = 0; nt < 4; ++nt) {
        int rb = (nt * 16 + lrow) * LDA + kof;
        bh[nt]  = *(const short8*)&Bh[rb];
        blo[nt] = *(const short8*)&Bl[rb];
      }
#pragma unroll
      for (int nt = 0; nt < 4; ++nt) {
#pragma unroll
        for (int mt = 0; mt < MT; ++mt) {
          acc[mt][nt] = __builtin_amdgcn_mfma_f32_16x16x32_bf16(ah[mt], bh[nt],  acc[mt][nt], 0, 0, 0);
          acc[mt][nt] = __builtin_amdgcn_mfma_f32_16x16x32_bf16(al[mt], bh[nt],  acc[mt][nt], 0, 0, 0);
          acc[mt][nt] = __builtin_amdgcn_mfma_f32_16x16x32_bf16(ah[mt], blo[nt], acc[mt][nt], 0, 0, 0);
        }
      }
    }
    __syncthreads();
  }
#pragma unroll
  for (int mt = 0; mt < MT; ++mt) {
#pragma unroll
    for (int nt = 0; nt < 4; ++nt) {
#pragma unroll
      for (int reg = 0; reg < 4; ++reg) {
        int row = bm + wave * (BM / 4) + mt * 16 + quad * 4 + reg;
        int col = bn + nt * 16 + lrow;
        if (row < M) atomicAdd(&C[(size_t)row * N + col], acc[mt][nt][reg]);
      }
    }
  }
}

// ---------------- weight transpose+split: relation pairs -> [L*2][2048][128] ----------------
__global__ void conv_wT2(const float* __restrict__ Wl, const float* __restrict__ Wr,
                         const float* __restrict__ bl, const float* __restrict__ br,
                         ushort* __restrict__ WTh, ushort* __restrict__ WTl,
                         float* __restrict__ bout, int total) {
  int i = blockIdx.x * 256 + threadIdx.x;
  if (i >= total) return;
  int g2 = i / (2048 * 128), rem = i % (2048 * 128);
  int n = rem >> 7, k = rem & 127;
  int l = g2 >> 1, pair = g2 & 1;
  int r = pair * 2 + (n >> 10);          // relation within layer
  int nsub = n & 1023;                   // 0..1023 within [Wl|Wr]
  int nn = nsub & 511;
  int g = l * NR + r;
  const float* W = (nsub < 512) ? Wl : Wr;
  float v = W[(size_t)g * 65536 + (size_t)k * 512 + nn];
  ushort hi = f2bf(v);
  WTh[i] = hi;
  WTl[i] = f2bf(v - bf2f(hi));
  if (k == 0) bout[g2 * 2048 + n] = ((nsub < 512) ? bl : br)[g * 512 + nn];
}

// ---------------- build expanded KAN weight, transposed + split ----------------
__global__ void build_kan_wT(const float* __restrict__ base_w, const float* __restrict__ spline_w,
                             const float* __restrict__ scaler,
                             ushort* __restrict__ BTh, ushort* __restrict__ BTl,
                             int In, int Out) {
  int i = blockIdx.x * 256 + threadIdx.x;
  if (i >= In * 9 * Out) return;
  int o = i / (In * 9), k = i % (In * 9);
  float v;
  if (k < In) v = base_w[(size_t)o * In + k];
  else {
    int q = k - In, ii = q >> 3, gq = q & 7;
    v = spline_w[((size_t)o * In + ii) * 8 + gq] * scaler[(size_t)o * In + ii];
  }
  ushort hi = f2bf(v);
  BTh[i] = hi;
  BTl[i] = f2bf(v - bf2f(hi));
}

// ---------------- input projection (fp32 h + hi/lo bf16) ----------------
__global__ __launch_bounds__(128) void input_proj(
    const float* __restrict__ x, const float* __restrict__ id_emb,
    const int* __restrict__ id_token, const float* __restrict__ inW,
    const float* __restrict__ inb, float* __restrict__ h,
    ushort* __restrict__ hh, ushort* __restrict__ hl) {
  int n = blockIdx.x, j = threadIdx.x;
  __shared__ float s[FNODE + IDDIM];
  if (j < FNODE) s[j] = x[(size_t)n * FNODE + j];
  else if (j < FNODE + IDDIM) s[j] = id_emb[(size_t)id_token[n] * IDDIM + (j - FNODE)];
  __syncthreads();
  float acc = inb[j];
#pragma unroll
  for (int k = 0; k < FNODE + IDDIM; ++k) acc = fmaf(s[k], inW[k * HID + j], acc);
  float v = silu_f(acc);
  h[(size_t)n * HID + j] = v;
  ushort hi = f2bf(v);
  hh[(size_t)n * HID + j] = hi;
  hl[(size_t)n * HID + j] = f2bf(v - bf2f(hi));
}

// ---------------- per-layer prep ----------------
__global__ __launch_bounds__(512) void layer_prep(
    const float* __restrict__ rel_gate, const float* __restrict__ gat_bias,
    const float* __restrict__ rel_emb, const float* __restrict__ We, int l,
    float* __restrict__ gates, float* __restrict__ msg_bias, float* __restrict__ erel) {
  int j = threadIdx.x;
  float g[NR]; float mx = -1e30f;
  for (int r = 0; r < NR; ++r) { g[r] = rel_gate[l * NR + r]; mx = fmaxf(mx, g[r]); }
  float s = 0.f;
  for (int r = 0; r < NR; ++r) { g[r] = expf(g[r] - mx); s += g[r]; }
  for (int r = 0; r < NR; ++r) g[r] /= s;
  if (j < NR) gates[j] = g[j];
  if (j < HID) {
    float b = 0.f;
    for (int r = 0; r < NR; ++r) b = fmaf(g[r], gat_bias[((size_t)(l * NR + r)) * HID + j], b);
    msg_bias[j] = b;
  }
  for (int r = 0; r < NR; ++r) {
    const float* Wer = We + ((size_t)(l * NR + r)) * 24 * 512;
    const float* re  = rel_emb + (l * NR + r) * RELDIM;
    float acc = 0.f;
#pragma unroll
    for (int q = 0; q < RELDIM; ++q) acc = fmaf(re[q], Wer[(FEDGE + q) * 512 + j], acc);
    erel[r * 512 + j] = acc;
  }
}

// ---------------- fills ----------------
__global__ void fill_zero(float* __restrict__ p, int n) {
  int i = blockIdx.x * 256 + threadIdx.x;
  if (i < n) p[i] = 0.f;
}
__global__ void fill_zero_i(int* __restrict__ p, int n) {
  int i = blockIdx.x * 256 + threadIdx.x;
  if (i < n) p[i] = 0;
}

// ---------------- relation-sorted CSR build: bins (target, relation) ----------------
__global__ void csr_count2(const int* __restrict__ eidx, const int* __restrict__ etype,
                           int* __restrict__ deg2) {
  int e = blockIdx.x * 256 + threadIdx.x;
  if (e < NE) atomicAdd(&deg2[eidx[NE + e] * NR + etype[e]], 1);
}
__global__ __launch_bounds__(256) void csr_scan2(const int* __restrict__ deg2,
                                                 int* __restrict__ in_off2, int* __restrict__ cursor2) {
  __shared__ int ps[256];
  int t = threadIdx.x;
  const int TOT = NN * NR;
  const int CH = (TOT + 255) / 256;  // 157
  int base = t * CH;
  int sum = 0;
  for (int i = 0; i < CH; ++i) { int idx = base + i; if (idx < TOT) sum += deg2[idx]; }
  ps[t] = sum;
  __syncthreads();
  for (int o = 1; o < 256; o <<= 1) {
    int v = (t >= o) ? ps[t - o] : 0;
    __syncthreads();
    ps[t] += v;
    __syncthreads();
  }
  int run = (t == 0) ? 0 : ps[t - 1];
  for (int i = 0; i < CH; ++i) {
    int idx = base + i;
    if (idx < TOT) { in_off2[idx] = run; cursor2[idx] = run; run += deg2[idx]; }
  }
  if (t == 255) in_off2[TOT] = run;
}
__global__ void csr_scatter2(const int* __restrict__ eidx, const int* __restrict__ etype,
                             int* __restrict__ cursor2,
                             int* __restrict__ in_e2, int* __restrict__ in_s2) {
  int e = blockIdx.x * 256 + threadIdx.x;
  if (e < NE) {
    int pos = atomicAdd(&cursor2[eidx[NE + e] * NR + etype[e]], 1);
    in_e2[pos] = e;
    in_s2[pos] = eidx[e];
  }
}

// ---------------- node-centric GAT, relation-sorted CSR, 16 nodes/block ----------------
// xlr [NN,2048]: for r_sub: xl at [rs*1024, +512), xr at [rs*1024+512, +512).
// hmsg += gates[r]*0.25*agg via atomicAdd (hmsg pre-zeroed).
__global__ __launch_bounds__(1024) void gat_node3(
    const int* __restrict__ in_off2, const int* __restrict__ in_e2, const int* __restrict__ in_s2,
    const float* __restrict__ eattr, const float* __restrict__ xlr,
    const float* __restrict__ We_base, const float* __restrict__ erel_base,
    const float* __restrict__ att_base, const float* __restrict__ gates,
    int rbase, float* __restrict__ hmsg) {
  __shared__ float WeL[16][512];
  __shared__ float attL[512];
  __shared__ float erelL[512];
  int tid = threadIdx.x;
  int rs = blockIdx.y;
  int r = rbase + rs;
  const float* We_r = We_base + (size_t)rs * 24 * 512;
  for (int i = tid; i < 16 * 512; i += 1024) WeL[i >> 9][i & 511] = We_r[i];
  for (int i = tid; i < 512; i += 1024) {
    attL[i] = att_base[rs * 512 + i];
    erelL[i] = erel_base[rs * 512 + i];
  }
  __syncthreads();
  float gr = gates[r] * 0.25f;
  int lane = tid & 63, wave = tid >> 6;
  int n = blockIdx.x * 16 + wave;
  if (n >= NN) return;
  int roff = rs * 1024;
  float xr[8];
  const float* xrb = xlr + (size_t)n * 2048 + roff + 512;
#pragma unroll
  for (int h = 0; h < 4; ++h) {
    xr[h * 2]     = xrb[h * 128 + lane];
    xr[h * 2 + 1] = xrb[h * 128 + 64 + lane];
  }
  float m[4] = {-1e30f, -1e30f, -1e30f, -1e30f};
  float lsum[4] = {0.f, 0.f, 0.f, 0.f};
  float acc[8] = {0.f, 0.f, 0.f, 0.f, 0.f, 0.f, 0.f, 0.f};
  int e0 = in_off2[n * NR + r], e1 = in_off2[n * NR + r + 1];
  int e_nxt = 0, s_nxt = 0;
  if (e0 < e1) { e_nxt = in_e2[e0]; s_nxt = in_s2[e0]; }
  for (int ii = e0; ii < e1; ++ii) {
    int e = e_nxt, s = s_nxt;
    if (ii + 1 < e1) { e_nxt = in_e2[ii + 1]; s_nxt = in_s2[ii + 1]; }
    const float* xls = xlr + (size_t)s * 2048 + roff;
    float ea[16];
#pragma unroll
    for (int k = 0; k < 16; ++k) ea[k] = eattr[(size_t)e * 16 + k];
    float xlv[8], p[4];
#pragma unroll
    for (int h = 0; h < 4; ++h) {
      float ph = 0.f;
#pragma unroll
      for (int half = 0; half < 2; ++half) {
        int idx = h * 128 + half * 64 + lane;
        float xv = xls[idx];
        xlv[h * 2 + half] = xv;
        float et = erelL[idx];
#pragma unroll
        for (int k = 0; k < 16; ++k) et = fmaf(ea[k], WeL[k][idx], et);
        float z = xv + xr[h * 2 + half] + et;
        z = (z > 0.f) ? z : 0.2f * z;  // leaky_relu 0.2
        ph = fmaf(z, attL[idx], ph);
      }
      p[h] = ph;
    }
#pragma unroll
    for (int h = 0; h < 4; ++h) {
#pragma unroll
      for (int o = 32; o > 0; o >>= 1) p[h] += __shfl_xor(p[h], o, 64);
    }
#pragma unroll
    for (int h = 0; h < 4; ++h) {
      float sh = p[h];
      float mn = fmaxf(m[h], sh);
      float sc = expf(m[h] - mn);
      float we = expf(sh - mn);
      m[h] = mn;
      lsum[h] = lsum[h] * sc + we;
      acc[h * 2]     = acc[h * 2] * sc + we * xlv[h * 2];
      acc[h * 2 + 1] = acc[h * 2 + 1] * sc + we * xlv[h * 2 + 1];
    }
  }
  float o0 = 0.f, o1 = 0.f;
#pragma unroll
  for (int h = 0; h < 4; ++h) {
    float inv = 1.f / fmaxf(lsum[h], 1e-16f);
    o0 += acc[h * 2] * inv;
    o1 += acc[h * 2 + 1] * inv;
  }
  size_t base = (size_t)n * HID;
  atomicAdd(&hmsg[base + lane],      gr * o0);
  atomicAdd(&hmsg[base + 64 + lane], gr * o1);
}

// ---------------- LayerNorm over 128 dims (optionally emits hi/lo bf16) ----------------
__global__ __launch_bounds__(64) void ln128(
    float* __restrict__ h, const float* __restrict__ add, const float* __restrict__ bvec,
    const float* __restrict__ g, const float* __restrict__ b,
    ushort* __restrict__ hh, ushort* __restrict__ hl) {
  int n = blockIdx.x, lane = threadIdx.x;
  size_t base = (size_t)n * HID;
  float x0 = h[base + lane] + add[base + lane];
  float x1 = h[base + 64 + lane] + add[base + 64 + lane];
  if (bvec) { x0 += bvec[lane]; x1 += bvec[64 + lane]; }
  float s = x0 + x1;
#pragma unroll
  for (int m = 32; m > 0; m >>= 1) s += __shfl_xor(s, m, 64);
  float mu = s * (1.f / 128.f);
  float d0 = x0 - mu, d1 = x1 - mu;
  float q = d0 * d0 + d1 * d1;
#pragma unroll
  for (int m = 32; m > 0; m >>= 1) q += __shfl_xor(q, m, 64);
  float inv = 1.f / sqrtf(q * (1.f / 128.f) + 1e-5f);
  float o0 = d0 * inv * g[lane] + b[lane];
  float o1 = d1 * inv * g[64 + lane] + b[64 + lane];
  h[base + lane]      = o0;
  h[base + 64 + lane] = o1;
  if (hh) {
    ushort i0 = f2bf(o0), i1 = f2bf(o1);
    hh[base + lane] = i0;        hh[base + 64 + lane] = i1;
    hl[base + lane] = f2bf(o0 - bf2f(i0));
    hl[base + 64 + lane] = f2bf(o1 - bf2f(i1));
  }
}

// ---------------- KAN expansion (fp32) — tiny readout head only ----------------
__global__ void expand_f32(const float* __restrict__ v, float* __restrict__ u, int In, int rows) {
  int i = blockIdx.x * 256 + threadIdx.x;
  if (i >= rows * In) return;
  int n = i / In, c = i % In;
  float x = v[(size_t)n * In + c];
  size_t base = (size_t)n * In * 9;
  u[base + c] = silu_f(x);
  float b8[8];
  kan_bases(x, b8);
  float* ub = u + base + In + (size_t)c * 8;
#pragma unroll
  for (int gq = 0; gq < 8; ++gq) ub[gq] = b8[gq];
}

// ---------------- atomic-free pooling, stage 1: per-chunk partials ----------------
__global__ __launch_bounds__(128) void pool_part(
    const float* __restrict__ h, const int* __restrict__ batch,
    float* __restrict__ psum, float* __restrict__ pmax, float* __restrict__ pcnt) {
  __shared__ float sS[NG][HID];
  __shared__ float sM[NG][HID];
  __shared__ int sC[NG];
  int d = threadIdx.x, blk = blockIdx.x;
  const float NEGINF = __uint_as_float(0xff800000u);  // -inf
  for (int i = d; i < NG * HID; i += 128) {
    ((float*)sS)[i] = 0.f;
    ((float*)sM)[i] = NEGINF;
  }
  if (d < NG) sC[d] = 0;
  __syncthreads();
  const int CH = (NN + NCHUNK - 1) / NCHUNK;  // 79
  int n0 = blk * CH, n1 = (n0 + CH < NN) ? n0 + CH : NN;
  for (int n = n0; n < n1; ++n) {
    int g = batch[n];
    float v = h[(size_t)n * HID + d];
    sS[g][d] += v;
    sM[g][d] = fmaxf(sM[g][d], v);
    if (d == 0) sC[g]++;
  }
  __syncthreads();
  for (int i = d; i < NG * HID; i += 128) {
    psum[(size_t)blk * NG * HID + i] = ((float*)sS)[i];
    pmax[(size_t)blk * NG * HID + i] = ((float*)sM)[i];
  }
  if (d < NG) pcnt[blk * NG + d] = (float)sC[d];
}

// ---------------- pooling stage 2 + readout LN ----------------
__global__ __launch_bounds__(256) void pool_final2(
    const float* __restrict__ psum, const float* __restrict__ pmax,
    const float* __restrict__ pcnt, const float* __restrict__ rog,
    const float* __restrict__ rob, float* __restrict__ gvec) {
  int g = blockIdx.x, j = threadIdx.x;
  __shared__ float rb[256];
  float x;
  if (j < HID) {
    float s = 0.f, cn = 0.f;
    for (int c = 0; c < NCHUNK; ++c) {
      s += psum[(size_t)c * NG * HID + g * HID + j];
      cn += pcnt[c * NG + g];
    }
    x = s / fmaxf(cn, 1.f);
  } else {
    float mx = __uint_as_float(0xff800000u);
    for (int c = 0; c < NCHUNK; ++c)
      mx = fmaxf(mx, pmax[(size_t)c * NG * HID + g * HID + (j - HID)]);
    x = (mx > -1e38f) ? mx : 0.f;  // where(isfinite, ., 0)
  }
  rb[j] = x; __syncthreads();
  for (int st = 128; st > 0; st >>= 1) { if (j < st) rb[j] += rb[j + st]; __syncthreads(); }
  float mu = rb[0] * (1.f / 256.f); __syncthreads();
  float d = x - mu;
  rb[j] = d * d; __syncthreads();
  for (int st = 128; st > 0; st >>= 1) { if (j < st) rb[j] += rb[j + st]; __syncthreads(); }
  float var = rb[0] * (1.f / 256.f);
  float inv = 1.f / sqrtf(var + 1e-5f);
  gvec[(size_t)g * 256 + j] = d * inv * rog[j] + rob[j];
}

// ---------------- wave-parallel KAN head: one wave per (graph, output) ----------------
__global__ __launch_bounds__(256) void kan_head_w(
    const float* __restrict__ u, const float* __restrict__ base_w,
    const float* __restrict__ spline_w, const float* __restrict__ scaler,
    float* __restrict__ out, int In, int Out, int npairs) {
  int wid = blockIdx.x * 4 + (threadIdx.x >> 6);
  if (wid >= npairs) return;
  int g = wid / Out, o = wid % Out;
  int lane = threadIdx.x & 63;
  const float* ug = u + (size_t)g * In * 9;
  const float* bw = base_w + (size_t)o * In;
  const float* sp = spline_w + (size_t)o * In * 8;
  const float* sc = scaler + (size_t)o * In;
  float acc = 0.f;
  for (int i = lane; i < In; i += 64) acc = fmaf(ug[i], bw[i], acc);
  const float* us = ug + In;
  for (int k = lane; k < In * 8; k += 64) {
    int i = k >> 3;
    acc = fmaf(us[k], sp[k] * sc[i], acc);
  }
#pragma unroll
  for (int off2 = 32; off2 > 0; off2 >>= 1) acc += __shfl_xor(acc, off2, 64);
  if (lane == 0) out[(size_t)g * Out + o] = acc;
}

// ---------------- launch ----------------
extern "C" void kernel_launch(void* const* d_in, const int* in_sizes, int n_in,
                              void* d_out, int out_size, void* d_ws, size_t ws_size,
                              hipStream_t stream) {
  const float* x         = (const float*)d_in[0];
  const float* edge_attr = (const float*)d_in[1];
  const int*   id_token  = (const int*)  d_in[2];
  const int*   edge_index= (const int*)  d_in[3];
  const int*   edge_type = (const int*)  d_in[4];
  const int*   batch     = (const int*)  d_in[5];
  const float* id_emb    = (const float*)d_in[6];
  const float* inW       = (const float*)d_in[7];
  const float* inb       = (const float*)d_in[8];
  const float* Wl        = (const float*)d_in[9];
  const float* bl        = (const float*)d_in[10];
  const float* Wr        = (const float*)d_in[11];
  const float* br        = (const float*)d_in[12];
  const float* We        = (const float*)d_in[13];
  const float* att       = (const float*)d_in[14];
  const float* gat_bias  = (const float*)d_in[15];
  const float* rel_gate  = (const float*)d_in[16];
  const float* rel_emb   = (const float*)d_in[17];
  const float* ln1g      = (const float*)d_in[18];
  const float* ln1b      = (const float*)d_in[19];
  const float* ln2g      = (const float*)d_in[20];
  const float* ln2b      = (const float*)d_in[21];
  const float* ffn1_base = (const float*)d_in[22];
  const float* ffn1_spl  = (const float*)d_in[23];
  const float* ffn1_sc   = (const float*)d_in[24];
  const float* ffn2_base = (const float*)d_in[25];
  const float* ffn2_spl  = (const float*)d_in[26];
  const float* ffn2_sc   = (const float*)d_in[27];
  const float* rog       = (const float*)d_in[28];
  const float* rob       = (const float*)d_in[29];
  const float* h1_base   = (const float*)d_in[30];
  const float* h1_spl    = (const float*)d_in[31];
  const float* h1_sc     = (const float*)d_in[32];
  const float* h2_base   = (const float*)d_in[33];
  const float* h2_spl    = (const float*)d_in[34];
  const float* h2_sc     = (const float*)d_in[35];
  (void)in_sizes; (void)n_in; (void)out_size; (void)ws_size;

  // ---- workspace carve (256B aligned) ----
  char* wsp = (char*)d_ws;
  size_t off = 0;
  auto carve = [&](size_t bytes) { char* p = wsp + off; off = (off + bytes + 255) & ~(size_t)255; return p; };
  float*    h     = (float*)   carve((size_t)NN * HID * 4);
  ushort*   h_hi  = (ushort*)  carve((size_t)NN * HID * 2);
  ushort*   h_lo  = (ushort*)  carve((size_t)NN * HID * 2);
  float*    hmsg  = (float*)   carve((size_t)NN * HID * 4);
  float*    t1    = (float*)   carve((size_t)NN * FFNH * 4);
  float*    gates = (float*)   carve(NR * 4);
  float*    msgb  = (float*)   carve(HID * 4);
  float*    erel  = (float*)   carve(NR * 512 * 4);
  ushort*   WTh   = (ushort*)  carve((size_t)NL * 2 * 2048 * HID * 2);
  ushort*   WTl   = (ushort*)  carve((size_t)NL * 2 * 2048 * HID * 2);
  float*    blr   = (float*)   carve((size_t)NL * 2 * 2048 * 4);
  ushort*   B1h   = (ushort*)  carve((size_t)FFNH * HID * 9 * 2);
  ushort*   B1l   = (ushort*)  carve((size_t)FFNH * HID * 9 * 2);
  ushort*   B2h   = (ushort*)  carve((size_t)HID * FFNH * 9 * 2);
  ushort*   B2l   = (ushort*)  carve((size_t)HID * FFNH * 9 * 2);
  float*    psum  = (float*)   carve((size_t)NCHUNK * NG * HID * 4);
  float*    pmax  = (float*)   carve((size_t)NCHUNK * NG * HID * 4);
  float*    pcnt  = (float*)   carve((size_t)NCHUNK * NG * 4);
  float*    gvec  = (float*)   carve((size_t)NG * 256 * 4);
  float*    uhead = (float*)   carve((size_t)NG * 256 * 9 * 4);
  float*    thead = (float*)   carve((size_t)NG * HEADH * 4);
  float*    xlr   = (float*)   carve((size_t)NN * 2048 * 4);        // 82 MB
  int*      deg2  = (int*)     carve((size_t)NN * NR * 4);
  int*      in_off2=(int*)     carve((size_t)(NN * NR + 1) * 4);
  int*      cursor2=(int*)     carve((size_t)NN * NR * 4);
  int*      in_e2 = (int*)     carve((size_t)NE * 4);
  int*      in_s2 = (int*)     carve((size_t)NE * 4);

  // ---- relation-sorted CSR build (once; graph static across layers) ----
  fill_zero_i<<<(NN * NR + 255) / 256, 256, 0, stream>>>(deg2, NN * NR);
  csr_count2<<<(NE + 255) / 256, 256, 0, stream>>>(edge_index, edge_type, deg2);
  csr_scan2<<<1, 256, 0, stream>>>(deg2, in_off2, cursor2);
  csr_scatter2<<<(NE + 255) / 256, 256, 0, stream>>>(edge_index, edge_type, cursor2, in_e2, in_s2);

  // ---- weight transpose + split (once per launch) ----
  {
    int total = NL * 2 * 2048 * 128;
    conv_wT2<<<(total + 255) / 256, 256, 0, stream>>>(Wl, Wr, bl, br, WTh, WTl, blr, total);
  }

  // ---- input projection ----
  input_proj<<<NN, 128, 0, stream>>>(x, id_emb, id_token, inW, inb, h, h_hi, h_lo);

  const int MB128 = (NN + 127) / 128;  // 79
  const int MB64  = (NN + 63) / 64;    // 157
  for (int l = 0; l < NL; ++l) {
    layer_prep<<<1, 512, 0, stream>>>(rel_gate, gat_bias, rel_emb, We, l, gates, msgb, erel);
    fill_zero<<<(NN * HID + 255) / 256, 256, 0, stream>>>(hmsg, NN * HID);
    for (int pair = 0; pair < 2; ++pair) {
      int g2 = l * 2 + pair;
      const ushort* WThp = WTh + (size_t)g2 * 2048 * HID;
      const ushort* WTlp = WTl + (size_t)g2 * 2048 * HID;
      const float* blp   = blr + (size_t)g2 * 2048;
      int rbase = pair * 2;
      gemm_bf3<<<dim3(2048 / 64, MB128), 256, 0, stream>>>(h_hi, h_lo, WThp, WTlp, blp, xlr, NN, HID, 2048);
      gat_node3<<<dim3((NN + 15) / 16, 2), 1024, 0, stream>>>(
          in_off2, in_e2, in_s2, edge_attr, xlr,
          We + ((size_t)(l * NR + rbase)) * 24 * 512, erel + rbase * 512,
          att + (size_t)(l * NR + rbase) * 512, gates, rbase, hmsg);
    }
    ln128<<<NN, 64, 0, stream>>>(h, hmsg, msgb, ln1g + l * HID, ln1b + l * HID, nullptr, nullptr);

    // ---- KAN FFN1: 128 -> 256 (K = 1152), fused expansion, split-K 3 ----
    build_kan_wT<<<((HID * 9 * FFNH) + 255) / 256, 256, 0, stream>>>(
        ffn1_base + (size_t)l * FFNH * HID, ffn1_spl + (size_t)l * FFNH * HID * 8,
        ffn1_sc + (size_t)l * FFNH * HID, B1h, B1l, HID, FFNH);
    fill_zero<<<(NN * FFNH + 255) / 256, 256, 0, stream>>>(t1, NN * FFNH);
    gemm_kan<128, 3><<<dim3(FFNH / 64, MB128, 3), 256, 0, stream>>>(h, B1h, B1l, t1, NN, HID, FFNH);
    // ---- KAN FFN2: 256 -> 128 (K = 2304), fused expansion, split-K 4 ----
    build_kan_wT<<<((FFNH * 9 * HID) + 255) / 256, 256, 0, stream>>>(
        ffn2_base + (size_t)l * HID * FFNH, ffn2_spl + (size_t)l * HID * FFNH * 8,
        ffn2_sc + (size_t)l * HID * FFNH, B2h, B2l, FFNH, HID);
    fill_zero<<<(NN * HID + 255) / 256, 256, 0, stream>>>(hmsg, NN * HID);
    gemm_kan<64, 4><<<dim3(HID / 64, MB64, 4), 256, 0, stream>>>(t1, B2h, B2l, hmsg, NN, FFNH, HID);
    ln128<<<NN, 64, 0, stream>>>(h, hmsg, nullptr, ln2g + l * HID, ln2b + l * HID, h_hi, h_lo);
  }

  // ---- readout (atomic-free pooling) ----
  pool_part<<<NCHUNK, 128, 0, stream>>>(h, batch, psum, pmax, pcnt);
  pool_final2<<<NG, 256, 0, stream>>>(psum, pmax, pcnt, rog, rob, gvec);
  expand_f32<<<((NG * 256) + 255) / 256, 256, 0, stream>>>(gvec, uhead, 256, NG);
  {
    int npairs = NG * HEADH;  // 4096 waves
    kan_head_w<<<(npairs + 3) / 4, 256, 0, stream>>>(uhead, h1_base, h1_spl, h1_sc, thead, 256, HEADH, npairs);
  }
  expand_f32<<<((NG * HEADH) + 255) / 256, 256, 0, stream>>>(thead, uhead, HEADH, NG);
  {
    int npairs = NG * NCLS;   // 320 waves
    kan_head_w<<<(npairs + 3) / 4, 256, 0, stream>>>(uhead, h2_base, h2_spl, h2_sc, (float*)d_out, HEADH, NCLS, npairs);
  }
}

// Round 10
// 1729.433 us; speedup vs baseline: 2.5759x; 2.5759x over previous
//
#include <hip/hip_runtime.h>
#include <cstdint>
#include <cstddef>

// ---------------- static problem config ----------------
#define NN      10000   // nodes
#define NE      120000  // edges
#define NG      32      // graphs
#define FNODE   64
#define FEDGE   16
#define HID     128
#define NHEADS  4
#define NL      3
#define NR      4
#define IDDIM   32
#define RELDIM  8
#define FFNH    256
#define HEADH   128
#define NCLS    10

#define NCHUNK  128     // pooling stage-1 blocks

typedef __attribute__((ext_vector_type(8))) short short8;
typedef __attribute__((ext_vector_type(4))) float floatx4;

// ---------------- helpers ----------------
__device__ __forceinline__ float silu_f(float x) { return x / (1.f + expf(-x)); }
__device__ __forceinline__ ushort f2bf(float f) {   // round-to-nearest-even bf16
  unsigned u = __float_as_uint(f);
  return (ushort)((u + 0x7FFFu + ((u >> 16) & 1u)) >> 16);
}
__device__ __forceinline__ float bf2f(ushort h) { return __uint_as_float((unsigned)h << 16); }

// Cox–de Boor cubic bases on grid t_j = (j-3)*0.4 - 1 (GRID_SIZE=5, ORDER=3) -> 8 bases
__device__ __forceinline__ void kan_bases(float x, float* out8) {
  float bb[11];
#pragma unroll
  for (int j = 0; j < 11; ++j) {
    float t0 = (j - 3) * 0.4f - 1.f;
    float t1 = (j - 2) * 0.4f - 1.f;
    bb[j] = (x >= t0 && x < t1) ? 1.f : 0.f;
  }
  {
    const float inv = 1.f / 0.4f;
#pragma unroll
    for (int j = 0; j < 10; ++j) {
      float tj = (j - 3) * 0.4f - 1.f, tjp1 = (j - 1) * 0.4f - 1.f;
      bb[j] = ((x - tj) * bb[j] + (tjp1 - x) * bb[j + 1]) * inv;
    }
  }
  {
    const float inv = 1.f / 0.8f;
#pragma unroll
    for (int j = 0; j < 9; ++j) {
      float tj = (j - 3) * 0.4f - 1.f, tjp1 = (j) * 0.4f - 1.f;
      bb[j] = ((x - tj) * bb[j] + (tjp1 - x) * bb[j + 1]) * inv;
    }
  }
  {
    const float inv = 1.f / 1.2000001f;
#pragma unroll
    for (int j = 0; j < 8; ++j) {
      float tj = (j - 3) * 0.4f - 1.f, tjp1 = (j + 1) * 0.4f - 1.f;
      bb[j] = ((x - tj) * bb[j] + (tjp1 - x) * bb[j + 1]) * inv;
    }
  }
#pragma unroll
  for (int j = 0; j < 8; ++j) out8[j] = bb[j];
}

// ---------------- 3-term MFMA GEMM, operands pre-split bf16 hi/lo ----------------
__global__ __launch_bounds__(256) void gemm_bf3(
    const ushort* __restrict__ Ahg, const ushort* __restrict__ Alg,
    const ushort* __restrict__ Bhg, const ushort* __restrict__ Blg,
    const float* __restrict__ bias, float* __restrict__ C,
    int M, int K, int N) {
  constexpr int LDA = 68;
  __shared__ __align__(16) ushort Ah[128 * LDA];
  __shared__ __align__(16) ushort Al[128 * LDA];
  __shared__ __align__(16) ushort Bh[64 * LDA];
  __shared__ __align__(16) ushort Bl[64 * LDA];
  const int tid = threadIdx.x;
  const int lane = tid & 63, wave = tid >> 6;
  const int lrow = lane & 15, quad = lane >> 4;
  const int bm = blockIdx.y * 128, bn = blockIdx.x * 64;
  floatx4 acc[2][4] = {};
  for (int k0 = 0; k0 < K; k0 += 64) {
#pragma unroll
    for (int i = 0; i < 4; ++i) {
      int c = tid + i * 256;
      int row = c >> 3, col8 = c & 7;
      int gr = bm + row;
      uint4 vh = make_uint4(0, 0, 0, 0), vl = make_uint4(0, 0, 0, 0);
      if (gr < M) {
        vh = *(const uint4*)(Ahg + (size_t)gr * K + k0 + col8 * 8);
        vl = *(const uint4*)(Alg + (size_t)gr * K + k0 + col8 * 8);
      }
      *(uint4*)&Ah[row * LDA + col8 * 8] = vh;
      *(uint4*)&Al[row * LDA + col8 * 8] = vl;
    }
#pragma unroll
    for (int i = 0; i < 2; ++i) {
      int c = tid + i * 256;
      int row = c >> 3, col8 = c & 7;
      *(uint4*)&Bh[row * LDA + col8 * 8] = *(const uint4*)(Bhg + (size_t)(bn + row) * K + k0 + col8 * 8);
      *(uint4*)&Bl[row * LDA + col8 * 8] = *(const uint4*)(Blg + (size_t)(bn + row) * K + k0 + col8 * 8);
    }
    __syncthreads();
#pragma unroll
    for (int kk = 0; kk < 64; kk += 32) {
      int kof = kk + quad * 8;
      const int ra0 = (wave * 32 + lrow) * LDA + kof;
      const int ra1 = (wave * 32 + 16 + lrow) * LDA + kof;
      short8 ah0 = *(const short8*)&Ah[ra0];
      short8 ah1 = *(const short8*)&Ah[ra1];
      short8 al0 = *(const short8*)&Al[ra0];
      short8 al1 = *(const short8*)&Al[ra1];
      short8 bh[4], blo[4];
#pragma unroll
      for (int nt = 0; nt < 4; ++nt) {
        int rb = (nt * 16 + lrow) * LDA + kof;
        bh[nt]  = *(const short8*)&Bh[rb];
        blo[nt] = *(const short8*)&Bl[rb];
      }
#pragma unroll
      for (int nt = 0; nt < 4; ++nt) {
        acc[0][nt] = __builtin_amdgcn_mfma_f32_16x16x32_bf16(ah0, bh[nt],  acc[0][nt], 0, 0, 0);
        acc[1][nt] = __builtin_amdgcn_mfma_f32_16x16x32_bf16(ah1, bh[nt],  acc[1][nt], 0, 0, 0);
        acc[0][nt] = __builtin_amdgcn_mfma_f32_16x16x32_bf16(al0, bh[nt],  acc[0][nt], 0, 0, 0);
        acc[1][nt] = __builtin_amdgcn_mfma_f32_16x16x32_bf16(al1, bh[nt],  acc[1][nt], 0, 0, 0);
        acc[0][nt] = __builtin_amdgcn_mfma_f32_16x16x32_bf16(ah0, blo[nt], acc[0][nt], 0, 0, 0);
        acc[1][nt] = __builtin_amdgcn_mfma_f32_16x16x32_bf16(ah1, blo[nt], acc[1][nt], 0, 0, 0);
      }
    }
    __syncthreads();
  }
#pragma unroll
  for (int mt = 0; mt < 2; ++mt) {
#pragma unroll
    for (int nt = 0; nt < 4; ++nt) {
#pragma unroll
      for (int reg = 0; reg < 4; ++reg) {
        int row = bm + wave * 32 + mt * 16 + quad * 4 + reg;
        int col = bn + nt * 16 + lrow;
        if (row < M) {
          float v = acc[mt][nt][reg];
          if (bias) v += bias[col];
          C[(size_t)row * N + col] = v;
        }
      }
    }
  }
}

// ---------------- fused KAN GEMM w/ split-K: C += expand(A) @ BT^T ----------------
template<int BM, int SPLIT>
__global__ __launch_bounds__(256) void gemm_kan(
    const float* __restrict__ A, const ushort* __restrict__ Bhg, const ushort* __restrict__ Blg,
    float* __restrict__ C, int M, int In, int N) {
  const int K = In * 9;
  const int ntiles = K >> 6;
  const int per = (ntiles + SPLIT - 1) / SPLIT;
  const int kt0 = blockIdx.z * per;
  const int kt1 = (kt0 + per < ntiles) ? (kt0 + per) : ntiles;
  constexpr int LDA = 68;
  __shared__ __align__(16) ushort Ah[BM * LDA];
  __shared__ __align__(16) ushort Al[BM * LDA];
  __shared__ __align__(16) ushort Bh[64 * LDA];
  __shared__ __align__(16) ushort Bl[64 * LDA];
  const int tid = threadIdx.x;
  const int lane = tid & 63, wave = tid >> 6;
  const int lrow = lane & 15, quad = lane >> 4;
  const int bm = blockIdx.y * BM, bn = blockIdx.x * 64;
  constexpr int MT = BM / 64;
  floatx4 acc[MT][4] = {};
  for (int kt = kt0; kt < kt1; ++kt) {
    int k0 = kt << 6;
    if (k0 < In) {
#pragma unroll
      for (int i = 0; i < BM / 16; ++i) {
        int c = tid + i * 256;
        int row = c >> 4, col4 = c & 15;
        int gr = bm + row;
        float4 v = make_float4(0.f, 0.f, 0.f, 0.f);
        if (gr < M) v = *(const float4*)(A + (size_t)gr * In + k0 + col4 * 4);
        float vv[4] = {silu_f(v.x), silu_f(v.y), silu_f(v.z), silu_f(v.w)};
        ushort h0 = f2bf(vv[0]), h1 = f2bf(vv[1]), h2 = f2bf(vv[2]), h3 = f2bf(vv[3]);
        ushort l0 = f2bf(vv[0] - bf2f(h0)), l1 = f2bf(vv[1] - bf2f(h1));
        ushort l2 = f2bf(vv[2] - bf2f(h2)), l3 = f2bf(vv[3] - bf2f(h3));
        *(uint2*)&Ah[row * LDA + col4 * 4] =
          make_uint2((unsigned)h0 | ((unsigned)h1 << 16), (unsigned)h2 | ((unsigned)h3 << 16));
        *(uint2*)&Al[row * LDA + col4 * 4] =
          make_uint2((unsigned)l0 | ((unsigned)l1 << 16), (unsigned)l2 | ((unsigned)l3 << 16));
      }
    } else {
      int i0 = (k0 - In) >> 3;
      if (tid < BM * 2) {
        int row = tid >> 1, half = tid & 1;
        int gr = bm + row;
        float4 v = make_float4(0.f, 0.f, 0.f, 0.f);
        if (gr < M) v = *(const float4*)(A + (size_t)gr * In + i0 + half * 4);
        float vv[4] = {v.x, v.y, v.z, v.w};
#pragma unroll
        for (int jj = 0; jj < 4; ++jj) {
          float b8[8];
          kan_bases(vv[jj], b8);
          unsigned hu[4], lu[4];
#pragma unroll
          for (int q = 0; q < 4; ++q) {
            ushort ha = f2bf(b8[2 * q]), hb = f2bf(b8[2 * q + 1]);
            ushort la = f2bf(b8[2 * q] - bf2f(ha)), lb = f2bf(b8[2 * q + 1] - bf2f(hb));
            hu[q] = (unsigned)ha | ((unsigned)hb << 16);
            lu[q] = (unsigned)la | ((unsigned)lb << 16);
          }
          int cbase = (half * 4 + jj) * 8;
          *(uint4*)&Ah[row * LDA + cbase] = make_uint4(hu[0], hu[1], hu[2], hu[3]);
          *(uint4*)&Al[row * LDA + cbase] = make_uint4(lu[0], lu[1], lu[2], lu[3]);
        }
      }
    }
#pragma unroll
    for (int i = 0; i < 2; ++i) {
      int c = tid + i * 256;
      int row = c >> 3, col8 = c & 7;
      *(uint4*)&Bh[row * LDA + col8 * 8] = *(const uint4*)(Bhg + (size_t)(bn + row) * K + k0 + col8 * 8);
      *(uint4*)&Bl[row * LDA + col8 * 8] = *(const uint4*)(Blg + (size_t)(bn + row) * K + k0 + col8 * 8);
    }
    __syncthreads();
#pragma unroll
    for (int kk = 0; kk < 64; kk += 32) {
      int kof = kk + quad * 8;
      short8 ah[MT], al[MT];
#pragma unroll
      for (int mt = 0; mt < MT; ++mt) {
        int ra = (wave * (BM / 4) + mt * 16 + lrow) * LDA + kof;
        ah[mt] = *(const short8*)&Ah[ra];
        al[mt] = *(const short8*)&Al[ra];
      }
      short8 bh[4], blo[4];
#pragma unroll
      for (int nt = 0; nt < 4; ++nt) {
        int rb = (nt * 16 + lrow) * LDA + kof;
        bh[nt]  = *(const short8*)&Bh[rb];
        blo[nt] = *(const short8*)&Bl[rb];
      }
#pragma unroll
      for (int nt = 0; nt < 4; ++nt) {
#pragma unroll
        for (int mt = 0; mt < MT; ++mt) {
          acc[mt][nt] = __builtin_amdgcn_mfma_f32_16x16x32_bf16(ah[mt], bh[nt],  acc[mt][nt], 0, 0, 0);
          acc[mt][nt] = __builtin_amdgcn_mfma_f32_16x16x32_bf16(al[mt], bh[nt],  acc[mt][nt], 0, 0, 0);
          acc[mt][nt] = __builtin_amdgcn_mfma_f32_16x16x32_bf16(ah[mt], blo[nt], acc[mt][nt], 0, 0, 0);
        }
      }
    }
    __syncthreads();
  }
#pragma unroll
  for (int mt = 0; mt < MT; ++mt) {
#pragma unroll
    for (int nt = 0; nt < 4; ++nt) {
#pragma unroll
      for (int reg = 0; reg < 4; ++reg) {
        int row = bm + wave * (BM / 4) + mt * 16 + quad * 4 + reg;
        int col = bn + nt * 16 + lrow;
        if (row < M) atomicAdd(&C[(size_t)row * N + col], acc[mt][nt][reg]);
      }
    }
  }
}

// ---------------- weight transpose+split: relation pairs -> [L*2][2048][128] ----------------
__global__ void conv_wT2(const float* __restrict__ Wl, const float* __restrict__ Wr,
                         const float* __restrict__ bl, const float* __restrict__ br,
                         ushort* __restrict__ WTh, ushort* __restrict__ WTl,
                         float* __restrict__ bout, int total) {
  int i = blockIdx.x * 256 + threadIdx.x;
  if (i >= total) return;
  int g2 = i / (2048 * 128), rem = i % (2048 * 128);
  int n = rem >> 7, k = rem & 127;
  int l = g2 >> 1, pair = g2 & 1;
  int r = pair * 2 + (n >> 10);          // relation within layer
  int nsub = n & 1023;                   // 0..1023 within [Wl|Wr]
  int nn = nsub & 511;
  int g = l * NR + r;
  const float* W = (nsub < 512) ? Wl : Wr;
  float v = W[(size_t)g * 65536 + (size_t)k * 512 + nn];
  ushort hi = f2bf(v);
  WTh[i] = hi;
  WTl[i] = f2bf(v - bf2f(hi));
  if (k == 0) bout[g2 * 2048 + n] = ((nsub < 512) ? bl : br)[g * 512 + nn];
}

// ---------------- build expanded KAN weight, transposed + split ----------------
__global__ void build_kan_wT(const float* __restrict__ base_w, const float* __restrict__ spline_w,
                             const float* __restrict__ scaler,
                             ushort* __restrict__ BTh, ushort* __restrict__ BTl,
                             int In, int Out) {
  int i = blockIdx.x * 256 + threadIdx.x;
  if (i >= In * 9 * Out) return;
  int o = i / (In * 9), k = i % (In * 9);
  float v;
  if (k < In) v = base_w[(size_t)o * In + k];
  else {
    int q = k - In, ii = q >> 3, gq = q & 7;
    v = spline_w[((size_t)o * In + ii) * 8 + gq] * scaler[(size_t)o * In + ii];
  }
  ushort hi = f2bf(v);
  BTh[i] = hi;
  BTl[i] = f2bf(v - bf2f(hi));
}

// ---------------- input projection (fp32 h + hi/lo bf16) ----------------
__global__ __launch_bounds__(128) void input_proj(
    const float* __restrict__ x, const float* __restrict__ id_emb,
    const int* __restrict__ id_token, const float* __restrict__ inW,
    const float* __restrict__ inb, float* __restrict__ h,
    ushort* __restrict__ hh, ushort* __restrict__ hl) {
  int n = blockIdx.x, j = threadIdx.x;
  __shared__ float s[FNODE + IDDIM];
  if (j < FNODE) s[j] = x[(size_t)n * FNODE + j];
  else if (j < FNODE + IDDIM) s[j] = id_emb[(size_t)id_token[n] * IDDIM + (j - FNODE)];
  __syncthreads();
  float acc = inb[j];
#pragma unroll
  for (int k = 0; k < FNODE + IDDIM; ++k) acc = fmaf(s[k], inW[k * HID + j], acc);
  float v = silu_f(acc);
  h[(size_t)n * HID + j] = v;
  ushort hi = f2bf(v);
  hh[(size_t)n * HID + j] = hi;
  hl[(size_t)n * HID + j] = f2bf(v - bf2f(hi));
}

// ---------------- per-layer prep ----------------
__global__ __launch_bounds__(512) void layer_prep(
    const float* __restrict__ rel_gate, const float* __restrict__ gat_bias,
    const float* __restrict__ rel_emb, const float* __restrict__ We, int l,
    float* __restrict__ gates, float* __restrict__ msg_bias, float* __restrict__ erel) {
  int j = threadIdx.x;
  float g[NR]; float mx = -1e30f;
  for (int r = 0; r < NR; ++r) { g[r] = rel_gate[l * NR + r]; mx = fmaxf(mx, g[r]); }
  float s = 0.f;
  for (int r = 0; r < NR; ++r) { g[r] = expf(g[r] - mx); s += g[r]; }
  for (int r = 0; r < NR; ++r) g[r] /= s;
  if (j < NR) gates[j] = g[j];
  if (j < HID) {
    float b = 0.f;
    for (int r = 0; r < NR; ++r) b = fmaf(g[r], gat_bias[((size_t)(l * NR + r)) * HID + j], b);
    msg_bias[j] = b;
  }
  for (int r = 0; r < NR; ++r) {
    const float* Wer = We + ((size_t)(l * NR + r)) * 24 * 512;
    const float* re  = rel_emb + (l * NR + r) * RELDIM;
    float acc = 0.f;
#pragma unroll
    for (int q = 0; q < RELDIM; ++q) acc = fmaf(re[q], Wer[(FEDGE + q) * 512 + j], acc);
    erel[r * 512 + j] = acc;
  }
}

// ---------------- fills ----------------
__global__ void fill_zero(float* __restrict__ p, int n) {
  int i = blockIdx.x * 256 + threadIdx.x;
  if (i < n) p[i] = 0.f;
}
__global__ void fill_zero_i(int* __restrict__ p, int n) {
  int i = blockIdx.x * 256 + threadIdx.x;
  if (i < n) p[i] = 0;
}

// ---------------- relation-sorted CSR build: bins (target, relation) ----------------
__global__ void csr_count2(const int* __restrict__ eidx, const int* __restrict__ etype,
                           int* __restrict__ deg2) {
  int e = blockIdx.x * 256 + threadIdx.x;
  if (e < NE) atomicAdd(&deg2[eidx[NE + e] * NR + etype[e]], 1);
}
__global__ __launch_bounds__(256) void csr_scan2(const int* __restrict__ deg2,
                                                 int* __restrict__ in_off2, int* __restrict__ cursor2) {
  __shared__ int ps[256];
  int t = threadIdx.x;
  const int TOT = NN * NR;
  const int CH = (TOT + 255) / 256;  // 157
  int base = t * CH;
  int sum = 0;
  for (int i = 0; i < CH; ++i) { int idx = base + i; if (idx < TOT) sum += deg2[idx]; }
  ps[t] = sum;
  __syncthreads();
  for (int o = 1; o < 256; o <<= 1) {
    int v = (t >= o) ? ps[t - o] : 0;
    __syncthreads();
    ps[t] += v;
    __syncthreads();
  }
  int run = (t == 0) ? 0 : ps[t - 1];
  for (int i = 0; i < CH; ++i) {
    int idx = base + i;
    if (idx < TOT) { in_off2[idx] = run; cursor2[idx] = run; run += deg2[idx]; }
  }
  if (t == 255) in_off2[TOT] = run;
}
__global__ void csr_scatter2(const int* __restrict__ eidx, const int* __restrict__ etype,
                             int* __restrict__ cursor2,
                             int* __restrict__ in_e2, int* __restrict__ in_s2) {
  int e = blockIdx.x * 256 + threadIdx.x;
  if (e < NE) {
    int pos = atomicAdd(&cursor2[eidx[NE + e] * NR + etype[e]], 1);
    in_e2[pos] = e;
    in_s2[pos] = eidx[e];
  }
}

// ---------------- node-centric GAT, relation-sorted CSR, 4 nodes/block ----------------
// xlr [NN,2048]: for r_sub: xl at [rs*1024, +512), xr at [rs*1024+512, +512).
// hmsg += gates[r]*0.25*agg via atomicAdd (hmsg pre-zeroed).
__global__ __launch_bounds__(256) void gat_node4(
    const int* __restrict__ in_off2, const int* __restrict__ in_e2, const int* __restrict__ in_s2,
    const float* __restrict__ eattr, const float* __restrict__ xlr,
    const float* __restrict__ We_base, const float* __restrict__ erel_base,
    const float* __restrict__ att_base, const float* __restrict__ gates,
    int rbase, float* __restrict__ hmsg) {
  __shared__ float WeL[16][512];
  __shared__ float attL[512];
  __shared__ float erelL[512];
  int tid = threadIdx.x;
  int rs = blockIdx.y;
  int r = rbase + rs;
  const float* We_r = We_base + (size_t)rs * 24 * 512;
  for (int i = tid; i < 16 * 512; i += 256) WeL[i >> 9][i & 511] = We_r[i];
  for (int i = tid; i < 512; i += 256) {
    attL[i] = att_base[rs * 512 + i];
    erelL[i] = erel_base[rs * 512 + i];
  }
  __syncthreads();
  float gr = gates[r] * 0.25f;
  int lane = tid & 63, wave = tid >> 6;
  int n = blockIdx.x * 4 + wave;
  if (n >= NN) return;
  int roff = rs * 1024;
  float xr[8];
  const float* xrb = xlr + (size_t)n * 2048 + roff + 512;
#pragma unroll
  for (int h = 0; h < 4; ++h) {
    xr[h * 2]     = xrb[h * 128 + lane];
    xr[h * 2 + 1] = xrb[h * 128 + 64 + lane];
  }
  float m[4] = {-1e30f, -1e30f, -1e30f, -1e30f};
  float lsum[4] = {0.f, 0.f, 0.f, 0.f};
  float acc[8] = {0.f, 0.f, 0.f, 0.f, 0.f, 0.f, 0.f, 0.f};
  int e0 = in_off2[n * NR + r], e1 = in_off2[n * NR + r + 1];
  int e_nxt = 0, s_nxt = 0;
  if (e0 < e1) { e_nxt = in_e2[e0]; s_nxt = in_s2[e0]; }
  for (int ii = e0; ii < e1; ++ii) {
    int e = e_nxt, s = s_nxt;
    if (ii + 1 < e1) { e_nxt = in_e2[ii + 1]; s_nxt = in_s2[ii + 1]; }
    const float* xls = xlr + (size_t)s * 2048 + roff;
    float ea[16];
#pragma unroll
    for (int k = 0; k < 16; ++k) ea[k] = eattr[(size_t)e * 16 + k];
    float xlv[8], p[4];
#pragma unroll
    for (int h = 0; h < 4; ++h) {
      float ph = 0.f;
#pragma unroll
      for (int half = 0; half < 2; ++half) {
        int idx = h * 128 + half * 64 + lane;
        float xv = xls[idx];
        xlv[h * 2 + half] = xv;
        float et = erelL[idx];
#pragma unroll
        for (int k = 0; k < 16; ++k) et = fmaf(ea[k], WeL[k][idx], et);
        float z = xv + xr[h * 2 + half] + et;
        z = (z > 0.f) ? z : 0.2f * z;  // leaky_relu 0.2
        ph = fmaf(z, attL[idx], ph);
      }
      p[h] = ph;
    }
#pragma unroll
    for (int h = 0; h < 4; ++h) {
#pragma unroll
      for (int o = 32; o > 0; o >>= 1) p[h] += __shfl_xor(p[h], o, 64);
    }
#pragma unroll
    for (int h = 0; h < 4; ++h) {
      float sh = p[h];
      float mn = fmaxf(m[h], sh);
      float sc = expf(m[h] - mn);
      float we = expf(sh - mn);
      m[h] = mn;
      lsum[h] = lsum[h] * sc + we;
      acc[h * 2]     = acc[h * 2] * sc + we * xlv[h * 2];
      acc[h * 2 + 1] = acc[h * 2 + 1] * sc + we * xlv[h * 2 + 1];
    }
  }
  float o0 = 0.f, o1 = 0.f;
#pragma unroll
  for (int h = 0; h < 4; ++h) {
    float inv = 1.f / fmaxf(lsum[h], 1e-16f);
    o0 += acc[h * 2] * inv;
    o1 += acc[h * 2 + 1] * inv;
  }
  size_t base = (size_t)n * HID;
  atomicAdd(&hmsg[base + lane],      gr * o0);
  atomicAdd(&hmsg[base + 64 + lane], gr * o1);
}

// ---------------- LayerNorm over 128 dims (optionally emits hi/lo bf16) ----------------
__global__ __launch_bounds__(64) void ln128(
    float* __restrict__ h, const float* __restrict__ add, const float* __restrict__ bvec,
    const float* __restrict__ g, const float* __restrict__ b,
    ushort* __restrict__ hh, ushort* __restrict__ hl) {
  int n = blockIdx.x, lane = threadIdx.x;
  size_t base = (size_t)n * HID;
  float x0 = h[base + lane] + add[base + lane];
  float x1 = h[base + 64 + lane] + add[base + 64 + lane];
  if (bvec) { x0 += bvec[lane]; x1 += bvec[64 + lane]; }
  float s = x0 + x1;
#pragma unroll
  for (int m = 32; m > 0; m >>= 1) s += __shfl_xor(s, m, 64);
  float mu = s * (1.f / 128.f);
  float d0 = x0 - mu, d1 = x1 - mu;
  float q = d0 * d0 + d1 * d1;
#pragma unroll
  for (int m = 32; m > 0; m >>= 1) q += __shfl_xor(q, m, 64);
  float inv = 1.f / sqrtf(q * (1.f / 128.f) + 1e-5f);
  float o0 = d0 * inv * g[lane] + b[lane];
  float o1 = d1 * inv * g[64 + lane] + b[64 + lane];
  h[base + lane]      = o0;
  h[base + 64 + lane] = o1;
  if (hh) {
    ushort i0 = f2bf(o0), i1 = f2bf(o1);
    hh[base + lane] = i0;        hh[base + 64 + lane] = i1;
    hl[base + lane] = f2bf(o0 - bf2f(i0));
    hl[base + 64 + lane] = f2bf(o1 - bf2f(i1));
  }
}

// ---------------- KAN expansion (fp32) — tiny readout head only ----------------
__global__ void expand_f32(const float* __restrict__ v, float* __restrict__ u, int In, int rows) {
  int i = blockIdx.x * 256 + threadIdx.x;
  if (i >= rows * In) return;
  int n = i / In, c = i % In;
  float x = v[(size_t)n * In + c];
  size_t base = (size_t)n * In * 9;
  u[base + c] = silu_f(x);
  float b8[8];
  kan_bases(x, b8);
  float* ub = u + base + In + (size_t)c * 8;
#pragma unroll
  for (int gq = 0; gq < 8; ++gq) ub[gq] = b8[gq];
}

// ---------------- atomic-free pooling, stage 1: per-chunk partials ----------------
__global__ __launch_bounds__(128) void pool_part(
    const float* __restrict__ h, const int* __restrict__ batch,
    float* __restrict__ psum, float* __restrict__ pmax, float* __restrict__ pcnt) {
  __shared__ float sS[NG][HID];
  __shared__ float sM[NG][HID];
  __shared__ int sC[NG];
  int d = threadIdx.x, blk = blockIdx.x;
  const float NEGINF = __uint_as_float(0xff800000u);  // -inf
  for (int i = d; i < NG * HID; i += 128) {
    ((float*)sS)[i] = 0.f;
    ((float*)sM)[i] = NEGINF;
  }
  if (d < NG) sC[d] = 0;
  __syncthreads();
  const int CH = (NN + NCHUNK - 1) / NCHUNK;  // 79
  int n0 = blk * CH, n1 = (n0 + CH < NN) ? n0 + CH : NN;
  for (int n = n0; n < n1; ++n) {
    int g = batch[n];
    float v = h[(size_t)n * HID + d];
    sS[g][d] += v;
    sM[g][d] = fmaxf(sM[g][d], v);
    if (d == 0) sC[g]++;
  }
  __syncthreads();
  for (int i = d; i < NG * HID; i += 128) {
    psum[(size_t)blk * NG * HID + i] = ((float*)sS)[i];
    pmax[(size_t)blk * NG * HID + i] = ((float*)sM)[i];
  }
  if (d < NG) pcnt[blk * NG + d] = (float)sC[d];
}

// ---------------- pooling stage 2 + readout LN ----------------
__global__ __launch_bounds__(256) void pool_final2(
    const float* __restrict__ psum, const float* __restrict__ pmax,
    const float* __restrict__ pcnt, const float* __restrict__ rog,
    const float* __restrict__ rob, float* __restrict__ gvec) {
  int g = blockIdx.x, j = threadIdx.x;
  __shared__ float rb[256];
  float x;
  if (j < HID) {
    float s = 0.f, cn = 0.f;
    for (int c = 0; c < NCHUNK; ++c) {
      s += psum[(size_t)c * NG * HID + g * HID + j];
      cn += pcnt[c * NG + g];
    }
    x = s / fmaxf(cn, 1.f);
  } else {
    float mx = __uint_as_float(0xff800000u);
    for (int c = 0; c < NCHUNK; ++c)
      mx = fmaxf(mx, pmax[(size_t)c * NG * HID + g * HID + (j - HID)]);
    x = (mx > -1e38f) ? mx : 0.f;  // where(isfinite, ., 0)
  }
  rb[j] = x; __syncthreads();
  for (int st = 128; st > 0; st >>= 1) { if (j < st) rb[j] += rb[j + st]; __syncthreads(); }
  float mu = rb[0] * (1.f / 256.f); __syncthreads();
  float d = x - mu;
  rb[j] = d * d; __syncthreads();
  for (int st = 128; st > 0; st >>= 1) { if (j < st) rb[j] += rb[j + st]; __syncthreads(); }
  float var = rb[0] * (1.f / 256.f);
  float inv = 1.f / sqrtf(var + 1e-5f);
  gvec[(size_t)g * 256 + j] = d * inv * rog[j] + rob[j];
}

// ---------------- wave-parallel KAN head: one wave per (graph, output) ----------------
__global__ __launch_bounds__(256) void kan_head_w(
    const float* __restrict__ u, const float* __restrict__ base_w,
    const float* __restrict__ spline_w, const float* __restrict__ scaler,
    float* __restrict__ out, int In, int Out, int npairs) {
  int wid = blockIdx.x * 4 + (threadIdx.x >> 6);
  if (wid >= npairs) return;
  int g = wid / Out, o = wid % Out;
  int lane = threadIdx.x & 63;
  const float* ug = u + (size_t)g * In * 9;
  const float* bw = base_w + (size_t)o * In;
  const float* sp = spline_w + (size_t)o * In * 8;
  const float* sc = scaler + (size_t)o * In;
  float acc = 0.f;
  for (int i = lane; i < In; i += 64) acc = fmaf(ug[i], bw[i], acc);
  const float* us = ug + In;
  for (int k = lane; k < In * 8; k += 64) {
    int i = k >> 3;
    acc = fmaf(us[k], sp[k] * sc[i], acc);
  }
#pragma unroll
  for (int off2 = 32; off2 > 0; off2 >>= 1) acc += __shfl_xor(acc, off2, 64);
  if (lane == 0) out[(size_t)g * Out + o] = acc;
}

// ---------------- launch ----------------
extern "C" void kernel_launch(void* const* d_in, const int* in_sizes, int n_in,
                              void* d_out, int out_size, void* d_ws, size_t ws_size,
                              hipStream_t stream) {
  const float* x         = (const float*)d_in[0];
  const float* edge_attr = (const float*)d_in[1];
  const int*   id_token  = (const int*)  d_in[2];
  const int*   edge_index= (const int*)  d_in[3];
  const int*   edge_type = (const int*)  d_in[4];
  const int*   batch     = (const int*)  d_in[5];
  const float* id_emb    = (const float*)d_in[6];
  const float* inW       = (const float*)d_in[7];
  const float* inb       = (const float*)d_in[8];
  const float* Wl        = (const float*)d_in[9];
  const float* bl        = (const float*)d_in[10];
  const float* Wr        = (const float*)d_in[11];
  const float* br        = (const float*)d_in[12];
  const float* We        = (const float*)d_in[13];
  const float* att       = (const float*)d_in[14];
  const float* gat_bias  = (const float*)d_in[15];
  const float* rel_gate  = (const float*)d_in[16];
  const float* rel_emb   = (const float*)d_in[17];
  const float* ln1g      = (const float*)d_in[18];
  const float* ln1b      = (const float*)d_in[19];
  const float* ln2g      = (const float*)d_in[20];
  const float* ln2b      = (const float*)d_in[21];
  const float* ffn1_base = (const float*)d_in[22];
  const float* ffn1_spl  = (const float*)d_in[23];
  const float* ffn1_sc   = (const float*)d_in[24];
  const float* ffn2_base = (const float*)d_in[25];
  const float* ffn2_spl  = (const float*)d_in[26];
  const float* ffn2_sc   = (const float*)d_in[27];
  const float* rog       = (const float*)d_in[28];
  const float* rob       = (const float*)d_in[29];
  const float* h1_base   = (const float*)d_in[30];
  const float* h1_spl    = (const float*)d_in[31];
  const float* h1_sc     = (const float*)d_in[32];
  const float* h2_base   = (const float*)d_in[33];
  const float* h2_spl    = (const float*)d_in[34];
  const float* h2_sc     = (const float*)d_in[35];
  (void)in_sizes; (void)n_in; (void)out_size; (void)ws_size;

  // ---- workspace carve (256B aligned) ----
  char* wsp = (char*)d_ws;
  size_t off = 0;
  auto carve = [&](size_t bytes) { char* p = wsp + off; off = (off + bytes + 255) & ~(size_t)255; return p; };
  float*    h     = (float*)   carve((size_t)NN * HID * 4);
  ushort*   h_hi  = (ushort*)  carve((size_t)NN * HID * 2);
  ushort*   h_lo  = (ushort*)  carve((size_t)NN * HID * 2);
  float*    hmsg  = (float*)   carve((size_t)NN * HID * 4);
  float*    t1    = (float*)   carve((size_t)NN * FFNH * 4);
  float*    gates = (float*)   carve(NR * 4);
  float*    msgb  = (float*)   carve(HID * 4);
  float*    erel  = (float*)   carve(NR * 512 * 4);
  ushort*   WTh   = (ushort*)  carve((size_t)NL * 2 * 2048 * HID * 2);
  ushort*   WTl   = (ushort*)  carve((size_t)NL * 2 * 2048 * HID * 2);
  float*    blr   = (float*)   carve((size_t)NL * 2 * 2048 * 4);
  ushort*   B1h   = (ushort*)  carve((size_t)FFNH * HID * 9 * 2);
  ushort*   B1l   = (ushort*)  carve((size_t)FFNH * HID * 9 * 2);
  ushort*   B2h   = (ushort*)  carve((size_t)HID * FFNH * 9 * 2);
  ushort*   B2l   = (ushort*)  carve((size_t)HID * FFNH * 9 * 2);
  float*    psum  = (float*)   carve((size_t)NCHUNK * NG * HID * 4);
  float*    pmax  = (float*)   carve((size_t)NCHUNK * NG * HID * 4);
  float*    pcnt  = (float*)   carve((size_t)NCHUNK * NG * 4);
  float*    gvec  = (float*)   carve((size_t)NG * 256 * 4);
  float*    uhead = (float*)   carve((size_t)NG * 256 * 9 * 4);
  float*    thead = (float*)   carve((size_t)NG * HEADH * 4);
  float*    xlr   = (float*)   carve((size_t)NN * 2048 * 4);        // 82 MB
  int*      deg2  = (int*)     carve((size_t)NN * NR * 4);
  int*      in_off2=(int*)     carve((size_t)(NN * NR + 1) * 4);
  int*      cursor2=(int*)     carve((size_t)NN * NR * 4);
  int*      in_e2 = (int*)     carve((size_t)NE * 4);
  int*      in_s2 = (int*)     carve((size_t)NE * 4);

  // ---- relation-sorted CSR build (once; graph static across layers) ----
  fill_zero_i<<<(NN * NR + 255) / 256, 256, 0, stream>>>(deg2, NN * NR);
  csr_count2<<<(NE + 255) / 256, 256, 0, stream>>>(edge_index, edge_type, deg2);
  csr_scan2<<<1, 256, 0, stream>>>(deg2, in_off2, cursor2);
  csr_scatter2<<<(NE + 255) / 256, 256, 0, stream>>>(edge_index, edge_type, cursor2, in_e2, in_s2);

  // ---- weight transpose + split (once per launch) ----
  {
    int total = NL * 2 * 2048 * 128;
    conv_wT2<<<(total + 255) / 256, 256, 0, stream>>>(Wl, Wr, bl, br, WTh, WTl, blr, total);
  }

  // ---- input projection ----
  input_proj<<<NN, 128, 0, stream>>>(x, id_emb, id_token, inW, inb, h, h_hi, h_lo);

  const int MB128 = (NN + 127) / 128;  // 79
  const int MB64  = (NN + 63) / 64;    // 157
  for (int l = 0; l < NL; ++l) {
    layer_prep<<<1, 512, 0, stream>>>(rel_gate, gat_bias, rel_emb, We, l, gates, msgb, erel);
    fill_zero<<<(NN * HID + 255) / 256, 256, 0, stream>>>(hmsg, NN * HID);
    for (int pair = 0; pair < 2; ++pair) {
      int g2 = l * 2 + pair;
      const ushort* WThp = WTh + (size_t)g2 * 2048 * HID;
      const ushort* WTlp = WTl + (size_t)g2 * 2048 * HID;
      const float* blp   = blr + (size_t)g2 * 2048;
      int rbase = pair * 2;
      gemm_bf3<<<dim3(2048 / 64, MB128), 256, 0, stream>>>(h_hi, h_lo, WThp, WTlp, blp, xlr, NN, HID, 2048);
      gat_node4<<<dim3((NN + 3) / 4, 2), 256, 0, stream>>>(
          in_off2, in_e2, in_s2, edge_attr, xlr,
          We + ((size_t)(l * NR + rbase)) * 24 * 512, erel + rbase * 512,
          att + (size_t)(l * NR + rbase) * 512, gates, rbase, hmsg);
    }
    ln128<<<NN, 64, 0, stream>>>(h, hmsg, msgb, ln1g + l * HID, ln1b + l * HID, nullptr, nullptr);

    // ---- KAN FFN1: 128 -> 256 (K = 1152), fused expansion, split-K 3 ----
    build_kan_wT<<<((HID * 9 * FFNH) + 255) / 256, 256, 0, stream>>>(
        ffn1_base + (size_t)l * FFNH * HID, ffn1_spl + (size_t)l * FFNH * HID * 8,
        ffn1_sc + (size_t)l * FFNH * HID, B1h, B1l, HID, FFNH);
    fill_zero<<<(NN * FFNH + 255) / 256, 256, 0, stream>>>(t1, NN * FFNH);
    gemm_kan<128, 3><<<dim3(FFNH / 64, MB128, 3), 256, 0, stream>>>(h, B1h, B1l, t1, NN, HID, FFNH);
    // ---- KAN FFN2: 256 -> 128 (K = 2304), fused expansion, split-K 4 ----
    build_kan_wT<<<((FFNH * 9 * HID) + 255) / 256, 256, 0, stream>>>(
        ffn2_base + (size_t)l * HID * FFNH, ffn2_spl + (size_t)l * HID * FFNH * 8,
        ffn2_sc + (size_t)l * HID * FFNH, B2h, B2l, FFNH, HID);
    fill_zero<<<(NN * HID + 255) / 256, 256, 0, stream>>>(hmsg, NN * HID);
    gemm_kan<64, 4><<<dim3(HID / 64, MB64, 4), 256, 0, stream>>>(t1, B2h, B2l, hmsg, NN, FFNH, HID);
    ln128<<<NN, 64, 0, stream>>>(h, hmsg, nullptr, ln2g + l * HID, ln2b + l * HID, h_hi, h_lo);
  }

  // ---- readout (atomic-free pooling) ----
  pool_part<<<NCHUNK, 128, 0, stream>>>(h, batch, psum, pmax, pcnt);
  pool_final2<<<NG, 256, 0, stream>>>(psum, pmax, pcnt, rog, rob, gvec);
  expand_f32<<<((NG * 256) + 255) / 256, 256, 0, stream>>>(gvec, uhead, 256, NG);
  {
    int npairs = NG * HEADH;  // 4096 waves
    kan_head_w<<<(npairs + 3) / 4, 256, 0, stream>>>(uhead, h1_base, h1_spl, h1_sc, thead, 256, HEADH, npairs);
  }
  expand_f32<<<((NG * HEADH) + 255) / 256, 256, 0, stream>>>(thead, uhead, HEADH, NG);
  {
    int npairs = NG * NCLS;   // 320 waves
    kan_head_w<<<(npairs + 3) / 4, 256, 0, stream>>>(uhead, h2_base, h2_spl, h2_sc, (float*)d_out, HEADH, NCLS, npairs);
  }
}

// Round 11
// 1626.435 us; speedup vs baseline: 2.7390x; 1.0633x over previous
//
#include <hip/hip_runtime.h>
#include <cstdint>
#include <cstddef>

// ---------------- static problem config ----------------
#define NN      10000   // nodes
#define NE      120000  // edges
#define NG      32      // graphs
#define FNODE   64
#define FEDGE   16
#define HID     128
#define NHEADS  4
#define NL      3
#define NR      4
#define IDDIM   32
#define RELDIM  8
#define FFNH    256
#define HEADH   128
#define NCLS    10

#define NCHUNK  128     // pooling stage-1 blocks
#define SCTOT   (NN * NR)            // 40000 scan entries
#define SCBLK   ((SCTOT + 255) / 256)  // 157 scan blocks

typedef __attribute__((ext_vector_type(8))) short short8;
typedef __attribute__((ext_vector_type(4))) float floatx4;

// ---------------- helpers ----------------
__device__ __forceinline__ float silu_f(float x) { return x / (1.f + expf(-x)); }
__device__ __forceinline__ ushort f2bf(float f) {   // round-to-nearest-even bf16
  unsigned u = __float_as_uint(f);
  return (ushort)((u + 0x7FFFu + ((u >> 16) & 1u)) >> 16);
}
__device__ __forceinline__ float bf2f(ushort h) { return __uint_as_float((unsigned)h << 16); }

// Cox–de Boor cubic bases on grid t_j = (j-3)*0.4 - 1 (GRID_SIZE=5, ORDER=3) -> 8 bases
__device__ __forceinline__ void kan_bases(float x, float* out8) {
  float bb[11];
#pragma unroll
  for (int j = 0; j < 11; ++j) {
    float t0 = (j - 3) * 0.4f - 1.f;
    float t1 = (j - 2) * 0.4f - 1.f;
    bb[j] = (x >= t0 && x < t1) ? 1.f : 0.f;
  }
  {
    const float inv = 1.f / 0.4f;
#pragma unroll
    for (int j = 0; j < 10; ++j) {
      float tj = (j - 3) * 0.4f - 1.f, tjp1 = (j - 1) * 0.4f - 1.f;
      bb[j] = ((x - tj) * bb[j] + (tjp1 - x) * bb[j + 1]) * inv;
    }
  }
  {
    const float inv = 1.f / 0.8f;
#pragma unroll
    for (int j = 0; j < 9; ++j) {
      float tj = (j - 3) * 0.4f - 1.f, tjp1 = (j) * 0.4f - 1.f;
      bb[j] = ((x - tj) * bb[j] + (tjp1 - x) * bb[j + 1]) * inv;
    }
  }
  {
    const float inv = 1.f / 1.2000001f;
#pragma unroll
    for (int j = 0; j < 8; ++j) {
      float tj = (j - 3) * 0.4f - 1.f, tjp1 = (j + 1) * 0.4f - 1.f;
      bb[j] = ((x - tj) * bb[j] + (tjp1 - x) * bb[j + 1]) * inv;
    }
  }
#pragma unroll
  for (int j = 0; j < 8; ++j) out8[j] = bb[j];
}

// ---------------- 3-term MFMA GEMM, operands pre-split bf16 hi/lo ----------------
__global__ __launch_bounds__(256) void gemm_bf3(
    const ushort* __restrict__ Ahg, const ushort* __restrict__ Alg,
    const ushort* __restrict__ Bhg, const ushort* __restrict__ Blg,
    const float* __restrict__ bias, float* __restrict__ C,
    int M, int K, int N) {
  constexpr int LDA = 68;
  __shared__ __align__(16) ushort Ah[128 * LDA];
  __shared__ __align__(16) ushort Al[128 * LDA];
  __shared__ __align__(16) ushort Bh[64 * LDA];
  __shared__ __align__(16) ushort Bl[64 * LDA];
  const int tid = threadIdx.x;
  const int lane = tid & 63, wave = tid >> 6;
  const int lrow = lane & 15, quad = lane >> 4;
  const int bm = blockIdx.y * 128, bn = blockIdx.x * 64;
  floatx4 acc[2][4] = {};
  for (int k0 = 0; k0 < K; k0 += 64) {
#pragma unroll
    for (int i = 0; i < 4; ++i) {
      int c = tid + i * 256;
      int row = c >> 3, col8 = c & 7;
      int gr = bm + row;
      uint4 vh = make_uint4(0, 0, 0, 0), vl = make_uint4(0, 0, 0, 0);
      if (gr < M) {
        vh = *(const uint4*)(Ahg + (size_t)gr * K + k0 + col8 * 8);
        vl = *(const uint4*)(Alg + (size_t)gr * K + k0 + col8 * 8);
      }
      *(uint4*)&Ah[row * LDA + col8 * 8] = vh;
      *(uint4*)&Al[row * LDA + col8 * 8] = vl;
    }
#pragma unroll
    for (int i = 0; i < 2; ++i) {
      int c = tid + i * 256;
      int row = c >> 3, col8 = c & 7;
      *(uint4*)&Bh[row * LDA + col8 * 8] = *(const uint4*)(Bhg + (size_t)(bn + row) * K + k0 + col8 * 8);
      *(uint4*)&Bl[row * LDA + col8 * 8] = *(const uint4*)(Blg + (size_t)(bn + row) * K + k0 + col8 * 8);
    }
    __syncthreads();
#pragma unroll
    for (int kk = 0; kk < 64; kk += 32) {
      int kof = kk + quad * 8;
      const int ra0 = (wave * 32 + lrow) * LDA + kof;
      const int ra1 = (wave * 32 + 16 + lrow) * LDA + kof;
      short8 ah0 = *(const short8*)&Ah[ra0];
      short8 ah1 = *(const short8*)&Ah[ra1];
      short8 al0 = *(const short8*)&Al[ra0];
      short8 al1 = *(const short8*)&Al[ra1];
      short8 bh[4], blo[4];
#pragma unroll
      for (int nt = 0; nt < 4; ++nt) {
        int rb = (nt * 16 + lrow) * LDA + kof;
        bh[nt]  = *(const short8*)&Bh[rb];
        blo[nt] = *(const short8*)&Bl[rb];
      }
#pragma unroll
      for (int nt = 0; nt < 4; ++nt) {
        acc[0][nt] = __builtin_amdgcn_mfma_f32_16x16x32_bf16(ah0, bh[nt],  acc[0][nt], 0, 0, 0);
        acc[1][nt] = __builtin_amdgcn_mfma_f32_16x16x32_bf16(ah1, bh[nt],  acc[1][nt], 0, 0, 0);
        acc[0][nt] = __builtin_amdgcn_mfma_f32_16x16x32_bf16(al0, bh[nt],  acc[0][nt], 0, 0, 0);
        acc[1][nt] = __builtin_amdgcn_mfma_f32_16x16x32_bf16(al1, bh[nt],  acc[1][nt], 0, 0, 0);
        acc[0][nt] = __builtin_amdgcn_mfma_f32_16x16x32_bf16(ah0, blo[nt], acc[0][nt], 0, 0, 0);
        acc[1][nt] = __builtin_amdgcn_mfma_f32_16x16x32_bf16(ah1, blo[nt], acc[1][nt], 0, 0, 0);
      }
    }
    __syncthreads();
  }
#pragma unroll
  for (int mt = 0; mt < 2; ++mt) {
#pragma unroll
    for (int nt = 0; nt < 4; ++nt) {
#pragma unroll
      for (int reg = 0; reg < 4; ++reg) {
        int row = bm + wave * 32 + mt * 16 + quad * 4 + reg;
        int col = bn + nt * 16 + lrow;
        if (row < M) {
          float v = acc[mt][nt][reg];
          if (bias) v += bias[col];
          C[(size_t)row * N + col] = v;
        }
      }
    }
  }
}

// ---------------- fused KAN GEMM w/ split-K: C += expand(A) @ BT^T ----------------
template<int BM, int SPLIT>
__global__ __launch_bounds__(256) void gemm_kan(
    const float* __restrict__ A, const ushort* __restrict__ Bhg, const ushort* __restrict__ Blg,
    float* __restrict__ C, int M, int In, int N) {
  const int K = In * 9;
  const int ntiles = K >> 6;
  const int per = (ntiles + SPLIT - 1) / SPLIT;
  const int kt0 = blockIdx.z * per;
  const int kt1 = (kt0 + per < ntiles) ? (kt0 + per) : ntiles;
  constexpr int LDA = 68;
  __shared__ __align__(16) ushort Ah[BM * LDA];
  __shared__ __align__(16) ushort Al[BM * LDA];
  __shared__ __align__(16) ushort Bh[64 * LDA];
  __shared__ __align__(16) ushort Bl[64 * LDA];
  const int tid = threadIdx.x;
  const int lane = tid & 63, wave = tid >> 6;
  const int lrow = lane & 15, quad = lane >> 4;
  const int bm = blockIdx.y * BM, bn = blockIdx.x * 64;
  constexpr int MT = BM / 64;
  floatx4 acc[MT][4] = {};
  for (int kt = kt0; kt < kt1; ++kt) {
    int k0 = kt << 6;
    if (k0 < In) {
#pragma unroll
      for (int i = 0; i < BM / 16; ++i) {
        int c = tid + i * 256;
        int row = c >> 4, col4 = c & 15;
        int gr = bm + row;
        float4 v = make_float4(0.f, 0.f, 0.f, 0.f);
        if (gr < M) v = *(const float4*)(A + (size_t)gr * In + k0 + col4 * 4);
        float vv[4] = {silu_f(v.x), silu_f(v.y), silu_f(v.z), silu_f(v.w)};
        ushort h0 = f2bf(vv[0]), h1 = f2bf(vv[1]), h2 = f2bf(vv[2]), h3 = f2bf(vv[3]);
        ushort l0 = f2bf(vv[0] - bf2f(h0)), l1 = f2bf(vv[1] - bf2f(h1));
        ushort l2 = f2bf(vv[2] - bf2f(h2)), l3 = f2bf(vv[3] - bf2f(h3));
        *(uint2*)&Ah[row * LDA + col4 * 4] =
          make_uint2((unsigned)h0 | ((unsigned)h1 << 16), (unsigned)h2 | ((unsigned)h3 << 16));
        *(uint2*)&Al[row * LDA + col4 * 4] =
          make_uint2((unsigned)l0 | ((unsigned)l1 << 16), (unsigned)l2 | ((unsigned)l3 << 16));
      }
    } else {
      int i0 = (k0 - In) >> 3;
      if (tid < BM * 2) {
        int row = tid >> 1, half = tid & 1;
        int gr = bm + row;
        float4 v = make_float4(0.f, 0.f, 0.f, 0.f);
        if (gr < M) v = *(const float4*)(A + (size_t)gr * In + i0 + half * 4);
        float vv[4] = {v.x, v.y, v.z, v.w};
#pragma unroll
        for (int jj = 0; jj < 4; ++jj) {
          float b8[8];
          kan_bases(vv[jj], b8);
          unsigned hu[4], lu[4];
#pragma unroll
          for (int q = 0; q < 4; ++q) {
            ushort ha = f2bf(b8[2 * q]), hb = f2bf(b8[2 * q + 1]);
            ushort la = f2bf(b8[2 * q] - bf2f(ha)), lb = f2bf(b8[2 * q + 1] - bf2f(hb));
            hu[q] = (unsigned)ha | ((unsigned)hb << 16);
            lu[q] = (unsigned)la | ((unsigned)lb << 16);
          }
          int cbase = (half * 4 + jj) * 8;
          *(uint4*)&Ah[row * LDA + cbase] = make_uint4(hu[0], hu[1], hu[2], hu[3]);
          *(uint4*)&Al[row * LDA + cbase] = make_uint4(lu[0], lu[1], lu[2], lu[3]);
        }
      }
    }
#pragma unroll
    for (int i = 0; i < 2; ++i) {
      int c = tid + i * 256;
      int row = c >> 3, col8 = c & 7;
      *(uint4*)&Bh[row * LDA + col8 * 8] = *(const uint4*)(Bhg + (size_t)(bn + row) * K + k0 + col8 * 8);
      *(uint4*)&Bl[row * LDA + col8 * 8] = *(const uint4*)(Blg + (size_t)(bn + row) * K + k0 + col8 * 8);
    }
    __syncthreads();
#pragma unroll
    for (int kk = 0; kk < 64; kk += 32) {
      int kof = kk + quad * 8;
      short8 ah[MT], al[MT];
#pragma unroll
      for (int mt = 0; mt < MT; ++mt) {
        int ra = (wave * (BM / 4) + mt * 16 + lrow) * LDA + kof;
        ah[mt] = *(const short8*)&Ah[ra];
        al[mt] = *(const short8*)&Al[ra];
      }
      short8 bh[4], blo[4];
#pragma unroll
      for (int nt = 0; nt < 4; ++nt) {
        int rb = (nt * 16 + lrow) * LDA + kof;
        bh[nt]  = *(const short8*)&Bh[rb];
        blo[nt] = *(const short8*)&Bl[rb];
      }
#pragma unroll
      for (int nt = 0; nt < 4; ++nt) {
#pragma unroll
        for (int mt = 0; mt < MT; ++mt) {
          acc[mt][nt] = __builtin_amdgcn_mfma_f32_16x16x32_bf16(ah[mt], bh[nt],  acc[mt][nt], 0, 0, 0);
          acc[mt][nt] = __builtin_amdgcn_mfma_f32_16x16x32_bf16(al[mt], bh[nt],  acc[mt][nt], 0, 0, 0);
          acc[mt][nt] = __builtin_amdgcn_mfma_f32_16x16x32_bf16(ah[mt], blo[nt], acc[mt][nt], 0, 0, 0);
        }
      }
    }
    __syncthreads();
  }
#pragma unroll
  for (int mt = 0; mt < MT; ++mt) {
#pragma unroll
    for (int nt = 0; nt < 4; ++nt) {
#pragma unroll
      for (int reg = 0; reg < 4; ++reg) {
        int row = bm + wave * (BM / 4) + mt * 16 + quad * 4 + reg;
        int col = bn + nt * 16 + lrow;
        if (row < M) atomicAdd(&C[(size_t)row * N + col], acc[mt][nt][reg]);
      }
    }
  }
}

// ---------------- weight transpose+split: relation pairs -> [L*2][2048][128] ----------------
__global__ void conv_wT2(const float* __restrict__ Wl, const float* __restrict__ Wr,
                         const float* __restrict__ bl, const float* __restrict__ br,
                         ushort* __restrict__ WTh, ushort* __restrict__ WTl,
                         float* __restrict__ bout, int total) {
  int i = blockIdx.x * 256 + threadIdx.x;
  if (i >= total) return;
  int g2 = i / (2048 * 128), rem = i % (2048 * 128);
  int n = rem >> 7, k = rem & 127;
  int l = g2 >> 1, pair = g2 & 1;
  int r = pair * 2 + (n >> 10);          // relation within layer
  int nsub = n & 1023;                   // 0..1023 within [Wl|Wr]
  int nn = nsub & 511;
  int g = l * NR + r;
  const float* W = (nsub < 512) ? Wl : Wr;
  float v = W[(size_t)g * 65536 + (size_t)k * 512 + nn];
  ushort hi = f2bf(v);
  WTh[i] = hi;
  WTl[i] = f2bf(v - bf2f(hi));
  if (k == 0) bout[g2 * 2048 + n] = ((nsub < 512) ? bl : br)[g * 512 + nn];
}

// ---------------- build expanded KAN weight, transposed + split ----------------
__global__ void build_kan_wT(const float* __restrict__ base_w, const float* __restrict__ spline_w,
                             const float* __restrict__ scaler,
                             ushort* __restrict__ BTh, ushort* __restrict__ BTl,
                             int In, int Out) {
  int i = blockIdx.x * 256 + threadIdx.x;
  if (i >= In * 9 * Out) return;
  int o = i / (In * 9), k = i % (In * 9);
  float v;
  if (k < In) v = base_w[(size_t)o * In + k];
  else {
    int q = k - In, ii = q >> 3, gq = q & 7;
    v = spline_w[((size_t)o * In + ii) * 8 + gq] * scaler[(size_t)o * In + ii];
  }
  ushort hi = f2bf(v);
  BTh[i] = hi;
  BTl[i] = f2bf(v - bf2f(hi));
}

// ---------------- input projection (fp32 h + hi/lo bf16) ----------------
__global__ __launch_bounds__(128) void input_proj(
    const float* __restrict__ x, const float* __restrict__ id_emb,
    const int* __restrict__ id_token, const float* __restrict__ inW,
    const float* __restrict__ inb, float* __restrict__ h,
    ushort* __restrict__ hh, ushort* __restrict__ hl) {
  int n = blockIdx.x, j = threadIdx.x;
  __shared__ float s[FNODE + IDDIM];
  if (j < FNODE) s[j] = x[(size_t)n * FNODE + j];
  else if (j < FNODE + IDDIM) s[j] = id_emb[(size_t)id_token[n] * IDDIM + (j - FNODE)];
  __syncthreads();
  float acc = inb[j];
#pragma unroll
  for (int k = 0; k < FNODE + IDDIM; ++k) acc = fmaf(s[k], inW[k * HID + j], acc);
  float v = silu_f(acc);
  h[(size_t)n * HID + j] = v;
  ushort hi = f2bf(v);
  hh[(size_t)n * HID + j] = hi;
  hl[(size_t)n * HID + j] = f2bf(v - bf2f(hi));
}

// ---------------- per-layer prep ----------------
__global__ __launch_bounds__(512) void layer_prep(
    const float* __restrict__ rel_gate, const float* __restrict__ gat_bias,
    const float* __restrict__ rel_emb, const float* __restrict__ We, int l,
    float* __restrict__ gates, float* __restrict__ msg_bias, float* __restrict__ erel) {
  int j = threadIdx.x;
  float g[NR]; float mx = -1e30f;
  for (int r = 0; r < NR; ++r) { g[r] = rel_gate[l * NR + r]; mx = fmaxf(mx, g[r]); }
  float s = 0.f;
  for (int r = 0; r < NR; ++r) { g[r] = expf(g[r] - mx); s += g[r]; }
  for (int r = 0; r < NR; ++r) g[r] /= s;
  if (j < NR) gates[j] = g[j];
  if (j < HID) {
    float b = 0.f;
    for (int r = 0; r < NR; ++r) b = fmaf(g[r], gat_bias[((size_t)(l * NR + r)) * HID + j], b);
    msg_bias[j] = b;
  }
  for (int r = 0; r < NR; ++r) {
    const float* Wer = We + ((size_t)(l * NR + r)) * 24 * 512;
    const float* re  = rel_emb + (l * NR + r) * RELDIM;
    float acc = 0.f;
#pragma unroll
    for (int q = 0; q < RELDIM; ++q) acc = fmaf(re[q], Wer[(FEDGE + q) * 512 + j], acc);
    erel[r * 512 + j] = acc;
  }
}

// ---------------- fills ----------------
__global__ void fill_zero(float* __restrict__ p, int n) {
  int i = blockIdx.x * 256 + threadIdx.x;
  if (i < n) p[i] = 0.f;
}
__global__ void fill_zero_i(int* __restrict__ p, int n) {
  int i = blockIdx.x * 256 + threadIdx.x;
  if (i < n) p[i] = 0;
}

// ---------------- relation-sorted CSR build: bins (target, relation) ----------------
__global__ void csr_count2(const int* __restrict__ eidx, const int* __restrict__ etype,
                           int* __restrict__ deg2) {
  int e = blockIdx.x * 256 + threadIdx.x;
  if (e < NE) atomicAdd(&deg2[eidx[NE + e] * NR + etype[e]], 1);
}

// ---- parallel 3-pass scan over deg2[SCTOT] ----
// p1: per-256-tile inclusive scan -> tmp_incl; block totals -> bsum
__global__ __launch_bounds__(256) void scan_p1(const int* __restrict__ deg2,
                                               int* __restrict__ tmp_incl, int* __restrict__ bsum) {
  __shared__ int ps[256];
  int t = threadIdx.x, blk = blockIdx.x;
  int i = blk * 256 + t;
  int v = (i < SCTOT) ? deg2[i] : 0;
  ps[t] = v;
  __syncthreads();
  for (int o = 1; o < 256; o <<= 1) {
    int u = (t >= o) ? ps[t - o] : 0;
    __syncthreads();
    ps[t] += u;
    __syncthreads();
  }
  if (i < SCTOT) tmp_incl[i] = ps[t];
  if (t == 255) bsum[blk] = ps[255];
}
// p2: single small block scans SCBLK (<=256) block sums -> exclusive boff
__global__ __launch_bounds__(256) void scan_p2(const int* __restrict__ bsum, int* __restrict__ boff) {
  __shared__ int ps[256];
  int t = threadIdx.x;
  int v = (t < SCBLK) ? bsum[t] : 0;
  ps[t] = v;
  __syncthreads();
  for (int o = 1; o < 256; o <<= 1) {
    int u = (t >= o) ? ps[t - o] : 0;
    __syncthreads();
    ps[t] += u;
    __syncthreads();
  }
  if (t < SCBLK) boff[t] = ps[t] - v;   // exclusive
}
// p3: write exclusive offsets into in_off2 + cursor2; set sentinel
__global__ __launch_bounds__(256) void scan_p3(const int* __restrict__ deg2,
                                               const int* __restrict__ tmp_incl,
                                               const int* __restrict__ boff,
                                               int* __restrict__ in_off2, int* __restrict__ cursor2) {
  int t = threadIdx.x, blk = blockIdx.x;
  int i = blk * 256 + t;
  if (i < SCTOT) {
    int excl = boff[blk] + tmp_incl[i] - deg2[i];
    in_off2[i] = excl;
    cursor2[i] = excl;
  }
  if (i == 0) in_off2[SCTOT] = NE;  // total edges is a static constant
}

__global__ void csr_scatter2(const int* __restrict__ eidx, const int* __restrict__ etype,
                             int* __restrict__ cursor2,
                             int* __restrict__ in_e2, int* __restrict__ in_s2) {
  int e = blockIdx.x * 256 + threadIdx.x;
  if (e < NE) {
    int pos = atomicAdd(&cursor2[eidx[NE + e] * NR + etype[e]], 1);
    in_e2[pos] = e;
    in_s2[pos] = eidx[e];
  }
}

// ---------------- node-centric GAT, relation-sorted CSR, 4 nodes/block ----------------
// xlr [NN,2048]: for r_sub: xl at [rs*1024, +512), xr at [rs*1024+512, +512).
// hmsg += gates[r]*0.25*agg via atomicAdd (hmsg pre-zeroed).
__global__ __launch_bounds__(256) void gat_node4(
    const int* __restrict__ in_off2, const int* __restrict__ in_e2, const int* __restrict__ in_s2,
    const float* __restrict__ eattr, const float* __restrict__ xlr,
    const float* __restrict__ We_base, const float* __restrict__ erel_base,
    const float* __restrict__ att_base, const float* __restrict__ gates,
    int rbase, float* __restrict__ hmsg) {
  __shared__ float WeL[16][512];
  __shared__ float attL[512];
  __shared__ float erelL[512];
  int tid = threadIdx.x;
  int rs = blockIdx.y;
  int r = rbase + rs;
  const float* We_r = We_base + (size_t)rs * 24 * 512;
  for (int i = tid; i < 16 * 512; i += 256) WeL[i >> 9][i & 511] = We_r[i];
  for (int i = tid; i < 512; i += 256) {
    attL[i] = att_base[rs * 512 + i];
    erelL[i] = erel_base[rs * 512 + i];
  }
  __syncthreads();
  float gr = gates[r] * 0.25f;
  int lane = tid & 63, wave = tid >> 6;
  int n = blockIdx.x * 4 + wave;
  if (n >= NN) return;
  int roff = rs * 1024;
  float xr[8];
  const float* xrb = xlr + (size_t)n * 2048 + roff + 512;
#pragma unroll
  for (int h = 0; h < 4; ++h) {
    xr[h * 2]     = xrb[h * 128 + lane];
    xr[h * 2 + 1] = xrb[h * 128 + 64 + lane];
  }
  float m[4] = {-1e30f, -1e30f, -1e30f, -1e30f};
  float lsum[4] = {0.f, 0.f, 0.f, 0.f};
  float acc[8] = {0.f, 0.f, 0.f, 0.f, 0.f, 0.f, 0.f, 0.f};
  int e0 = in_off2[n * NR + r], e1 = in_off2[n * NR + r + 1];
  int e_nxt = 0, s_nxt = 0;
  if (e0 < e1) { e_nxt = in_e2[e0]; s_nxt = in_s2[e0]; }
  for (int ii = e0; ii < e1; ++ii) {
    int e = e_nxt, s = s_nxt;
    if (ii + 1 < e1) { e_nxt = in_e2[ii + 1]; s_nxt = in_s2[ii + 1]; }
    const float* xls = xlr + (size_t)s * 2048 + roff;
    float ea[16];
#pragma unroll
    for (int k = 0; k < 16; ++k) ea[k] = eattr[(size_t)e * 16 + k];
    float xlv[8], p[4];
#pragma unroll
    for (int h = 0; h < 4; ++h) {
      float ph = 0.f;
#pragma unroll
      for (int half = 0; half < 2; ++half) {
        int idx = h * 128 + half * 64 + lane;
        float xv = xls[idx];
        xlv[h * 2 + half] = xv;
        float et = erelL[idx];
#pragma unroll
        for (int k = 0; k < 16; ++k) et = fmaf(ea[k], WeL[k][idx], et);
        float z = xv + xr[h * 2 + half] + et;
        z = (z > 0.f) ? z : 0.2f * z;  // leaky_relu 0.2
        ph = fmaf(z, attL[idx], ph);
      }
      p[h] = ph;
    }
#pragma unroll
    for (int h = 0; h < 4; ++h) {
#pragma unroll
      for (int o = 32; o > 0; o >>= 1) p[h] += __shfl_xor(p[h], o, 64);
    }
#pragma unroll
    for (int h = 0; h < 4; ++h) {
      float sh = p[h];
      float mn = fmaxf(m[h], sh);
      float sc = expf(m[h] - mn);
      float we = expf(sh - mn);
      m[h] = mn;
      lsum[h] = lsum[h] * sc + we;
      acc[h * 2]     = acc[h * 2] * sc + we * xlv[h * 2];
      acc[h * 2 + 1] = acc[h * 2 + 1] * sc + we * xlv[h * 2 + 1];
    }
  }
  float o0 = 0.f, o1 = 0.f;
#pragma unroll
  for (int h = 0; h < 4; ++h) {
    float inv = 1.f / fmaxf(lsum[h], 1e-16f);
    o0 += acc[h * 2] * inv;
    o1 += acc[h * 2 + 1] * inv;
  }
  size_t base = (size_t)n * HID;
  atomicAdd(&hmsg[base + lane],      gr * o0);
  atomicAdd(&hmsg[base + 64 + lane], gr * o1);
}

// ---------------- LayerNorm over 128 dims (optionally emits hi/lo bf16) ----------------
__global__ __launch_bounds__(64) void ln128(
    float* __restrict__ h, const float* __restrict__ add, const float* __restrict__ bvec,
    const float* __restrict__ g, const float* __restrict__ b,
    ushort* __restrict__ hh, ushort* __restrict__ hl) {
  int n = blockIdx.x, lane = threadIdx.x;
  size_t base = (size_t)n * HID;
  float x0 = h[base + lane] + add[base + lane];
  float x1 = h[base + 64 + lane] + add[base + 64 + lane];
  if (bvec) { x0 += bvec[lane]; x1 += bvec[64 + lane]; }
  float s = x0 + x1;
#pragma unroll
  for (int m = 32; m > 0; m >>= 1) s += __shfl_xor(s, m, 64);
  float mu = s * (1.f / 128.f);
  float d0 = x0 - mu, d1 = x1 - mu;
  float q = d0 * d0 + d1 * d1;
#pragma unroll
  for (int m = 32; m > 0; m >>= 1) q += __shfl_xor(q, m, 64);
  float inv = 1.f / sqrtf(q * (1.f / 128.f) + 1e-5f);
  float o0 = d0 * inv * g[lane] + b[lane];
  float o1 = d1 * inv * g[64 + lane] + b[64 + lane];
  h[base + lane]      = o0;
  h[base + 64 + lane] = o1;
  if (hh) {
    ushort i0 = f2bf(o0), i1 = f2bf(o1);
    hh[base + lane] = i0;        hh[base + 64 + lane] = i1;
    hl[base + lane] = f2bf(o0 - bf2f(i0));
    hl[base + 64 + lane] = f2bf(o1 - bf2f(i1));
  }
}

// ---------------- KAN expansion (fp32) — tiny readout head only ----------------
__global__ void expand_f32(const float* __restrict__ v, float* __restrict__ u, int In, int rows) {
  int i = blockIdx.x * 256 + threadIdx.x;
  if (i >= rows * In) return;
  int n = i / In, c = i % In;
  float x = v[(size_t)n * In + c];
  size_t base = (size_t)n * In * 9;
  u[base + c] = silu_f(x);
  float b8[8];
  kan_bases(x, b8);
  float* ub = u + base + In + (size_t)c * 8;
#pragma unroll
  for (int gq = 0; gq < 8; ++gq) ub[gq] = b8[gq];
}

// ---------------- atomic-free pooling, stage 1: per-chunk partials ----------------
__global__ __launch_bounds__(128) void pool_part(
    const float* __restrict__ h, const int* __restrict__ batch,
    float* __restrict__ psum, float* __restrict__ pmax, float* __restrict__ pcnt) {
  __shared__ float sS[NG][HID];
  __shared__ float sM[NG][HID];
  __shared__ int sC[NG];
  int d = threadIdx.x, blk = blockIdx.x;
  const float NEGINF = __uint_as_float(0xff800000u);  // -inf
  for (int i = d; i < NG * HID; i += 128) {
    ((float*)sS)[i] = 0.f;
    ((float*)sM)[i] = NEGINF;
  }
  if (d < NG) sC[d] = 0;
  __syncthreads();
  const int CH = (NN + NCHUNK - 1) / NCHUNK;  // 79
  int n0 = blk * CH, n1 = (n0 + CH < NN) ? n0 + CH : NN;
  for (int n = n0; n < n1; ++n) {
    int g = batch[n];
    float v = h[(size_t)n * HID + d];
    sS[g][d] += v;
    sM[g][d] = fmaxf(sM[g][d], v);
    if (d == 0) sC[g]++;
  }
  __syncthreads();
  for (int i = d; i < NG * HID; i += 128) {
    psum[(size_t)blk * NG * HID + i] = ((float*)sS)[i];
    pmax[(size_t)blk * NG * HID + i] = ((float*)sM)[i];
  }
  if (d < NG) pcnt[blk * NG + d] = (float)sC[d];
}

// ---------------- pooling stage 2 + readout LN ----------------
__global__ __launch_bounds__(256) void pool_final2(
    const float* __restrict__ psum, const float* __restrict__ pmax,
    const float* __restrict__ pcnt, const float* __restrict__ rog,
    const float* __restrict__ rob, float* __restrict__ gvec) {
  int g = blockIdx.x, j = threadIdx.x;
  __shared__ float rb[256];
  float x;
  if (j < HID) {
    float s = 0.f, cn = 0.f;
    for (int c = 0; c < NCHUNK; ++c) {
      s += psum[(size_t)c * NG * HID + g * HID + j];
      cn += pcnt[c * NG + g];
    }
    x = s / fmaxf(cn, 1.f);
  } else {
    float mx = __uint_as_float(0xff800000u);
    for (int c = 0; c < NCHUNK; ++c)
      mx = fmaxf(mx, pmax[(size_t)c * NG * HID + g * HID + (j - HID)]);
    x = (mx > -1e38f) ? mx : 0.f;  // where(isfinite, ., 0)
  }
  rb[j] = x; __syncthreads();
  for (int st = 128; st > 0; st >>= 1) { if (j < st) rb[j] += rb[j + st]; __syncthreads(); }
  float mu = rb[0] * (1.f / 256.f); __syncthreads();
  float d = x - mu;
  rb[j] = d * d; __syncthreads();
  for (int st = 128; st > 0; st >>= 1) { if (j < st) rb[j] += rb[j + st]; __syncthreads(); }
  float var = rb[0] * (1.f / 256.f);
  float inv = 1.f / sqrtf(var + 1e-5f);
  gvec[(size_t)g * 256 + j] = d * inv * rog[j] + rob[j];
}

// ---------------- wave-parallel KAN head: one wave per (graph, output) ----------------
__global__ __launch_bounds__(256) void kan_head_w(
    const float* __restrict__ u, const float* __restrict__ base_w,
    const float* __restrict__ spline_w, const float* __restrict__ scaler,
    float* __restrict__ out, int In, int Out, int npairs) {
  int wid = blockIdx.x * 4 + (threadIdx.x >> 6);
  if (wid >= npairs) return;
  int g = wid / Out, o = wid % Out;
  int lane = threadIdx.x & 63;
  const float* ug = u + (size_t)g * In * 9;
  const float* bw = base_w + (size_t)o * In;
  const float* sp = spline_w + (size_t)o * In * 8;
  const float* sc = scaler + (size_t)o * In;
  float acc = 0.f;
  for (int i = lane; i < In; i += 64) acc = fmaf(ug[i], bw[i], acc);
  const float* us = ug + In;
  for (int k = lane; k < In * 8; k += 64) {
    int i = k >> 3;
    acc = fmaf(us[k], sp[k] * sc[i], acc);
  }
#pragma unroll
  for (int off2 = 32; off2 > 0; off2 >>= 1) acc += __shfl_xor(acc, off2, 64);
  if (lane == 0) out[(size_t)g * Out + o] = acc;
}

// ---------------- launch ----------------
extern "C" void kernel_launch(void* const* d_in, const int* in_sizes, int n_in,
                              void* d_out, int out_size, void* d_ws, size_t ws_size,
                              hipStream_t stream) {
  const float* x         = (const float*)d_in[0];
  const float* edge_attr = (const float*)d_in[1];
  const int*   id_token  = (const int*)  d_in[2];
  const int*   edge_index= (const int*)  d_in[3];
  const int*   edge_type = (const int*)  d_in[4];
  const int*   batch     = (const int*)  d_in[5];
  const float* id_emb    = (const float*)d_in[6];
  const float* inW       = (const float*)d_in[7];
  const float* inb       = (const float*)d_in[8];
  const float* Wl        = (const float*)d_in[9];
  const float* bl        = (const float*)d_in[10];
  const float* Wr        = (const float*)d_in[11];
  const float* br        = (const float*)d_in[12];
  const float* We        = (const float*)d_in[13];
  const float* att       = (const float*)d_in[14];
  const float* gat_bias  = (const float*)d_in[15];
  const float* rel_gate  = (const float*)d_in[16];
  const float* rel_emb   = (const float*)d_in[17];
  const float* ln1g      = (const float*)d_in[18];
  const float* ln1b      = (const float*)d_in[19];
  const float* ln2g      = (const float*)d_in[20];
  const float* ln2b      = (const float*)d_in[21];
  const float* ffn1_base = (const float*)d_in[22];
  const float* ffn1_spl  = (const float*)d_in[23];
  const float* ffn1_sc   = (const float*)d_in[24];
  const float* ffn2_base = (const float*)d_in[25];
  const float* ffn2_spl  = (const float*)d_in[26];
  const float* ffn2_sc   = (const float*)d_in[27];
  const float* rog       = (const float*)d_in[28];
  const float* rob       = (const float*)d_in[29];
  const float* h1_base   = (const float*)d_in[30];
  const float* h1_spl    = (const float*)d_in[31];
  const float* h1_sc     = (const float*)d_in[32];
  const float* h2_base   = (const float*)d_in[33];
  const float* h2_spl    = (const float*)d_in[34];
  const float* h2_sc     = (const float*)d_in[35];
  (void)in_sizes; (void)n_in; (void)out_size; (void)ws_size;

  // ---- workspace carve (256B aligned) ----
  char* wsp = (char*)d_ws;
  size_t off = 0;
  auto carve = [&](size_t bytes) { char* p = wsp + off; off = (off + bytes + 255) & ~(size_t)255; return p; };
  float*    h     = (float*)   carve((size_t)NN * HID * 4);
  ushort*   h_hi  = (ushort*)  carve((size_t)NN * HID * 2);
  ushort*   h_lo  = (ushort*)  carve((size_t)NN * HID * 2);
  float*    hmsg  = (float*)   carve((size_t)NN * HID * 4);
  float*    t1    = (float*)   carve((size_t)NN * FFNH * 4);
  float*    gates = (float*)   carve(NR * 4);
  float*    msgb  = (float*)   carve(HID * 4);
  float*    erel  = (float*)   carve(NR * 512 * 4);
  ushort*   WTh   = (ushort*)  carve((size_t)NL * 2 * 2048 * HID * 2);
  ushort*   WTl   = (ushort*)  carve((size_t)NL * 2 * 2048 * HID * 2);
  float*    blr   = (float*)   carve((size_t)NL * 2 * 2048 * 4);
  ushort*   B1h   = (ushort*)  carve((size_t)FFNH * HID * 9 * 2);
  ushort*   B1l   = (ushort*)  carve((size_t)FFNH * HID * 9 * 2);
  ushort*   B2h   = (ushort*)  carve((size_t)HID * FFNH * 9 * 2);
  ushort*   B2l   = (ushort*)  carve((size_t)HID * FFNH * 9 * 2);
  float*    psum  = (float*)   carve((size_t)NCHUNK * NG * HID * 4);
  float*    pmax  = (float*)   carve((size_t)NCHUNK * NG * HID * 4);
  float*    pcnt  = (float*)   carve((size_t)NCHUNK * NG * 4);
  float*    gvec  = (float*)   carve((size_t)NG * 256 * 4);
  float*    uhead = (float*)   carve((size_t)NG * 256 * 9 * 4);
  float*    thead = (float*)   carve((size_t)NG * HEADH * 4);
  float*    xlr   = (float*)   carve((size_t)NN * 2048 * 4);        // 82 MB
  int*      deg2  = (int*)     carve((size_t)SCTOT * 4);
  int*      in_off2=(int*)     carve((size_t)(SCTOT + 1) * 4);
  int*      cursor2=(int*)     carve((size_t)SCTOT * 4);
  int*      tmp_incl=(int*)    carve((size_t)SCTOT * 4);
  int*      bsum  = (int*)     carve((size_t)SCBLK * 4);
  int*      boff  = (int*)     carve((size_t)SCBLK * 4);
  int*      in_e2 = (int*)     carve((size_t)NE * 4);
  int*      in_s2 = (int*)     carve((size_t)NE * 4);

  // ---- relation-sorted CSR build (once; graph static across layers) ----
  fill_zero_i<<<(SCTOT + 255) / 256, 256, 0, stream>>>(deg2, SCTOT);
  csr_count2<<<(NE + 255) / 256, 256, 0, stream>>>(edge_index, edge_type, deg2);
  scan_p1<<<SCBLK, 256, 0, stream>>>(deg2, tmp_incl, bsum);
  scan_p2<<<1, 256, 0, stream>>>(bsum, boff);
  scan_p3<<<SCBLK, 256, 0, stream>>>(deg2, tmp_incl, boff, in_off2, cursor2);
  csr_scatter2<<<(NE + 255) / 256, 256, 0, stream>>>(edge_index, edge_type, cursor2, in_e2, in_s2);

  // ---- weight transpose + split (once per launch) ----
  {
    int total = NL * 2 * 2048 * 128;
    conv_wT2<<<(total + 255) / 256, 256, 0, stream>>>(Wl, Wr, bl, br, WTh, WTl, blr, total);
  }

  // ---- input projection ----
  input_proj<<<NN, 128, 0, stream>>>(x, id_emb, id_token, inW, inb, h, h_hi, h_lo);

  const int MB128 = (NN + 127) / 128;  // 79
  const int MB64  = (NN + 63) / 64;    // 157
  for (int l = 0; l < NL; ++l) {
    layer_prep<<<1, 512, 0, stream>>>(rel_gate, gat_bias, rel_emb, We, l, gates, msgb, erel);
    fill_zero<<<(NN * HID + 255) / 256, 256, 0, stream>>>(hmsg, NN * HID);
    for (int pair = 0; pair < 2; ++pair) {
      int g2 = l * 2 + pair;
      const ushort* WThp = WTh + (size_t)g2 * 2048 * HID;
      const ushort* WTlp = WTl + (size_t)g2 * 2048 * HID;
      const float* blp   = blr + (size_t)g2 * 2048;
      int rbase = pair * 2;
      gemm_bf3<<<dim3(2048 / 64, MB128), 256, 0, stream>>>(h_hi, h_lo, WThp, WTlp, blp, xlr, NN, HID, 2048);
      gat_node4<<<dim3((NN + 3) / 4, 2), 256, 0, stream>>>(
          in_off2, in_e2, in_s2, edge_attr, xlr,
          We + ((size_t)(l * NR + rbase)) * 24 * 512, erel + rbase * 512,
          att + (size_t)(l * NR + rbase) * 512, gates, rbase, hmsg);
    }
    ln128<<<NN, 64, 0, stream>>>(h, hmsg, msgb, ln1g + l * HID, ln1b + l * HID, nullptr, nullptr);

    // ---- KAN FFN1: 128 -> 256 (K = 1152), fused expansion, split-K 3 ----
    build_kan_wT<<<((HID * 9 * FFNH) + 255) / 256, 256, 0, stream>>>(
        ffn1_base + (size_t)l * FFNH * HID, ffn1_spl + (size_t)l * FFNH * HID * 8,
        ffn1_sc + (size_t)l * FFNH * HID, B1h, B1l, HID, FFNH);
    fill_zero<<<(NN * FFNH + 255) / 256, 256, 0, stream>>>(t1, NN * FFNH);
    gemm_kan<128, 3><<<dim3(FFNH / 64, MB128, 3), 256, 0, stream>>>(h, B1h, B1l, t1, NN, HID, FFNH);
    // ---- KAN FFN2: 256 -> 128 (K = 2304), fused expansion, split-K 4 ----
    build_kan_wT<<<((FFNH * 9 * HID) + 255) / 256, 256, 0, stream>>>(
        ffn2_base + (size_t)l * HID * FFNH, ffn2_spl + (size_t)l * HID * FFNH * 8,
        ffn2_sc + (size_t)l * HID * FFNH, B2h, B2l, FFNH, HID);
    fill_zero<<<(NN * HID + 255) / 256, 256, 0, stream>>>(hmsg, NN * HID);
    gemm_kan<64, 4><<<dim3(HID / 64, MB64, 4), 256, 0, stream>>>(t1, B2h, B2l, hmsg, NN, FFNH, HID);
    ln128<<<NN, 64, 0, stream>>>(h, hmsg, nullptr, ln2g + l * HID, ln2b + l * HID, h_hi, h_lo);
  }

  // ---- readout (atomic-free pooling) ----
  pool_part<<<NCHUNK, 128, 0, stream>>>(h, batch, psum, pmax, pcnt);
  pool_final2<<<NG, 256, 0, stream>>>(psum, pmax, pcnt, rog, rob, gvec);
  expand_f32<<<((NG * 256) + 255) / 256, 256, 0, stream>>>(gvec, uhead, 256, NG);
  {
    int npairs = NG * HEADH;  // 4096 waves
    kan_head_w<<<(npairs + 3) / 4, 256, 0, stream>>>(uhead, h1_base, h1_spl, h1_sc, thead, 256, HEADH, npairs);
  }
  expand_f32<<<((NG * HEADH) + 255) / 256, 256, 0, stream>>>(thead, uhead, HEADH, NG);
  {
    int npairs = NG * NCLS;   // 320 waves
    kan_head_w<<<(npairs + 3) / 4, 256, 0, stream>>>(uhead, h2_base, h2_spl, h2_sc, (float*)d_out, HEADH, NCLS, npairs);
  }
}

// Round 12
// 1593.416 us; speedup vs baseline: 2.7958x; 1.0207x over previous
//
#include <hip/hip_runtime.h>
#include <cstdint>
#include <cstddef>

// ---------------- static problem config ----------------
#define NN      10000   // nodes
#define NE      120000  // edges
#define NG      32      // graphs
#define FNODE   64
#define FEDGE   16
#define HID     128
#define NHEADS  4
#define NL      3
#define NR      4
#define IDDIM   32
#define RELDIM  8
#define FFNH    256
#define HEADH   128
#define NCLS    10

#define NCHUNK  128     // pooling stage-1 blocks
#define SCTOT   (NN * NR)            // 40000 scan entries
#define SCBLK   ((SCTOT + 255) / 256)  // 157 scan blocks

typedef __attribute__((ext_vector_type(8))) short short8;
typedef __attribute__((ext_vector_type(4))) float floatx4;

// ---------------- helpers ----------------
__device__ __forceinline__ float silu_f(float x) { return x / (1.f + expf(-x)); }
__device__ __forceinline__ ushort f2bf(float f) {   // round-to-nearest-even bf16
  unsigned u = __float_as_uint(f);
  return (ushort)((u + 0x7FFFu + ((u >> 16) & 1u)) >> 16);
}
__device__ __forceinline__ float bf2f(ushort h) { return __uint_as_float((unsigned)h << 16); }

// Cox–de Boor cubic bases on grid t_j = (j-3)*0.4 - 1 (GRID_SIZE=5, ORDER=3) -> 8 bases
__device__ __forceinline__ void kan_bases(float x, float* out8) {
  float bb[11];
#pragma unroll
  for (int j = 0; j < 11; ++j) {
    float t0 = (j - 3) * 0.4f - 1.f;
    float t1 = (j - 2) * 0.4f - 1.f;
    bb[j] = (x >= t0 && x < t1) ? 1.f : 0.f;
  }
  {
    const float inv = 1.f / 0.4f;
#pragma unroll
    for (int j = 0; j < 10; ++j) {
      float tj = (j - 3) * 0.4f - 1.f, tjp1 = (j - 1) * 0.4f - 1.f;
      bb[j] = ((x - tj) * bb[j] + (tjp1 - x) * bb[j + 1]) * inv;
    }
  }
  {
    const float inv = 1.f / 0.8f;
#pragma unroll
    for (int j = 0; j < 9; ++j) {
      float tj = (j - 3) * 0.4f - 1.f, tjp1 = (j) * 0.4f - 1.f;
      bb[j] = ((x - tj) * bb[j] + (tjp1 - x) * bb[j + 1]) * inv;
    }
  }
  {
    const float inv = 1.f / 1.2000001f;
#pragma unroll
    for (int j = 0; j < 8; ++j) {
      float tj = (j - 3) * 0.4f - 1.f, tjp1 = (j + 1) * 0.4f - 1.f;
      bb[j] = ((x - tj) * bb[j] + (tjp1 - x) * bb[j + 1]) * inv;
    }
  }
#pragma unroll
  for (int j = 0; j < 8; ++j) out8[j] = bb[j];
}

// ---------------- 3-term MFMA GEMM, operands pre-split bf16 hi/lo ----------------
__global__ __launch_bounds__(256) void gemm_bf3(
    const ushort* __restrict__ Ahg, const ushort* __restrict__ Alg,
    const ushort* __restrict__ Bhg, const ushort* __restrict__ Blg,
    const float* __restrict__ bias, float* __restrict__ C,
    int M, int K, int N) {
  constexpr int LDA = 68;
  __shared__ __align__(16) ushort Ah[128 * LDA];
  __shared__ __align__(16) ushort Al[128 * LDA];
  __shared__ __align__(16) ushort Bh[64 * LDA];
  __shared__ __align__(16) ushort Bl[64 * LDA];
  const int tid = threadIdx.x;
  const int lane = tid & 63, wave = tid >> 6;
  const int lrow = lane & 15, quad = lane >> 4;
  const int bm = blockIdx.y * 128, bn = blockIdx.x * 64;
  floatx4 acc[2][4] = {};
  for (int k0 = 0; k0 < K; k0 += 64) {
#pragma unroll
    for (int i = 0; i < 4; ++i) {
      int c = tid + i * 256;
      int row = c >> 3, col8 = c & 7;
      int gr = bm + row;
      uint4 vh = make_uint4(0, 0, 0, 0), vl = make_uint4(0, 0, 0, 0);
      if (gr < M) {
        vh = *(const uint4*)(Ahg + (size_t)gr * K + k0 + col8 * 8);
        vl = *(const uint4*)(Alg + (size_t)gr * K + k0 + col8 * 8);
      }
      *(uint4*)&Ah[row * LDA + col8 * 8] = vh;
      *(uint4*)&Al[row * LDA + col8 * 8] = vl;
    }
#pragma unroll
    for (int i = 0; i < 2; ++i) {
      int c = tid + i * 256;
      int row = c >> 3, col8 = c & 7;
      *(uint4*)&Bh[row * LDA + col8 * 8] = *(const uint4*)(Bhg + (size_t)(bn + row) * K + k0 + col8 * 8);
      *(uint4*)&Bl[row * LDA + col8 * 8] = *(const uint4*)(Blg + (size_t)(bn + row) * K + k0 + col8 * 8);
    }
    __syncthreads();
#pragma unroll
    for (int kk = 0; kk < 64; kk += 32) {
      int kof = kk + quad * 8;
      const int ra0 = (wave * 32 + lrow) * LDA + kof;
      const int ra1 = (wave * 32 + 16 + lrow) * LDA + kof;
      short8 ah0 = *(const short8*)&Ah[ra0];
      short8 ah1 = *(const short8*)&Ah[ra1];
      short8 al0 = *(const short8*)&Al[ra0];
      short8 al1 = *(const short8*)&Al[ra1];
      short8 bh[4], blo[4];
#pragma unroll
      for (int nt = 0; nt < 4; ++nt) {
        int rb = (nt * 16 + lrow) * LDA + kof;
        bh[nt]  = *(const short8*)&Bh[rb];
        blo[nt] = *(const short8*)&Bl[rb];
      }
#pragma unroll
      for (int nt = 0; nt < 4; ++nt) {
        acc[0][nt] = __builtin_amdgcn_mfma_f32_16x16x32_bf16(ah0, bh[nt],  acc[0][nt], 0, 0, 0);
        acc[1][nt] = __builtin_amdgcn_mfma_f32_16x16x32_bf16(ah1, bh[nt],  acc[1][nt], 0, 0, 0);
        acc[0][nt] = __builtin_amdgcn_mfma_f32_16x16x32_bf16(al0, bh[nt],  acc[0][nt], 0, 0, 0);
        acc[1][nt] = __builtin_amdgcn_mfma_f32_16x16x32_bf16(al1, bh[nt],  acc[1][nt], 0, 0, 0);
        acc[0][nt] = __builtin_amdgcn_mfma_f32_16x16x32_bf16(ah0, blo[nt], acc[0][nt], 0, 0, 0);
        acc[1][nt] = __builtin_amdgcn_mfma_f32_16x16x32_bf16(ah1, blo[nt], acc[1][nt], 0, 0, 0);
      }
    }
    __syncthreads();
  }
#pragma unroll
  for (int mt = 0; mt < 2; ++mt) {
#pragma unroll
    for (int nt = 0; nt < 4; ++nt) {
#pragma unroll
      for (int reg = 0; reg < 4; ++reg) {
        int row = bm + wave * 32 + mt * 16 + quad * 4 + reg;
        int col = bn + nt * 16 + lrow;
        if (row < M) {
          float v = acc[mt][nt][reg];
          if (bias) v += bias[col];
          C[(size_t)row * N + col] = v;
        }
      }
    }
  }
}

// ---------------- fused KAN GEMM w/ split-K: C += expand(A) @ BT^T ----------------
template<int BM, int SPLIT>
__global__ __launch_bounds__(256) void gemm_kan(
    const float* __restrict__ A, const ushort* __restrict__ Bhg, const ushort* __restrict__ Blg,
    float* __restrict__ C, int M, int In, int N) {
  const int K = In * 9;
  const int ntiles = K >> 6;
  const int per = (ntiles + SPLIT - 1) / SPLIT;
  const int kt0 = blockIdx.z * per;
  const int kt1 = (kt0 + per < ntiles) ? (kt0 + per) : ntiles;
  constexpr int LDA = 68;
  __shared__ __align__(16) ushort Ah[BM * LDA];
  __shared__ __align__(16) ushort Al[BM * LDA];
  __shared__ __align__(16) ushort Bh[64 * LDA];
  __shared__ __align__(16) ushort Bl[64 * LDA];
  const int tid = threadIdx.x;
  const int lane = tid & 63, wave = tid >> 6;
  const int lrow = lane & 15, quad = lane >> 4;
  const int bm = blockIdx.y * BM, bn = blockIdx.x * 64;
  constexpr int MT = BM / 64;
  floatx4 acc[MT][4] = {};
  for (int kt = kt0; kt < kt1; ++kt) {
    int k0 = kt << 6;
    if (k0 < In) {
#pragma unroll
      for (int i = 0; i < BM / 16; ++i) {
        int c = tid + i * 256;
        int row = c >> 4, col4 = c & 15;
        int gr = bm + row;
        float4 v = make_float4(0.f, 0.f, 0.f, 0.f);
        if (gr < M) v = *(const float4*)(A + (size_t)gr * In + k0 + col4 * 4);
        float vv[4] = {silu_f(v.x), silu_f(v.y), silu_f(v.z), silu_f(v.w)};
        ushort h0 = f2bf(vv[0]), h1 = f2bf(vv[1]), h2 = f2bf(vv[2]), h3 = f2bf(vv[3]);
        ushort l0 = f2bf(vv[0] - bf2f(h0)), l1 = f2bf(vv[1] - bf2f(h1));
        ushort l2 = f2bf(vv[2] - bf2f(h2)), l3 = f2bf(vv[3] - bf2f(h3));
        *(uint2*)&Ah[row * LDA + col4 * 4] =
          make_uint2((unsigned)h0 | ((unsigned)h1 << 16), (unsigned)h2 | ((unsigned)h3 << 16));
        *(uint2*)&Al[row * LDA + col4 * 4] =
          make_uint2((unsigned)l0 | ((unsigned)l1 << 16), (unsigned)l2 | ((unsigned)l3 << 16));
      }
    } else {
      int i0 = (k0 - In) >> 3;
      if (tid < BM * 2) {
        int row = tid >> 1, half = tid & 1;
        int gr = bm + row;
        float4 v = make_float4(0.f, 0.f, 0.f, 0.f);
        if (gr < M) v = *(const float4*)(A + (size_t)gr * In + i0 + half * 4);
        float vv[4] = {v.x, v.y, v.z, v.w};
#pragma unroll
        for (int jj = 0; jj < 4; ++jj) {
          float b8[8];
          kan_bases(vv[jj], b8);
          unsigned hu[4], lu[4];
#pragma unroll
          for (int q = 0; q < 4; ++q) {
            ushort ha = f2bf(b8[2 * q]), hb = f2bf(b8[2 * q + 1]);
            ushort la = f2bf(b8[2 * q] - bf2f(ha)), lb = f2bf(b8[2 * q + 1] - bf2f(hb));
            hu[q] = (unsigned)ha | ((unsigned)hb << 16);
            lu[q] = (unsigned)la | ((unsigned)lb << 16);
          }
          int cbase = (half * 4 + jj) * 8;
          *(uint4*)&Ah[row * LDA + cbase] = make_uint4(hu[0], hu[1], hu[2], hu[3]);
          *(uint4*)&Al[row * LDA + cbase] = make_uint4(lu[0], lu[1], lu[2], lu[3]);
        }
      }
    }
#pragma unroll
    for (int i = 0; i < 2; ++i) {
      int c = tid + i * 256;
      int row = c >> 3, col8 = c & 7;
      *(uint4*)&Bh[row * LDA + col8 * 8] = *(const uint4*)(Bhg + (size_t)(bn + row) * K + k0 + col8 * 8);
      *(uint4*)&Bl[row * LDA + col8 * 8] = *(const uint4*)(Blg + (size_t)(bn + row) * K + k0 + col8 * 8);
    }
    __syncthreads();
#pragma unroll
    for (int kk = 0; kk < 64; kk += 32) {
      int kof = kk + quad * 8;
      short8 ah[MT], al[MT];
#pragma unroll
      for (int mt = 0; mt < MT; ++mt) {
        int ra = (wave * (BM / 4) + mt * 16 + lrow) * LDA + kof;
        ah[mt] = *(const short8*)&Ah[ra];
        al[mt] = *(const short8*)&Al[ra];
      }
      short8 bh[4], blo[4];
#pragma unroll
      for (int nt = 0; nt < 4; ++nt) {
        int rb = (nt * 16 + lrow) * LDA + kof;
        bh[nt]  = *(const short8*)&Bh[rb];
        blo[nt] = *(const short8*)&Bl[rb];
      }
#pragma unroll
      for (int nt = 0; nt < 4; ++nt) {
#pragma unroll
        for (int mt = 0; mt < MT; ++mt) {
          acc[mt][nt] = __builtin_amdgcn_mfma_f32_16x16x32_bf16(ah[mt], bh[nt],  acc[mt][nt], 0, 0, 0);
          acc[mt][nt] = __builtin_amdgcn_mfma_f32_16x16x32_bf16(al[mt], bh[nt],  acc[mt][nt], 0, 0, 0);
          acc[mt][nt] = __builtin_amdgcn_mfma_f32_16x16x32_bf16(ah[mt], blo[nt], acc[mt][nt], 0, 0, 0);
        }
      }
    }
    __syncthreads();
  }
#pragma unroll
  for (int mt = 0; mt < MT; ++mt) {
#pragma unroll
    for (int nt = 0; nt < 4; ++nt) {
#pragma unroll
      for (int reg = 0; reg < 4; ++reg) {
        int row = bm + wave * (BM / 4) + mt * 16 + quad * 4 + reg;
        int col = bn + nt * 16 + lrow;
        if (row < M) atomicAdd(&C[(size_t)row * N + col], acc[mt][nt][reg]);
      }
    }
  }
}

// ---------------- weight transpose+split: relation pairs -> [L*2][2048][128] ----------------
__global__ void conv_wT2(const float* __restrict__ Wl, const float* __restrict__ Wr,
                         const float* __restrict__ bl, const float* __restrict__ br,
                         ushort* __restrict__ WTh, ushort* __restrict__ WTl,
                         float* __restrict__ bout, int total) {
  int i = blockIdx.x * 256 + threadIdx.x;
  if (i >= total) return;
  int g2 = i / (2048 * 128), rem = i % (2048 * 128);
  int n = rem >> 7, k = rem & 127;
  int l = g2 >> 1, pair = g2 & 1;
  int r = pair * 2 + (n >> 10);          // relation within layer
  int nsub = n & 1023;                   // 0..1023 within [Wl|Wr]
  int nn = nsub & 511;
  int g = l * NR + r;
  const float* W = (nsub < 512) ? Wl : Wr;
  float v = W[(size_t)g * 65536 + (size_t)k * 512 + nn];
  ushort hi = f2bf(v);
  WTh[i] = hi;
  WTl[i] = f2bf(v - bf2f(hi));
  if (k == 0) bout[g2 * 2048 + n] = ((nsub < 512) ? bl : br)[g * 512 + nn];
}

// ---------------- build expanded KAN weight, transposed + split ----------------
__global__ void build_kan_wT(const float* __restrict__ base_w, const float* __restrict__ spline_w,
                             const float* __restrict__ scaler,
                             ushort* __restrict__ BTh, ushort* __restrict__ BTl,
                             int In, int Out) {
  int i = blockIdx.x * 256 + threadIdx.x;
  if (i >= In * 9 * Out) return;
  int o = i / (In * 9), k = i % (In * 9);
  float v;
  if (k < In) v = base_w[(size_t)o * In + k];
  else {
    int q = k - In, ii = q >> 3, gq = q & 7;
    v = spline_w[((size_t)o * In + ii) * 8 + gq] * scaler[(size_t)o * In + ii];
  }
  ushort hi = f2bf(v);
  BTh[i] = hi;
  BTl[i] = f2bf(v - bf2f(hi));
}

// ---------------- input projection (fp32 h + hi/lo bf16) ----------------
__global__ __launch_bounds__(128) void input_proj(
    const float* __restrict__ x, const float* __restrict__ id_emb,
    const int* __restrict__ id_token, const float* __restrict__ inW,
    const float* __restrict__ inb, float* __restrict__ h,
    ushort* __restrict__ hh, ushort* __restrict__ hl) {
  int n = blockIdx.x, j = threadIdx.x;
  __shared__ float s[FNODE + IDDIM];
  if (j < FNODE) s[j] = x[(size_t)n * FNODE + j];
  else if (j < FNODE + IDDIM) s[j] = id_emb[(size_t)id_token[n] * IDDIM + (j - FNODE)];
  __syncthreads();
  float acc = inb[j];
#pragma unroll
  for (int k = 0; k < FNODE + IDDIM; ++k) acc = fmaf(s[k], inW[k * HID + j], acc);
  float v = silu_f(acc);
  h[(size_t)n * HID + j] = v;
  ushort hi = f2bf(v);
  hh[(size_t)n * HID + j] = hi;
  hl[(size_t)n * HID + j] = f2bf(v - bf2f(hi));
}

// ---------------- per-layer prep ----------------
__global__ __launch_bounds__(512) void layer_prep(
    const float* __restrict__ rel_gate, const float* __restrict__ gat_bias,
    const float* __restrict__ rel_emb, const float* __restrict__ We, int l,
    float* __restrict__ gates, float* __restrict__ msg_bias, float* __restrict__ erel) {
  int j = threadIdx.x;
  float g[NR]; float mx = -1e30f;
  for (int r = 0; r < NR; ++r) { g[r] = rel_gate[l * NR + r]; mx = fmaxf(mx, g[r]); }
  float s = 0.f;
  for (int r = 0; r < NR; ++r) { g[r] = expf(g[r] - mx); s += g[r]; }
  for (int r = 0; r < NR; ++r) g[r] /= s;
  if (j < NR) gates[j] = g[j];
  if (j < HID) {
    float b = 0.f;
    for (int r = 0; r < NR; ++r) b = fmaf(g[r], gat_bias[((size_t)(l * NR + r)) * HID + j], b);
    msg_bias[j] = b;
  }
  for (int r = 0; r < NR; ++r) {
    const float* Wer = We + ((size_t)(l * NR + r)) * 24 * 512;
    const float* re  = rel_emb + (l * NR + r) * RELDIM;
    float acc = 0.f;
#pragma unroll
    for (int q = 0; q < RELDIM; ++q) acc = fmaf(re[q], Wer[(FEDGE + q) * 512 + j], acc);
    erel[r * 512 + j] = acc;
  }
}

// ---------------- fills ----------------
__global__ void fill_zero(float* __restrict__ p, int n) {
  int i = blockIdx.x * 256 + threadIdx.x;
  if (i < n) p[i] = 0.f;
}
__global__ void fill_zero_i(int* __restrict__ p, int n) {
  int i = blockIdx.x * 256 + threadIdx.x;
  if (i < n) p[i] = 0;
}

// ---------------- relation-sorted CSR build: bins (target, relation) ----------------
__global__ void csr_count2(const int* __restrict__ eidx, const int* __restrict__ etype,
                           int* __restrict__ deg2) {
  int e = blockIdx.x * 256 + threadIdx.x;
  if (e < NE) atomicAdd(&deg2[eidx[NE + e] * NR + etype[e]], 1);
}

// ---- parallel 3-pass scan over deg2[SCTOT] ----
__global__ __launch_bounds__(256) void scan_p1(const int* __restrict__ deg2,
                                               int* __restrict__ tmp_incl, int* __restrict__ bsum) {
  __shared__ int ps[256];
  int t = threadIdx.x, blk = blockIdx.x;
  int i = blk * 256 + t;
  int v = (i < SCTOT) ? deg2[i] : 0;
  ps[t] = v;
  __syncthreads();
  for (int o = 1; o < 256; o <<= 1) {
    int u = (t >= o) ? ps[t - o] : 0;
    __syncthreads();
    ps[t] += u;
    __syncthreads();
  }
  if (i < SCTOT) tmp_incl[i] = ps[t];
  if (t == 255) bsum[blk] = ps[255];
}
__global__ __launch_bounds__(256) void scan_p2(const int* __restrict__ bsum, int* __restrict__ boff) {
  __shared__ int ps[256];
  int t = threadIdx.x;
  int v = (t < SCBLK) ? bsum[t] : 0;
  ps[t] = v;
  __syncthreads();
  for (int o = 1; o < 256; o <<= 1) {
    int u = (t >= o) ? ps[t - o] : 0;
    __syncthreads();
    ps[t] += u;
    __syncthreads();
  }
  if (t < SCBLK) boff[t] = ps[t] - v;   // exclusive
}
__global__ __launch_bounds__(256) void scan_p3(const int* __restrict__ deg2,
                                               const int* __restrict__ tmp_incl,
                                               const int* __restrict__ boff,
                                               int* __restrict__ in_off2, int* __restrict__ cursor2) {
  int t = threadIdx.x, blk = blockIdx.x;
  int i = blk * 256 + t;
  if (i < SCTOT) {
    int excl = boff[blk] + tmp_incl[i] - deg2[i];
    in_off2[i] = excl;
    cursor2[i] = excl;
  }
  if (i == 0) in_off2[SCTOT] = NE;
}

__global__ void csr_scatter2(const int* __restrict__ eidx, const int* __restrict__ etype,
                             int* __restrict__ cursor2,
                             int* __restrict__ in_e2, int* __restrict__ in_s2) {
  int e = blockIdx.x * 256 + threadIdx.x;
  if (e < NE) {
    int pos = atomicAdd(&cursor2[eidx[NE + e] * NR + etype[e]], 1);
    in_e2[pos] = e;
    in_s2[pos] = eidx[e];
  }
}

// ---------------- node-centric GAT, software-pipelined edge loop ----------------
// Indices prefetched 2 ahead, payload (xlv + ea) prefetched 1 ahead.
// xlr [NN,2048]: for r_sub: xl at [rs*1024, +512), xr at [rs*1024+512, +512).
__global__ __launch_bounds__(256) void gat_node5(
    const int* __restrict__ in_off2, const int* __restrict__ in_e2, const int* __restrict__ in_s2,
    const float* __restrict__ eattr, const float* __restrict__ xlr,
    const float* __restrict__ We_base, const float* __restrict__ erel_base,
    const float* __restrict__ att_base, const float* __restrict__ gates,
    int rbase, float* __restrict__ hmsg) {
  __shared__ float WeL[16][512];
  __shared__ float attL[512];
  __shared__ float erelL[512];
  int tid = threadIdx.x;
  int rs = blockIdx.y;
  int r = rbase + rs;
  const float* We_r = We_base + (size_t)rs * 24 * 512;
  for (int i = tid; i < 16 * 512; i += 256) WeL[i >> 9][i & 511] = We_r[i];
  for (int i = tid; i < 512; i += 256) {
    attL[i] = att_base[rs * 512 + i];
    erelL[i] = erel_base[rs * 512 + i];
  }
  __syncthreads();
  float gr = gates[r] * 0.25f;
  int lane = tid & 63, wave = tid >> 6;
  int n = blockIdx.x * 4 + wave;
  if (n >= NN) return;
  int roff = rs * 1024;
  float xr[8];
  const float* xrb = xlr + (size_t)n * 2048 + roff + 512;
#pragma unroll
  for (int h = 0; h < 4; ++h) {
    xr[h * 2]     = xrb[h * 128 + lane];
    xr[h * 2 + 1] = xrb[h * 128 + 64 + lane];
  }
  float m[4] = {-1e30f, -1e30f, -1e30f, -1e30f};
  float lsum[4] = {0.f, 0.f, 0.f, 0.f};
  float acc[8] = {0.f, 0.f, 0.f, 0.f, 0.f, 0.f, 0.f, 0.f};
  int e0 = in_off2[n * NR + r];
  int cnt = in_off2[n * NR + r + 1] - e0;
  // software pipeline: indices 2 ahead, payload 1 ahead
  float px[8], pea[16];     // payload for edge j (consumed next iteration)
  int eN = 0, sN = 0;       // indices for edge j+1
  if (cnt > 0) {
    int eC = in_e2[e0], sC = in_s2[e0];
    if (cnt > 1) { eN = in_e2[e0 + 1]; sN = in_s2[e0 + 1]; }
    const float* xls = xlr + (size_t)sC * 2048 + roff;
#pragma unroll
    for (int h = 0; h < 4; ++h) {
      px[h * 2]     = xls[h * 128 + lane];
      px[h * 2 + 1] = xls[h * 128 + 64 + lane];
    }
    const float4* eap = (const float4*)(eattr + (size_t)eC * 16);
    float4 q0 = eap[0], q1 = eap[1], q2 = eap[2], q3 = eap[3];
    pea[0]=q0.x; pea[1]=q0.y; pea[2]=q0.z; pea[3]=q0.w;
    pea[4]=q1.x; pea[5]=q1.y; pea[6]=q1.z; pea[7]=q1.w;
    pea[8]=q2.x; pea[9]=q2.y; pea[10]=q2.z; pea[11]=q2.w;
    pea[12]=q3.x; pea[13]=q3.y; pea[14]=q3.z; pea[15]=q3.w;
  }
  for (int j = 0; j < cnt; ++j) {
    // rotate current payload out of the pipeline registers
    float xlv[8], ea[16];
#pragma unroll
    for (int q = 0; q < 8; ++q) xlv[q] = px[q];
#pragma unroll
    for (int q = 0; q < 16; ++q) ea[q] = pea[q];
    // issue prefetch for edge j+1 (indices already in eN/sN); fetch indices j+2
    if (j + 1 < cnt) {
      int eC = eN, sC = sN;
      if (j + 2 < cnt) { eN = in_e2[e0 + j + 2]; sN = in_s2[e0 + j + 2]; }
      const float* xls = xlr + (size_t)sC * 2048 + roff;
#pragma unroll
      for (int h = 0; h < 4; ++h) {
        px[h * 2]     = xls[h * 128 + lane];
        px[h * 2 + 1] = xls[h * 128 + 64 + lane];
      }
      const float4* eap = (const float4*)(eattr + (size_t)eC * 16);
      float4 q0 = eap[0], q1 = eap[1], q2 = eap[2], q3 = eap[3];
      pea[0]=q0.x; pea[1]=q0.y; pea[2]=q0.z; pea[3]=q0.w;
      pea[4]=q1.x; pea[5]=q1.y; pea[6]=q1.z; pea[7]=q1.w;
      pea[8]=q2.x; pea[9]=q2.y; pea[10]=q2.z; pea[11]=q2.w;
      pea[12]=q3.x; pea[13]=q3.y; pea[14]=q3.z; pea[15]=q3.w;
    }
    // compute with current payload (overlaps the prefetch loads above)
    float p[4];
#pragma unroll
    for (int h = 0; h < 4; ++h) {
      float ph = 0.f;
#pragma unroll
      for (int half = 0; half < 2; ++half) {
        int idx = h * 128 + half * 64 + lane;
        float et = erelL[idx];
#pragma unroll
        for (int k = 0; k < 16; ++k) et = fmaf(ea[k], WeL[k][idx], et);
        float z = xlv[h * 2 + half] + xr[h * 2 + half] + et;
        z = (z > 0.f) ? z : 0.2f * z;  // leaky_relu 0.2
        ph = fmaf(z, attL[idx], ph);
      }
      p[h] = ph;
    }
#pragma unroll
    for (int h = 0; h < 4; ++h) {
#pragma unroll
      for (int o = 32; o > 0; o >>= 1) p[h] += __shfl_xor(p[h], o, 64);
    }
#pragma unroll
    for (int h = 0; h < 4; ++h) {
      float sh = p[h];
      float mn = fmaxf(m[h], sh);
      float sc = expf(m[h] - mn);
      float we = expf(sh - mn);
      m[h] = mn;
      lsum[h] = lsum[h] * sc + we;
      acc[h * 2]     = acc[h * 2] * sc + we * xlv[h * 2];
      acc[h * 2 + 1] = acc[h * 2 + 1] * sc + we * xlv[h * 2 + 1];
    }
  }
  float o0 = 0.f, o1 = 0.f;
#pragma unroll
  for (int h = 0; h < 4; ++h) {
    float inv = 1.f / fmaxf(lsum[h], 1e-16f);
    o0 += acc[h * 2] * inv;
    o1 += acc[h * 2 + 1] * inv;
  }
  size_t base = (size_t)n * HID;
  atomicAdd(&hmsg[base + lane],      gr * o0);
  atomicAdd(&hmsg[base + 64 + lane], gr * o1);
}

// ---------------- LayerNorm over 128 dims (optionally emits hi/lo bf16) ----------------
__global__ __launch_bounds__(64) void ln128(
    float* __restrict__ h, const float* __restrict__ add, const float* __restrict__ bvec,
    const float* __restrict__ g, const float* __restrict__ b,
    ushort* __restrict__ hh, ushort* __restrict__ hl) {
  int n = blockIdx.x, lane = threadIdx.x;
  size_t base = (size_t)n * HID;
  float x0 = h[base + lane] + add[base + lane];
  float x1 = h[base + 64 + lane] + add[base + 64 + lane];
  if (bvec) { x0 += bvec[lane]; x1 += bvec[64 + lane]; }
  float s = x0 + x1;
#pragma unroll
  for (int m = 32; m > 0; m >>= 1) s += __shfl_xor(s, m, 64);
  float mu = s * (1.f / 128.f);
  float d0 = x0 - mu, d1 = x1 - mu;
  float q = d0 * d0 + d1 * d1;
#pragma unroll
  for (int m = 32; m > 0; m >>= 1) q += __shfl_xor(q, m, 64);
  float inv = 1.f / sqrtf(q * (1.f / 128.f) + 1e-5f);
  float o0 = d0 * inv * g[lane] + b[lane];
  float o1 = d1 * inv * g[64 + lane] + b[64 + lane];
  h[base + lane]      = o0;
  h[base + 64 + lane] = o1;
  if (hh) {
    ushort i0 = f2bf(o0), i1 = f2bf(o1);
    hh[base + lane] = i0;        hh[base + 64 + lane] = i1;
    hl[base + lane] = f2bf(o0 - bf2f(i0));
    hl[base + 64 + lane] = f2bf(o1 - bf2f(i1));
  }
}

// ---------------- KAN expansion (fp32) — tiny readout head only ----------------
__global__ void expand_f32(const float* __restrict__ v, float* __restrict__ u, int In, int rows) {
  int i = blockIdx.x * 256 + threadIdx.x;
  if (i >= rows * In) return;
  int n = i / In, c = i % In;
  float x = v[(size_t)n * In + c];
  size_t base = (size_t)n * In * 9;
  u[base + c] = silu_f(x);
  float b8[8];
  kan_bases(x, b8);
  float* ub = u + base + In + (size_t)c * 8;
#pragma unroll
  for (int gq = 0; gq < 8; ++gq) ub[gq] = b8[gq];
}

// ---------------- atomic-free pooling, stage 1: per-chunk partials ----------------
__global__ __launch_bounds__(128) void pool_part(
    const float* __restrict__ h, const int* __restrict__ batch,
    float* __restrict__ psum, float* __restrict__ pmax, float* __restrict__ pcnt) {
  __shared__ float sS[NG][HID];
  __shared__ float sM[NG][HID];
  __shared__ int sC[NG];
  int d = threadIdx.x, blk = blockIdx.x;
  const float NEGINF = __uint_as_float(0xff800000u);  // -inf
  for (int i = d; i < NG * HID; i += 128) {
    ((float*)sS)[i] = 0.f;
    ((float*)sM)[i] = NEGINF;
  }
  if (d < NG) sC[d] = 0;
  __syncthreads();
  const int CH = (NN + NCHUNK - 1) / NCHUNK;  // 79
  int n0 = blk * CH, n1 = (n0 + CH < NN) ? n0 + CH : NN;
  for (int n = n0; n < n1; ++n) {
    int g = batch[n];
    float v = h[(size_t)n * HID + d];
    sS[g][d] += v;
    sM[g][d] = fmaxf(sM[g][d], v);
    if (d == 0) sC[g]++;
  }
  __syncthreads();
  for (int i = d; i < NG * HID; i += 128) {
    psum[(size_t)blk * NG * HID + i] = ((float*)sS)[i];
    pmax[(size_t)blk * NG * HID + i] = ((float*)sM)[i];
  }
  if (d < NG) pcnt[blk * NG + d] = (float)sC[d];
}

// ---------------- pooling stage 2 + readout LN ----------------
__global__ __launch_bounds__(256) void pool_final2(
    const float* __restrict__ psum, const float* __restrict__ pmax,
    const float* __restrict__ pcnt, const float* __restrict__ rog,
    const float* __restrict__ rob, float* __restrict__ gvec) {
  int g = blockIdx.x, j = threadIdx.x;
  __shared__ float rb[256];
  float x;
  if (j < HID) {
    float s = 0.f, cn = 0.f;
    for (int c = 0; c < NCHUNK; ++c) {
      s += psum[(size_t)c * NG * HID + g * HID + j];
      cn += pcnt[c * NG + g];
    }
    x = s / fmaxf(cn, 1.f);
  } else {
    float mx = __uint_as_float(0xff800000u);
    for (int c = 0; c < NCHUNK; ++c)
      mx = fmaxf(mx, pmax[(size_t)c * NG * HID + g * HID + (j - HID)]);
    x = (mx > -1e38f) ? mx : 0.f;  // where(isfinite, ., 0)
  }
  rb[j] = x; __syncthreads();
  for (int st = 128; st > 0; st >>= 1) { if (j < st) rb[j] += rb[j + st]; __syncthreads(); }
  float mu = rb[0] * (1.f / 256.f); __syncthreads();
  float d = x - mu;
  rb[j] = d * d; __syncthreads();
  for (int st = 128; st > 0; st >>= 1) { if (j < st) rb[j] += rb[j + st]; __syncthreads(); }
  float var = rb[0] * (1.f / 256.f);
  float inv = 1.f / sqrtf(var + 1e-5f);
  gvec[(size_t)g * 256 + j] = d * inv * rog[j] + rob[j];
}

// ---------------- wave-parallel KAN head: one wave per (graph, output) ----------------
__global__ __launch_bounds__(256) void kan_head_w(
    const float* __restrict__ u, const float* __restrict__ base_w,
    const float* __restrict__ spline_w, const float* __restrict__ scaler,
    float* __restrict__ out, int In, int Out, int npairs) {
  int wid = blockIdx.x * 4 + (threadIdx.x >> 6);
  if (wid >= npairs) return;
  int g = wid / Out, o = wid % Out;
  int lane = threadIdx.x & 63;
  const float* ug = u + (size_t)g * In * 9;
  const float* bw = base_w + (size_t)o * In;
  const float* sp = spline_w + (size_t)o * In * 8;
  const float* sc = scaler + (size_t)o * In;
  float acc = 0.f;
  for (int i = lane; i < In; i += 64) acc = fmaf(ug[i], bw[i], acc);
  const float* us = ug + In;
  for (int k = lane; k < In * 8; k += 64) {
    int i = k >> 3;
    acc = fmaf(us[k], sp[k] * sc[i], acc);
  }
#pragma unroll
  for (int off2 = 32; off2 > 0; off2 >>= 1) acc += __shfl_xor(acc, off2, 64);
  if (lane == 0) out[(size_t)g * Out + o] = acc;
}

// ---------------- launch ----------------
extern "C" void kernel_launch(void* const* d_in, const int* in_sizes, int n_in,
                              void* d_out, int out_size, void* d_ws, size_t ws_size,
                              hipStream_t stream) {
  const float* x         = (const float*)d_in[0];
  const float* edge_attr = (const float*)d_in[1];
  const int*   id_token  = (const int*)  d_in[2];
  const int*   edge_index= (const int*)  d_in[3];
  const int*   edge_type = (const int*)  d_in[4];
  const int*   batch     = (const int*)  d_in[5];
  const float* id_emb    = (const float*)d_in[6];
  const float* inW       = (const float*)d_in[7];
  const float* inb       = (const float*)d_in[8];
  const float* Wl        = (const float*)d_in[9];
  const float* bl        = (const float*)d_in[10];
  const float* Wr        = (const float*)d_in[11];
  const float* br        = (const float*)d_in[12];
  const float* We        = (const float*)d_in[13];
  const float* att       = (const float*)d_in[14];
  const float* gat_bias  = (const float*)d_in[15];
  const float* rel_gate  = (const float*)d_in[16];
  const float* rel_emb   = (const float*)d_in[17];
  const float* ln1g      = (const float*)d_in[18];
  const float* ln1b      = (const float*)d_in[19];
  const float* ln2g      = (const float*)d_in[20];
  const float* ln2b      = (const float*)d_in[21];
  const float* ffn1_base = (const float*)d_in[22];
  const float* ffn1_spl  = (const float*)d_in[23];
  const float* ffn1_sc   = (const float*)d_in[24];
  const float* ffn2_base = (const float*)d_in[25];
  const float* ffn2_spl  = (const float*)d_in[26];
  const float* ffn2_sc   = (const float*)d_in[27];
  const float* rog       = (const float*)d_in[28];
  const float* rob       = (const float*)d_in[29];
  const float* h1_base   = (const float*)d_in[30];
  const float* h1_spl    = (const float*)d_in[31];
  const float* h1_sc     = (const float*)d_in[32];
  const float* h2_base   = (const float*)d_in[33];
  const float* h2_spl    = (const float*)d_in[34];
  const float* h2_sc     = (const float*)d_in[35];
  (void)in_sizes; (void)n_in; (void)out_size; (void)ws_size;

  // ---- workspace carve (256B aligned) ----
  char* wsp = (char*)d_ws;
  size_t off = 0;
  auto carve = [&](size_t bytes) { char* p = wsp + off; off = (off + bytes + 255) & ~(size_t)255; return p; };
  float*    h     = (float*)   carve((size_t)NN * HID * 4);
  ushort*   h_hi  = (ushort*)  carve((size_t)NN * HID * 2);
  ushort*   h_lo  = (ushort*)  carve((size_t)NN * HID * 2);
  float*    hmsg  = (float*)   carve((size_t)NN * HID * 4);
  float*    t1    = (float*)   carve((size_t)NN * FFNH * 4);
  float*    gates = (float*)   carve(NR * 4);
  float*    msgb  = (float*)   carve(HID * 4);
  float*    erel  = (float*)   carve(NR * 512 * 4);
  ushort*   WTh   = (ushort*)  carve((size_t)NL * 2 * 2048 * HID * 2);
  ushort*   WTl   = (ushort*)  carve((size_t)NL * 2 * 2048 * HID * 2);
  float*    blr   = (float*)   carve((size_t)NL * 2 * 2048 * 4);
  ushort*   B1h   = (ushort*)  carve((size_t)FFNH * HID * 9 * 2);
  ushort*   B1l   = (ushort*)  carve((size_t)FFNH * HID * 9 * 2);
  ushort*   B2h   = (ushort*)  carve((size_t)HID * FFNH * 9 * 2);
  ushort*   B2l   = (ushort*)  carve((size_t)HID * FFNH * 9 * 2);
  float*    psum  = (float*)   carve((size_t)NCHUNK * NG * HID * 4);
  float*    pmax  = (float*)   carve((size_t)NCHUNK * NG * HID * 4);
  float*    pcnt  = (float*)   carve((size_t)NCHUNK * NG * 4);
  float*    gvec  = (float*)   carve((size_t)NG * 256 * 4);
  float*    uhead = (float*)   carve((size_t)NG * 256 * 9 * 4);
  float*    thead = (float*)   carve((size_t)NG * HEADH * 4);
  float*    xlr   = (float*)   carve((size_t)NN * 2048 * 4);        // 82 MB
  int*      deg2  = (int*)     carve((size_t)SCTOT * 4);
  int*      in_off2=(int*)     carve((size_t)(SCTOT + 1) * 4);
  int*      cursor2=(int*)     carve((size_t)SCTOT * 4);
  int*      tmp_incl=(int*)    carve((size_t)SCTOT * 4);
  int*      bsum  = (int*)     carve((size_t)SCBLK * 4);
  int*      boff  = (int*)     carve((size_t)SCBLK * 4);
  int*      in_e2 = (int*)     carve((size_t)NE * 4);
  int*      in_s2 = (int*)     carve((size_t)NE * 4);

  // ---- relation-sorted CSR build (once; graph static across layers) ----
  fill_zero_i<<<(SCTOT + 255) / 256, 256, 0, stream>>>(deg2, SCTOT);
  csr_count2<<<(NE + 255) / 256, 256, 0, stream>>>(edge_index, edge_type, deg2);
  scan_p1<<<SCBLK, 256, 0, stream>>>(deg2, tmp_incl, bsum);
  scan_p2<<<1, 256, 0, stream>>>(bsum, boff);
  scan_p3<<<SCBLK, 256, 0, stream>>>(deg2, tmp_incl, boff, in_off2, cursor2);
  csr_scatter2<<<(NE + 255) / 256, 256, 0, stream>>>(edge_index, edge_type, cursor2, in_e2, in_s2);

  // ---- weight transpose + split (once per launch) ----
  {
    int total = NL * 2 * 2048 * 128;
    conv_wT2<<<(total + 255) / 256, 256, 0, stream>>>(Wl, Wr, bl, br, WTh, WTl, blr, total);
  }

  // ---- input projection ----
  input_proj<<<NN, 128, 0, stream>>>(x, id_emb, id_token, inW, inb, h, h_hi, h_lo);

  const int MB128 = (NN + 127) / 128;  // 79
  const int MB64  = (NN + 63) / 64;    // 157
  for (int l = 0; l < NL; ++l) {
    layer_prep<<<1, 512, 0, stream>>>(rel_gate, gat_bias, rel_emb, We, l, gates, msgb, erel);
    fill_zero<<<(NN * HID + 255) / 256, 256, 0, stream>>>(hmsg, NN * HID);
    for (int pair = 0; pair < 2; ++pair) {
      int g2 = l * 2 + pair;
      const ushort* WThp = WTh + (size_t)g2 * 2048 * HID;
      const ushort* WTlp = WTl + (size_t)g2 * 2048 * HID;
      const float* blp   = blr + (size_t)g2 * 2048;
      int rbase = pair * 2;
      gemm_bf3<<<dim3(2048 / 64, MB128), 256, 0, stream>>>(h_hi, h_lo, WThp, WTlp, blp, xlr, NN, HID, 2048);
      gat_node5<<<dim3((NN + 3) / 4, 2), 256, 0, stream>>>(
          in_off2, in_e2, in_s2, edge_attr, xlr,
          We + ((size_t)(l * NR + rbase)) * 24 * 512, erel + rbase * 512,
          att + (size_t)(l * NR + rbase) * 512, gates, rbase, hmsg);
    }
    ln128<<<NN, 64, 0, stream>>>(h, hmsg, msgb, ln1g + l * HID, ln1b + l * HID, nullptr, nullptr);

    // ---- KAN FFN1: 128 -> 256 (K = 1152), fused expansion, split-K 3 ----
    build_kan_wT<<<((HID * 9 * FFNH) + 255) / 256, 256, 0, stream>>>(
        ffn1_base + (size_t)l * FFNH * HID, ffn1_spl + (size_t)l * FFNH * HID * 8,
        ffn1_sc + (size_t)l * FFNH * HID, B1h, B1l, HID, FFNH);
    fill_zero<<<(NN * FFNH + 255) / 256, 256, 0, stream>>>(t1, NN * FFNH);
    gemm_kan<128, 3><<<dim3(FFNH / 64, MB128, 3), 256, 0, stream>>>(h, B1h, B1l, t1, NN, HID, FFNH);
    // ---- KAN FFN2: 256 -> 128 (K = 2304), fused expansion, split-K 4 ----
    build_kan_wT<<<((FFNH * 9 * HID) + 255) / 256, 256, 0, stream>>>(
        ffn2_base + (size_t)l * HID * FFNH, ffn2_spl + (size_t)l * HID * FFNH * 8,
        ffn2_sc + (size_t)l * HID * FFNH, B2h, B2l, FFNH, HID);
    fill_zero<<<(NN * HID + 255) / 256, 256, 0, stream>>>(hmsg, NN * HID);
    gemm_kan<64, 4><<<dim3(HID / 64, MB64, 4), 256, 0, stream>>>(t1, B2h, B2l, hmsg, NN, FFNH, HID);
    ln128<<<NN, 64, 0, stream>>>(h, hmsg, nullptr, ln2g + l * HID, ln2b + l * HID, h_hi, h_lo);
  }

  // ---- readout (atomic-free pooling) ----
  pool_part<<<NCHUNK, 128, 0, stream>>>(h, batch, psum, pmax, pcnt);
  pool_final2<<<NG, 256, 0, stream>>>(psum, pmax, pcnt, rog, rob, gvec);
  expand_f32<<<((NG * 256) + 255) / 256, 256, 0, stream>>>(gvec, uhead, 256, NG);
  {
    int npairs = NG * HEADH;  // 4096 waves
    kan_head_w<<<(npairs + 3) / 4, 256, 0, stream>>>(uhead, h1_base, h1_spl, h1_sc, thead, 256, HEADH, npairs);
  }
  expand_f32<<<((NG * HEADH) + 255) / 256, 256, 0, stream>>>(thead, uhead, HEADH, NG);
  {
    int npairs = NG * NCLS;   // 320 waves
    kan_head_w<<<(npairs + 3) / 4, 256, 0, stream>>>(uhead, h2_base, h2_spl, h2_sc, (float*)d_out, HEADH, NCLS, npairs);
  }
}

// Round 13
// 1491.804 us; speedup vs baseline: 2.9862x; 1.0681x over previous
//
#include <hip/hip_runtime.h>
#include <cstdint>
#include <cstddef>

// ---------------- static problem config ----------------
#define NN      10000   // nodes
#define NE      120000  // edges
#define NG      32      // graphs
#define FNODE   64
#define FEDGE   16
#define HID     128
#define NHEADS  4
#define NL      3
#define NR      4
#define IDDIM   32
#define RELDIM  8
#define FFNH    256
#define HEADH   128
#define NCLS    10

#define NCHUNK  128     // pooling stage-1 blocks
#define SCTOT   (NN * NR)            // 40000 scan entries
#define SCBLK   ((SCTOT + 255) / 256)  // 157 scan blocks

typedef __attribute__((ext_vector_type(8))) short short8;
typedef __attribute__((ext_vector_type(4))) float floatx4;

// ---------------- helpers ----------------
__device__ __forceinline__ float silu_f(float x) { return x / (1.f + expf(-x)); }
__device__ __forceinline__ ushort f2bf(float f) {   // round-to-nearest-even bf16
  unsigned u = __float_as_uint(f);
  return (ushort)((u + 0x7FFFu + ((u >> 16) & 1u)) >> 16);
}
__device__ __forceinline__ float bf2f(ushort h) { return __uint_as_float((unsigned)h << 16); }

// Cox–de Boor cubic bases on grid t_j = (j-3)*0.4 - 1 (GRID_SIZE=5, ORDER=3) -> 8 bases
__device__ __forceinline__ void kan_bases(float x, float* out8) {
  float bb[11];
#pragma unroll
  for (int j = 0; j < 11; ++j) {
    float t0 = (j - 3) * 0.4f - 1.f;
    float t1 = (j - 2) * 0.4f - 1.f;
    bb[j] = (x >= t0 && x < t1) ? 1.f : 0.f;
  }
  {
    const float inv = 1.f / 0.4f;
#pragma unroll
    for (int j = 0; j < 10; ++j) {
      float tj = (j - 3) * 0.4f - 1.f, tjp1 = (j - 1) * 0.4f - 1.f;
      bb[j] = ((x - tj) * bb[j] + (tjp1 - x) * bb[j + 1]) * inv;
    }
  }
  {
    const float inv = 1.f / 0.8f;
#pragma unroll
    for (int j = 0; j < 9; ++j) {
      float tj = (j - 3) * 0.4f - 1.f, tjp1 = (j) * 0.4f - 1.f;
      bb[j] = ((x - tj) * bb[j] + (tjp1 - x) * bb[j + 1]) * inv;
    }
  }
  {
    const float inv = 1.f / 1.2000001f;
#pragma unroll
    for (int j = 0; j < 8; ++j) {
      float tj = (j - 3) * 0.4f - 1.f, tjp1 = (j + 1) * 0.4f - 1.f;
      bb[j] = ((x - tj) * bb[j] + (tjp1 - x) * bb[j + 1]) * inv;
    }
  }
#pragma unroll
  for (int j = 0; j < 8; ++j) out8[j] = bb[j];
}

// ---------------- 3-term MFMA GEMM, operands pre-split bf16 hi/lo ----------------
__global__ __launch_bounds__(256) void gemm_bf3(
    const ushort* __restrict__ Ahg, const ushort* __restrict__ Alg,
    const ushort* __restrict__ Bhg, const ushort* __restrict__ Blg,
    const float* __restrict__ bias, float* __restrict__ C,
    int M, int K, int N) {
  constexpr int LDA = 68;
  __shared__ __align__(16) ushort Ah[128 * LDA];
  __shared__ __align__(16) ushort Al[128 * LDA];
  __shared__ __align__(16) ushort Bh[64 * LDA];
  __shared__ __align__(16) ushort Bl[64 * LDA];
  const int tid = threadIdx.x;
  const int lane = tid & 63, wave = tid >> 6;
  const int lrow = lane & 15, quad = lane >> 4;
  const int bm = blockIdx.y * 128, bn = blockIdx.x * 64;
  floatx4 acc[2][4] = {};
  for (int k0 = 0; k0 < K; k0 += 64) {
#pragma unroll
    for (int i = 0; i < 4; ++i) {
      int c = tid + i * 256;
      int row = c >> 3, col8 = c & 7;
      int gr = bm + row;
      uint4 vh = make_uint4(0, 0, 0, 0), vl = make_uint4(0, 0, 0, 0);
      if (gr < M) {
        vh = *(const uint4*)(Ahg + (size_t)gr * K + k0 + col8 * 8);
        vl = *(const uint4*)(Alg + (size_t)gr * K + k0 + col8 * 8);
      }
      *(uint4*)&Ah[row * LDA + col8 * 8] = vh;
      *(uint4*)&Al[row * LDA + col8 * 8] = vl;
    }
#pragma unroll
    for (int i = 0; i < 2; ++i) {
      int c = tid + i * 256;
      int row = c >> 3, col8 = c & 7;
      *(uint4*)&Bh[row * LDA + col8 * 8] = *(const uint4*)(Bhg + (size_t)(bn + row) * K + k0 + col8 * 8);
      *(uint4*)&Bl[row * LDA + col8 * 8] = *(const uint4*)(Blg + (size_t)(bn + row) * K + k0 + col8 * 8);
    }
    __syncthreads();
#pragma unroll
    for (int kk = 0; kk < 64; kk += 32) {
      int kof = kk + quad * 8;
      const int ra0 = (wave * 32 + lrow) * LDA + kof;
      const int ra1 = (wave * 32 + 16 + lrow) * LDA + kof;
      short8 ah0 = *(const short8*)&Ah[ra0];
      short8 ah1 = *(const short8*)&Ah[ra1];
      short8 al0 = *(const short8*)&Al[ra0];
      short8 al1 = *(const short8*)&Al[ra1];
      short8 bh[4], blo[4];
#pragma unroll
      for (int nt = 0; nt < 4; ++nt) {
        int rb = (nt * 16 + lrow) * LDA + kof;
        bh[nt]  = *(const short8*)&Bh[rb];
        blo[nt] = *(const short8*)&Bl[rb];
      }
#pragma unroll
      for (int nt = 0; nt < 4; ++nt) {
        acc[0][nt] = __builtin_amdgcn_mfma_f32_16x16x32_bf16(ah0, bh[nt],  acc[0][nt], 0, 0, 0);
        acc[1][nt] = __builtin_amdgcn_mfma_f32_16x16x32_bf16(ah1, bh[nt],  acc[1][nt], 0, 0, 0);
        acc[0][nt] = __builtin_amdgcn_mfma_f32_16x16x32_bf16(al0, bh[nt],  acc[0][nt], 0, 0, 0);
        acc[1][nt] = __builtin_amdgcn_mfma_f32_16x16x32_bf16(al1, bh[nt],  acc[1][nt], 0, 0, 0);
        acc[0][nt] = __builtin_amdgcn_mfma_f32_16x16x32_bf16(ah0, blo[nt], acc[0][nt], 0, 0, 0);
        acc[1][nt] = __builtin_amdgcn_mfma_f32_16x16x32_bf16(ah1, blo[nt], acc[1][nt], 0, 0, 0);
      }
    }
    __syncthreads();
  }
#pragma unroll
  for (int mt = 0; mt < 2; ++mt) {
#pragma unroll
    for (int nt = 0; nt < 4; ++nt) {
#pragma unroll
      for (int reg = 0; reg < 4; ++reg) {
        int row = bm + wave * 32 + mt * 16 + quad * 4 + reg;
        int col = bn + nt * 16 + lrow;
        if (row < M) {
          float v = acc[mt][nt][reg];
          if (bias) v += bias[col];
          C[(size_t)row * N + col] = v;
        }
      }
    }
  }
}

// ---------------- fused KAN GEMM w/ split-K: C += expand(A) @ BT^T ----------------
template<int BM, int SPLIT>
__global__ __launch_bounds__(256) void gemm_kan(
    const float* __restrict__ A, const ushort* __restrict__ Bhg, const ushort* __restrict__ Blg,
    float* __restrict__ C, int M, int In, int N) {
  const int K = In * 9;
  const int ntiles = K >> 6;
  const int per = (ntiles + SPLIT - 1) / SPLIT;
  const int kt0 = blockIdx.z * per;
  const int kt1 = (kt0 + per < ntiles) ? (kt0 + per) : ntiles;
  constexpr int LDA = 68;
  __shared__ __align__(16) ushort Ah[BM * LDA];
  __shared__ __align__(16) ushort Al[BM * LDA];
  __shared__ __align__(16) ushort Bh[64 * LDA];
  __shared__ __align__(16) ushort Bl[64 * LDA];
  const int tid = threadIdx.x;
  const int lane = tid & 63, wave = tid >> 6;
  const int lrow = lane & 15, quad = lane >> 4;
  const int bm = blockIdx.y * BM, bn = blockIdx.x * 64;
  constexpr int MT = BM / 64;
  floatx4 acc[MT][4] = {};
  for (int kt = kt0; kt < kt1; ++kt) {
    int k0 = kt << 6;
    if (k0 < In) {
#pragma unroll
      for (int i = 0; i < BM / 16; ++i) {
        int c = tid + i * 256;
        int row = c >> 4, col4 = c & 15;
        int gr = bm + row;
        float4 v = make_float4(0.f, 0.f, 0.f, 0.f);
        if (gr < M) v = *(const float4*)(A + (size_t)gr * In + k0 + col4 * 4);
        float vv[4] = {silu_f(v.x), silu_f(v.y), silu_f(v.z), silu_f(v.w)};
        ushort h0 = f2bf(vv[0]), h1 = f2bf(vv[1]), h2 = f2bf(vv[2]), h3 = f2bf(vv[3]);
        ushort l0 = f2bf(vv[0] - bf2f(h0)), l1 = f2bf(vv[1] - bf2f(h1));
        ushort l2 = f2bf(vv[2] - bf2f(h2)), l3 = f2bf(vv[3] - bf2f(h3));
        *(uint2*)&Ah[row * LDA + col4 * 4] =
          make_uint2((unsigned)h0 | ((unsigned)h1 << 16), (unsigned)h2 | ((unsigned)h3 << 16));
        *(uint2*)&Al[row * LDA + col4 * 4] =
          make_uint2((unsigned)l0 | ((unsigned)l1 << 16), (unsigned)l2 | ((unsigned)l3 << 16));
      }
    } else {
      int i0 = (k0 - In) >> 3;
      if (tid < BM * 2) {
        int row = tid >> 1, half = tid & 1;
        int gr = bm + row;
        float4 v = make_float4(0.f, 0.f, 0.f, 0.f);
        if (gr < M) v = *(const float4*)(A + (size_t)gr * In + i0 + half * 4);
        float vv[4] = {v.x, v.y, v.z, v.w};
#pragma unroll
        for (int jj = 0; jj < 4; ++jj) {
          float b8[8];
          kan_bases(vv[jj], b8);
          unsigned hu[4], lu[4];
#pragma unroll
          for (int q = 0; q < 4; ++q) {
            ushort ha = f2bf(b8[2 * q]), hb = f2bf(b8[2 * q + 1]);
            ushort la = f2bf(b8[2 * q] - bf2f(ha)), lb = f2bf(b8[2 * q + 1] - bf2f(hb));
            hu[q] = (unsigned)ha | ((unsigned)hb << 16);
            lu[q] = (unsigned)la | ((unsigned)lb << 16);
          }
          int cbase = (half * 4 + jj) * 8;
          *(uint4*)&Ah[row * LDA + cbase] = make_uint4(hu[0], hu[1], hu[2], hu[3]);
          *(uint4*)&Al[row * LDA + cbase] = make_uint4(lu[0], lu[1], lu[2], lu[3]);
        }
      }
    }
#pragma unroll
    for (int i = 0; i < 2; ++i) {
      int c = tid + i * 256;
      int row = c >> 3, col8 = c & 7;
      *(uint4*)&Bh[row * LDA + col8 * 8] = *(const uint4*)(Bhg + (size_t)(bn + row) * K + k0 + col8 * 8);
      *(uint4*)&Bl[row * LDA + col8 * 8] = *(const uint4*)(Blg + (size_t)(bn + row) * K + k0 + col8 * 8);
    }
    __syncthreads();
#pragma unroll
    for (int kk = 0; kk < 64; kk += 32) {
      int kof = kk + quad * 8;
      short8 ah[MT], al[MT];
#pragma unroll
      for (int mt = 0; mt < MT; ++mt) {
        int ra = (wave * (BM / 4) + mt * 16 + lrow) * LDA + kof;
        ah[mt] = *(const short8*)&Ah[ra];
        al[mt] = *(const short8*)&Al[ra];
      }
      short8 bh[4], blo[4];
#pragma unroll
      for (int nt = 0; nt < 4; ++nt) {
        int rb = (nt * 16 + lrow) * LDA + kof;
        bh[nt]  = *(const short8*)&Bh[rb];
        blo[nt] = *(const short8*)&Bl[rb];
      }
#pragma unroll
      for (int nt = 0; nt < 4; ++nt) {
#pragma unroll
        for (int mt = 0; mt < MT; ++mt) {
          acc[mt][nt] = __builtin_amdgcn_mfma_f32_16x16x32_bf16(ah[mt], bh[nt],  acc[mt][nt], 0, 0, 0);
          acc[mt][nt] = __builtin_amdgcn_mfma_f32_16x16x32_bf16(al[mt], bh[nt],  acc[mt][nt], 0, 0, 0);
          acc[mt][nt] = __builtin_amdgcn_mfma_f32_16x16x32_bf16(ah[mt], blo[nt], acc[mt][nt], 0, 0, 0);
        }
      }
    }
    __syncthreads();
  }
#pragma unroll
  for (int mt = 0; mt < MT; ++mt) {
#pragma unroll
    for (int nt = 0; nt < 4; ++nt) {
#pragma unroll
      for (int reg = 0; reg < 4; ++reg) {
        int row = bm + wave * (BM / 4) + mt * 16 + quad * 4 + reg;
        int col = bn + nt * 16 + lrow;
        if (row < M) atomicAdd(&C[(size_t)row * N + col], acc[mt][nt][reg]);
      }
    }
  }
}

// ---------------- weight transpose+split: relation pairs -> [L*2][2048][128] ----------------
__global__ void conv_wT2(const float* __restrict__ Wl, const float* __restrict__ Wr,
                         const float* __restrict__ bl, const float* __restrict__ br,
                         ushort* __restrict__ WTh, ushort* __restrict__ WTl,
                         float* __restrict__ bout, int total) {
  int i = blockIdx.x * 256 + threadIdx.x;
  if (i >= total) return;
  int g2 = i / (2048 * 128), rem = i % (2048 * 128);
  int n = rem >> 7, k = rem & 127;
  int l = g2 >> 1, pair = g2 & 1;
  int r = pair * 2 + (n >> 10);          // relation within layer
  int nsub = n & 1023;                   // 0..1023 within [Wl|Wr]
  int nn = nsub & 511;
  int g = l * NR + r;
  const float* W = (nsub < 512) ? Wl : Wr;
  float v = W[(size_t)g * 65536 + (size_t)k * 512 + nn];
  ushort hi = f2bf(v);
  WTh[i] = hi;
  WTl[i] = f2bf(v - bf2f(hi));
  if (k == 0) bout[g2 * 2048 + n] = ((nsub < 512) ? bl : br)[g * 512 + nn];
}

// ---------------- build expanded KAN weight, transposed + split ----------------
__global__ void build_kan_wT(const float* __restrict__ base_w, const float* __restrict__ spline_w,
                             const float* __restrict__ scaler,
                             ushort* __restrict__ BTh, ushort* __restrict__ BTl,
                             int In, int Out) {
  int i = blockIdx.x * 256 + threadIdx.x;
  if (i >= In * 9 * Out) return;
  int o = i / (In * 9), k = i % (In * 9);
  float v;
  if (k < In) v = base_w[(size_t)o * In + k];
  else {
    int q = k - In, ii = q >> 3, gq = q & 7;
    v = spline_w[((size_t)o * In + ii) * 8 + gq] * scaler[(size_t)o * In + ii];
  }
  ushort hi = f2bf(v);
  BTh[i] = hi;
  BTl[i] = f2bf(v - bf2f(hi));
}

// ---------------- input projection (fp32 h + hi/lo bf16) ----------------
__global__ __launch_bounds__(128) void input_proj(
    const float* __restrict__ x, const float* __restrict__ id_emb,
    const int* __restrict__ id_token, const float* __restrict__ inW,
    const float* __restrict__ inb, float* __restrict__ h,
    ushort* __restrict__ hh, ushort* __restrict__ hl) {
  int n = blockIdx.x, j = threadIdx.x;
  __shared__ float s[FNODE + IDDIM];
  if (j < FNODE) s[j] = x[(size_t)n * FNODE + j];
  else if (j < FNODE + IDDIM) s[j] = id_emb[(size_t)id_token[n] * IDDIM + (j - FNODE)];
  __syncthreads();
  float acc = inb[j];
#pragma unroll
  for (int k = 0; k < FNODE + IDDIM; ++k) acc = fmaf(s[k], inW[k * HID + j], acc);
  float v = silu_f(acc);
  h[(size_t)n * HID + j] = v;
  ushort hi = f2bf(v);
  hh[(size_t)n * HID + j] = hi;
  hl[(size_t)n * HID + j] = f2bf(v - bf2f(hi));
}

// ---------------- per-layer prep ----------------
__global__ __launch_bounds__(512) void layer_prep(
    const float* __restrict__ rel_gate, const float* __restrict__ gat_bias,
    const float* __restrict__ rel_emb, const float* __restrict__ We, int l,
    float* __restrict__ gates, float* __restrict__ msg_bias, float* __restrict__ erel) {
  int j = threadIdx.x;
  float g[NR]; float mx = -1e30f;
  for (int r = 0; r < NR; ++r) { g[r] = rel_gate[l * NR + r]; mx = fmaxf(mx, g[r]); }
  float s = 0.f;
  for (int r = 0; r < NR; ++r) { g[r] = expf(g[r] - mx); s += g[r]; }
  for (int r = 0; r < NR; ++r) g[r] /= s;
  if (j < NR) gates[j] = g[j];
  if (j < HID) {
    float b = 0.f;
    for (int r = 0; r < NR; ++r) b = fmaf(g[r], gat_bias[((size_t)(l * NR + r)) * HID + j], b);
    msg_bias[j] = b;
  }
  for (int r = 0; r < NR; ++r) {
    const float* Wer = We + ((size_t)(l * NR + r)) * 24 * 512;
    const float* re  = rel_emb + (l * NR + r) * RELDIM;
    float acc = 0.f;
#pragma unroll
    for (int q = 0; q < RELDIM; ++q) acc = fmaf(re[q], Wer[(FEDGE + q) * 512 + j], acc);
    erel[r * 512 + j] = acc;
  }
}

// ---------------- fills ----------------
__global__ void fill_zero(float* __restrict__ p, int n) {
  int i = blockIdx.x * 256 + threadIdx.x;
  if (i < n) p[i] = 0.f;
}
__global__ void fill_zero_i(int* __restrict__ p, int n) {
  int i = blockIdx.x * 256 + threadIdx.x;
  if (i < n) p[i] = 0;
}

// ---------------- relation-sorted CSR build: bins (target, relation) ----------------
__global__ void csr_count2(const int* __restrict__ eidx, const int* __restrict__ etype,
                           int* __restrict__ deg2) {
  int e = blockIdx.x * 256 + threadIdx.x;
  if (e < NE) atomicAdd(&deg2[eidx[NE + e] * NR + etype[e]], 1);
}

// ---- parallel 3-pass scan over deg2[SCTOT] ----
__global__ __launch_bounds__(256) void scan_p1(const int* __restrict__ deg2,
                                               int* __restrict__ tmp_incl, int* __restrict__ bsum) {
  __shared__ int ps[256];
  int t = threadIdx.x, blk = blockIdx.x;
  int i = blk * 256 + t;
  int v = (i < SCTOT) ? deg2[i] : 0;
  ps[t] = v;
  __syncthreads();
  for (int o = 1; o < 256; o <<= 1) {
    int u = (t >= o) ? ps[t - o] : 0;
    __syncthreads();
    ps[t] += u;
    __syncthreads();
  }
  if (i < SCTOT) tmp_incl[i] = ps[t];
  if (t == 255) bsum[blk] = ps[255];
}
__global__ __launch_bounds__(256) void scan_p2(const int* __restrict__ bsum, int* __restrict__ boff) {
  __shared__ int ps[256];
  int t = threadIdx.x;
  int v = (t < SCBLK) ? bsum[t] : 0;
  ps[t] = v;
  __syncthreads();
  for (int o = 1; o < 256; o <<= 1) {
    int u = (t >= o) ? ps[t - o] : 0;
    __syncthreads();
    ps[t] += u;
    __syncthreads();
  }
  if (t < SCBLK) boff[t] = ps[t] - v;   // exclusive
}
__global__ __launch_bounds__(256) void scan_p3(const int* __restrict__ deg2,
                                               const int* __restrict__ tmp_incl,
                                               const int* __restrict__ boff,
                                               int* __restrict__ in_off2, int* __restrict__ cursor2) {
  int t = threadIdx.x, blk = blockIdx.x;
  int i = blk * 256 + t;
  if (i < SCTOT) {
    int excl = boff[blk] + tmp_incl[i] - deg2[i];
    in_off2[i] = excl;
    cursor2[i] = excl;
  }
  if (i == 0) in_off2[SCTOT] = NE;
}

__global__ void csr_scatter2(const int* __restrict__ eidx, const int* __restrict__ etype,
                             int* __restrict__ cursor2,
                             int* __restrict__ in_e2, int* __restrict__ in_s2) {
  int e = blockIdx.x * 256 + threadIdx.x;
  if (e < NE) {
    int pos = atomicAdd(&cursor2[eidx[NE + e] * NR + etype[e]], 1);
    in_e2[pos] = e;
    in_s2[pos] = eidx[e];
  }
}

// ---------------- node-centric GAT, float4 column ownership ----------------
// Lane owns cols [lane*4,+4) (head hA=lane>>5) and [256+lane*4,+4) (head 2+hA).
// WeL read as conflict-free b128; att/erel/xr in regs; segmented 32-lane reductions.
// xlr [NN,2048]: for r_sub: xl at [rs*1024, +512), xr at [rs*1024+512, +512).
__global__ __launch_bounds__(256) void gat_node6(
    const int* __restrict__ in_off2, const int* __restrict__ in_e2, const int* __restrict__ in_s2,
    const float* __restrict__ eattr, const float* __restrict__ xlr,
    const float* __restrict__ We_base, const float* __restrict__ erel_base,
    const float* __restrict__ att_base, const float* __restrict__ gates,
    int rbase, float* __restrict__ hmsg) {
  __shared__ __align__(16) float WeL[16 * 512];
  __shared__ __align__(16) float sAgg[4][512];
  int tid = threadIdx.x;
  int rs = blockIdx.y;
  int r = rbase + rs;
  const float* We_r = We_base + (size_t)rs * 24 * 512;
  for (int i = tid; i < 16 * 512 / 4; i += 256)
    *(float4*)&WeL[i * 4] = *(const float4*)&We_r[i * 4];
  __syncthreads();
  float gr = gates[r] * 0.25f;
  int lane = tid & 63, wave = tid >> 6;
  int n = blockIdx.x * 4 + wave;
  if (n >= NN) return;
  int roff = rs * 1024;
  const int cA = lane * 4;         // head hA = lane>>5
  const int cB = 256 + lane * 4;   // head 2 + hA
  const float* xrb = xlr + (size_t)n * 2048 + roff + 512;
  float4 xrA = *(const float4*)(xrb + cA);
  float4 xrB = *(const float4*)(xrb + cB);
  float4 attA = *(const float4*)(att_base + rs * 512 + cA);
  float4 attB = *(const float4*)(att_base + rs * 512 + cB);
  float4 erA  = *(const float4*)(erel_base + rs * 512 + cA);
  float4 erB  = *(const float4*)(erel_base + rs * 512 + cB);
  float mA = -1e30f, mB = -1e30f, lsA = 0.f, lsB = 0.f;
  float4 accA = make_float4(0.f, 0.f, 0.f, 0.f);
  float4 accB = make_float4(0.f, 0.f, 0.f, 0.f);
  int e0 = in_off2[n * NR + r];
  int cnt = in_off2[n * NR + r + 1] - e0;
  // software pipeline: indices 2 ahead, payload 1 ahead
  float4 pxA, pxB, pe0, pe1, pe2, pe3;
  int eN = 0, sN = 0;
  if (cnt > 0) {
    int eC = in_e2[e0], sC = in_s2[e0];
    if (cnt > 1) { eN = in_e2[e0 + 1]; sN = in_s2[e0 + 1]; }
    const float* xls = xlr + (size_t)sC * 2048 + roff;
    pxA = *(const float4*)(xls + cA);
    pxB = *(const float4*)(xls + cB);
    const float4* eap = (const float4*)(eattr + (size_t)eC * 16);
    pe0 = eap[0]; pe1 = eap[1]; pe2 = eap[2]; pe3 = eap[3];
  }
  for (int j = 0; j < cnt; ++j) {
    float4 xA = pxA, xB = pxB;
    float ea[16] = {pe0.x, pe0.y, pe0.z, pe0.w, pe1.x, pe1.y, pe1.z, pe1.w,
                    pe2.x, pe2.y, pe2.z, pe2.w, pe3.x, pe3.y, pe3.z, pe3.w};
    if (j + 1 < cnt) {
      int eC = eN, sC = sN;
      if (j + 2 < cnt) { eN = in_e2[e0 + j + 2]; sN = in_s2[e0 + j + 2]; }
      const float* xls = xlr + (size_t)sC * 2048 + roff;
      pxA = *(const float4*)(xls + cA);
      pxB = *(const float4*)(xls + cB);
      const float4* eap = (const float4*)(eattr + (size_t)eC * 16);
      pe0 = eap[0]; pe1 = eap[1]; pe2 = eap[2]; pe3 = eap[3];
    }
    // et = erel + ea @ We (conflict-free b128 LDS reads)
    float4 etA = erA, etB = erB;
#pragma unroll
    for (int k = 0; k < 16; ++k) {
      float4 wA = *(const float4*)&WeL[k * 512 + cA];
      float4 wB = *(const float4*)&WeL[k * 512 + cB];
      etA.x = fmaf(ea[k], wA.x, etA.x); etA.y = fmaf(ea[k], wA.y, etA.y);
      etA.z = fmaf(ea[k], wA.z, etA.z); etA.w = fmaf(ea[k], wA.w, etA.w);
      etB.x = fmaf(ea[k], wB.x, etB.x); etB.y = fmaf(ea[k], wB.y, etB.y);
      etB.z = fmaf(ea[k], wB.z, etB.z); etB.w = fmaf(ea[k], wB.w, etB.w);
    }
    // z = leaky(xl + xr + et); partial att-dot per lane
    float sA, sB;
    {
      float z0 = xA.x + xrA.x + etA.x; z0 = (z0 > 0.f) ? z0 : 0.2f * z0;
      float z1 = xA.y + xrA.y + etA.y; z1 = (z1 > 0.f) ? z1 : 0.2f * z1;
      float z2 = xA.z + xrA.z + etA.z; z2 = (z2 > 0.f) ? z2 : 0.2f * z2;
      float z3 = xA.w + xrA.w + etA.w; z3 = (z3 > 0.f) ? z3 : 0.2f * z3;
      sA = z0 * attA.x + z1 * attA.y + z2 * attA.z + z3 * attA.w;
      z0 = xB.x + xrB.x + etB.x; z0 = (z0 > 0.f) ? z0 : 0.2f * z0;
      z1 = xB.y + xrB.y + etB.y; z1 = (z1 > 0.f) ? z1 : 0.2f * z1;
      z2 = xB.z + xrB.z + etB.z; z2 = (z2 > 0.f) ? z2 : 0.2f * z2;
      z3 = xB.w + xrB.w + etB.w; z3 = (z3 > 0.f) ? z3 : 0.2f * z3;
      sB = z0 * attB.x + z1 * attB.y + z2 * attB.z + z3 * attB.w;
    }
    // segmented reduction within 32-lane halves (head-local)
#pragma unroll
    for (int o = 1; o <= 16; o <<= 1) {
      sA += __shfl_xor(sA, o, 64);
      sB += __shfl_xor(sB, o, 64);
    }
    // online softmax, 2 heads per lane
    {
      float mn = fmaxf(mA, sA);
      float sc = expf(mA - mn), we = expf(sA - mn);
      mA = mn; lsA = lsA * sc + we;
      accA.x = accA.x * sc + we * xA.x; accA.y = accA.y * sc + we * xA.y;
      accA.z = accA.z * sc + we * xA.z; accA.w = accA.w * sc + we * xA.w;
    }
    {
      float mn = fmaxf(mB, sB);
      float sc = expf(mB - mn), we = expf(sB - mn);
      mB = mn; lsB = lsB * sc + we;
      accB.x = accB.x * sc + we * xB.x; accB.y = accB.y * sc + we * xB.y;
      accB.z = accB.z * sc + we * xB.z; accB.w = accB.w * sc + we * xB.w;
    }
  }
  float invA = 1.f / fmaxf(lsA, 1e-16f);
  float invB = 1.f / fmaxf(lsB, 1e-16f);
  *(float4*)&sAgg[wave][cA] = make_float4(accA.x * invA, accA.y * invA, accA.z * invA, accA.w * invA);
  *(float4*)&sAgg[wave][cB] = make_float4(accB.x * invB, accB.y * invB, accB.z * invB, accB.w * invB);
  // wave-local LDS transpose for head-mean (same-wave ordering via lgkmcnt)
  float o0 = sAgg[wave][lane]       + sAgg[wave][128 + lane]
           + sAgg[wave][256 + lane] + sAgg[wave][384 + lane];
  float o1 = sAgg[wave][64 + lane]  + sAgg[wave][192 + lane]
           + sAgg[wave][320 + lane] + sAgg[wave][448 + lane];
  size_t base = (size_t)n * HID;
  atomicAdd(&hmsg[base + lane],      gr * o0);
  atomicAdd(&hmsg[base + 64 + lane], gr * o1);
}

// ---------------- LayerNorm over 128 dims (optionally emits hi/lo bf16) ----------------
__global__ __launch_bounds__(64) void ln128(
    float* __restrict__ h, const float* __restrict__ add, const float* __restrict__ bvec,
    const float* __restrict__ g, const float* __restrict__ b,
    ushort* __restrict__ hh, ushort* __restrict__ hl) {
  int n = blockIdx.x, lane = threadIdx.x;
  size_t base = (size_t)n * HID;
  float x0 = h[base + lane] + add[base + lane];
  float x1 = h[base + 64 + lane] + add[base + 64 + lane];
  if (bvec) { x0 += bvec[lane]; x1 += bvec[64 + lane]; }
  float s = x0 + x1;
#pragma unroll
  for (int m = 32; m > 0; m >>= 1) s += __shfl_xor(s, m, 64);
  float mu = s * (1.f / 128.f);
  float d0 = x0 - mu, d1 = x1 - mu;
  float q = d0 * d0 + d1 * d1;
#pragma unroll
  for (int m = 32; m > 0; m >>= 1) q += __shfl_xor(q, m, 64);
  float inv = 1.f / sqrtf(q * (1.f / 128.f) + 1e-5f);
  float o0 = d0 * inv * g[lane] + b[lane];
  float o1 = d1 * inv * g[64 + lane] + b[64 + lane];
  h[base + lane]      = o0;
  h[base + 64 + lane] = o1;
  if (hh) {
    ushort i0 = f2bf(o0), i1 = f2bf(o1);
    hh[base + lane] = i0;        hh[base + 64 + lane] = i1;
    hl[base + lane] = f2bf(o0 - bf2f(i0));
    hl[base + 64 + lane] = f2bf(o1 - bf2f(i1));
  }
}

// ---------------- KAN expansion (fp32) — tiny readout head only ----------------
__global__ void expand_f32(const float* __restrict__ v, float* __restrict__ u, int In, int rows) {
  int i = blockIdx.x * 256 + threadIdx.x;
  if (i >= rows * In) return;
  int n = i / In, c = i % In;
  float x = v[(size_t)n * In + c];
  size_t base = (size_t)n * In * 9;
  u[base + c] = silu_f(x);
  float b8[8];
  kan_bases(x, b8);
  float* ub = u + base + In + (size_t)c * 8;
#pragma unroll
  for (int gq = 0; gq < 8; ++gq) ub[gq] = b8[gq];
}

// ---------------- atomic-free pooling, stage 1: per-chunk partials ----------------
__global__ __launch_bounds__(128) void pool_part(
    const float* __restrict__ h, const int* __restrict__ batch,
    float* __restrict__ psum, float* __restrict__ pmax, float* __restrict__ pcnt) {
  __shared__ float sS[NG][HID];
  __shared__ float sM[NG][HID];
  __shared__ int sC[NG];
  int d = threadIdx.x, blk = blockIdx.x;
  const float NEGINF = __uint_as_float(0xff800000u);  // -inf
  for (int i = d; i < NG * HID; i += 128) {
    ((float*)sS)[i] = 0.f;
    ((float*)sM)[i] = NEGINF;
  }
  if (d < NG) sC[d] = 0;
  __syncthreads();
  const int CH = (NN + NCHUNK - 1) / NCHUNK;  // 79
  int n0 = blk * CH, n1 = (n0 + CH < NN) ? n0 + CH : NN;
  for (int n = n0; n < n1; ++n) {
    int g = batch[n];
    float v = h[(size_t)n * HID + d];
    sS[g][d] += v;
    sM[g][d] = fmaxf(sM[g][d], v);
    if (d == 0) sC[g]++;
  }
  __syncthreads();
  for (int i = d; i < NG * HID; i += 128) {
    psum[(size_t)blk * NG * HID + i] = ((float*)sS)[i];
    pmax[(size_t)blk * NG * HID + i] = ((float*)sM)[i];
  }
  if (d < NG) pcnt[blk * NG + d] = (float)sC[d];
}

// ---------------- pooling stage 2 + readout LN ----------------
__global__ __launch_bounds__(256) void pool_final2(
    const float* __restrict__ psum, const float* __restrict__ pmax,
    const float* __restrict__ pcnt, const float* __restrict__ rog,
    const float* __restrict__ rob, float* __restrict__ gvec) {
  int g = blockIdx.x, j = threadIdx.x;
  __shared__ float rb[256];
  float x;
  if (j < HID) {
    float s = 0.f, cn = 0.f;
    for (int c = 0; c < NCHUNK; ++c) {
      s += psum[(size_t)c * NG * HID + g * HID + j];
      cn += pcnt[c * NG + g];
    }
    x = s / fmaxf(cn, 1.f);
  } else {
    float mx = __uint_as_float(0xff800000u);
    for (int c = 0; c < NCHUNK; ++c)
      mx = fmaxf(mx, pmax[(size_t)c * NG * HID + g * HID + (j - HID)]);
    x = (mx > -1e38f) ? mx : 0.f;  // where(isfinite, ., 0)
  }
  rb[j] = x; __syncthreads();
  for (int st = 128; st > 0; st >>= 1) { if (j < st) rb[j] += rb[j + st]; __syncthreads(); }
  float mu = rb[0] * (1.f / 256.f); __syncthreads();
  float d = x - mu;
  rb[j] = d * d; __syncthreads();
  for (int st = 128; st > 0; st >>= 1) { if (j < st) rb[j] += rb[j + st]; __syncthreads(); }
  float var = rb[0] * (1.f / 256.f);
  float inv = 1.f / sqrtf(var + 1e-5f);
  gvec[(size_t)g * 256 + j] = d * inv * rog[j] + rob[j];
}

// ---------------- wave-parallel KAN head: one wave per (graph, output) ----------------
__global__ __launch_bounds__(256) void kan_head_w(
    const float* __restrict__ u, const float* __restrict__ base_w,
    const float* __restrict__ spline_w, const float* __restrict__ scaler,
    float* __restrict__ out, int In, int Out, int npairs) {
  int wid = blockIdx.x * 4 + (threadIdx.x >> 6);
  if (wid >= npairs) return;
  int g = wid / Out, o = wid % Out;
  int lane = threadIdx.x & 63;
  const float* ug = u + (size_t)g * In * 9;
  const float* bw = base_w + (size_t)o * In;
  const float* sp = spline_w + (size_t)o * In * 8;
  const float* sc = scaler + (size_t)o * In;
  float acc = 0.f;
  for (int i = lane; i < In; i += 64) acc = fmaf(ug[i], bw[i], acc);
  const float* us = ug + In;
  for (int k = lane; k < In * 8; k += 64) {
    int i = k >> 3;
    acc = fmaf(us[k], sp[k] * sc[i], acc);
  }
#pragma unroll
  for (int off2 = 32; off2 > 0; off2 >>= 1) acc += __shfl_xor(acc, off2, 64);
  if (lane == 0) out[(size_t)g * Out + o] = acc;
}

// ---------------- launch ----------------
extern "C" void kernel_launch(void* const* d_in, const int* in_sizes, int n_in,
                              void* d_out, int out_size, void* d_ws, size_t ws_size,
                              hipStream_t stream) {
  const float* x         = (const float*)d_in[0];
  const float* edge_attr = (const float*)d_in[1];
  const int*   id_token  = (const int*)  d_in[2];
  const int*   edge_index= (const int*)  d_in[3];
  const int*   edge_type = (const int*)  d_in[4];
  const int*   batch     = (const int*)  d_in[5];
  const float* id_emb    = (const float*)d_in[6];
  const float* inW       = (const float*)d_in[7];
  const float* inb       = (const float*)d_in[8];
  const float* Wl        = (const float*)d_in[9];
  const float* bl        = (const float*)d_in[10];
  const float* Wr        = (const float*)d_in[11];
  const float* br        = (const float*)d_in[12];
  const float* We        = (const float*)d_in[13];
  const float* att       = (const float*)d_in[14];
  const float* gat_bias  = (const float*)d_in[15];
  const float* rel_gate  = (const float*)d_in[16];
  const float* rel_emb   = (const float*)d_in[17];
  const float* ln1g      = (const float*)d_in[18];
  const float* ln1b      = (const float*)d_in[19];
  const float* ln2g      = (const float*)d_in[20];
  const float* ln2b      = (const float*)d_in[21];
  const float* ffn1_base = (const float*)d_in[22];
  const float* ffn1_spl  = (const float*)d_in[23];
  const float* ffn1_sc   = (const float*)d_in[24];
  const float* ffn2_base = (const float*)d_in[25];
  const float* ffn2_spl  = (const float*)d_in[26];
  const float* ffn2_sc   = (const float*)d_in[27];
  const float* rog       = (const float*)d_in[28];
  const float* rob       = (const float*)d_in[29];
  const float* h1_base   = (const float*)d_in[30];
  const float* h1_spl    = (const float*)d_in[31];
  const float* h1_sc     = (const float*)d_in[32];
  const float* h2_base   = (const float*)d_in[33];
  const float* h2_spl    = (const float*)d_in[34];
  const float* h2_sc     = (const float*)d_in[35];
  (void)in_sizes; (void)n_in; (void)out_size; (void)ws_size;

  // ---- workspace carve (256B aligned) ----
  char* wsp = (char*)d_ws;
  size_t off = 0;
  auto carve = [&](size_t bytes) { char* p = wsp + off; off = (off + bytes + 255) & ~(size_t)255; return p; };
  float*    h     = (float*)   carve((size_t)NN * HID * 4);
  ushort*   h_hi  = (ushort*)  carve((size_t)NN * HID * 2);
  ushort*   h_lo  = (ushort*)  carve((size_t)NN * HID * 2);
  float*    hmsg  = (float*)   carve((size_t)NN * HID * 4);
  float*    t1    = (float*)   carve((size_t)NN * FFNH * 4);
  float*    gates = (float*)   carve(NR * 4);
  float*    msgb  = (float*)   carve(HID * 4);
  float*    erel  = (float*)   carve(NR * 512 * 4);
  ushort*   WTh   = (ushort*)  carve((size_t)NL * 2 * 2048 * HID * 2);
  ushort*   WTl   = (ushort*)  carve((size_t)NL * 2 * 2048 * HID * 2);
  float*    blr   = (float*)   carve((size_t)NL * 2 * 2048 * 4);
  ushort*   B1h   = (ushort*)  carve((size_t)FFNH * HID * 9 * 2);
  ushort*   B1l   = (ushort*)  carve((size_t)FFNH * HID * 9 * 2);
  ushort*   B2h   = (ushort*)  carve((size_t)HID * FFNH * 9 * 2);
  ushort*   B2l   = (ushort*)  carve((size_t)HID * FFNH * 9 * 2);
  float*    psum  = (float*)   carve((size_t)NCHUNK * NG * HID * 4);
  float*    pmax  = (float*)   carve((size_t)NCHUNK * NG * HID * 4);
  float*    pcnt  = (float*)   carve((size_t)NCHUNK * NG * 4);
  float*    gvec  = (float*)   carve((size_t)NG * 256 * 4);
  float*    uhead = (float*)   carve((size_t)NG * 256 * 9 * 4);
  float*    thead = (float*)   carve((size_t)NG * HEADH * 4);
  float*    xlr   = (float*)   carve((size_t)NN * 2048 * 4);        // 82 MB
  int*      deg2  = (int*)     carve((size_t)SCTOT * 4);
  int*      in_off2=(int*)     carve((size_t)(SCTOT + 1) * 4);
  int*      cursor2=(int*)     carve((size_t)SCTOT * 4);
  int*      tmp_incl=(int*)    carve((size_t)SCTOT * 4);
  int*      bsum  = (int*)     carve((size_t)SCBLK * 4);
  int*      boff  = (int*)     carve((size_t)SCBLK * 4);
  int*      in_e2 = (int*)     carve((size_t)NE * 4);
  int*      in_s2 = (int*)     carve((size_t)NE * 4);

  // ---- relation-sorted CSR build (once; graph static across layers) ----
  fill_zero_i<<<(SCTOT + 255) / 256, 256, 0, stream>>>(deg2, SCTOT);
  csr_count2<<<(NE + 255) / 256, 256, 0, stream>>>(edge_index, edge_type, deg2);
  scan_p1<<<SCBLK, 256, 0, stream>>>(deg2, tmp_incl, bsum);
  scan_p2<<<1, 256, 0, stream>>>(bsum, boff);
  scan_p3<<<SCBLK, 256, 0, stream>>>(deg2, tmp_incl, boff, in_off2, cursor2);
  csr_scatter2<<<(NE + 255) / 256, 256, 0, stream>>>(edge_index, edge_type, cursor2, in_e2, in_s2);

  // ---- weight transpose + split (once per launch) ----
  {
    int total = NL * 2 * 2048 * 128;
    conv_wT2<<<(total + 255) / 256, 256, 0, stream>>>(Wl, Wr, bl, br, WTh, WTl, blr, total);
  }

  // ---- input projection ----
  input_proj<<<NN, 128, 0, stream>>>(x, id_emb, id_token, inW, inb, h, h_hi, h_lo);

  const int MB128 = (NN + 127) / 128;  // 79
  const int MB64  = (NN + 63) / 64;    // 157
  for (int l = 0; l < NL; ++l) {
    layer_prep<<<1, 512, 0, stream>>>(rel_gate, gat_bias, rel_emb, We, l, gates, msgb, erel);
    fill_zero<<<(NN * HID + 255) / 256, 256, 0, stream>>>(hmsg, NN * HID);
    for (int pair = 0; pair < 2; ++pair) {
      int g2 = l * 2 + pair;
      const ushort* WThp = WTh + (size_t)g2 * 2048 * HID;
      const ushort* WTlp = WTl + (size_t)g2 * 2048 * HID;
      const float* blp   = blr + (size_t)g2 * 2048;
      int rbase = pair * 2;
      gemm_bf3<<<dim3(2048 / 64, MB128), 256, 0, stream>>>(h_hi, h_lo, WThp, WTlp, blp, xlr, NN, HID, 2048);
      gat_node6<<<dim3((NN + 3) / 4, 2), 256, 0, stream>>>(
          in_off2, in_e2, in_s2, edge_attr, xlr,
          We + ((size_t)(l * NR + rbase)) * 24 * 512, erel + rbase * 512,
          att + (size_t)(l * NR + rbase) * 512, gates, rbase, hmsg);
    }
    ln128<<<NN, 64, 0, stream>>>(h, hmsg, msgb, ln1g + l * HID, ln1b + l * HID, nullptr, nullptr);

    // ---- KAN FFN1: 128 -> 256 (K = 1152), fused expansion, split-K 3 ----
    build_kan_wT<<<((HID * 9 * FFNH) + 255) / 256, 256, 0, stream>>>(
        ffn1_base + (size_t)l * FFNH * HID, ffn1_spl + (size_t)l * FFNH * HID * 8,
        ffn1_sc + (size_t)l * FFNH * HID, B1h, B1l, HID, FFNH);
    fill_zero<<<(NN * FFNH + 255) / 256, 256, 0, stream>>>(t1, NN * FFNH);
    gemm_kan<128, 3><<<dim3(FFNH / 64, MB128, 3), 256, 0, stream>>>(h, B1h, B1l, t1, NN, HID, FFNH);
    // ---- KAN FFN2: 256 -> 128 (K = 2304), fused expansion, split-K 4 ----
    build_kan_wT<<<((FFNH * 9 * HID) + 255) / 256, 256, 0, stream>>>(
        ffn2_base + (size_t)l * HID * FFNH, ffn2_spl + (size_t)l * HID * FFNH * 8,
        ffn2_sc + (size_t)l * HID * FFNH, B2h, B2l, FFNH, HID);
    fill_zero<<<(NN * HID + 255) / 256, 256, 0, stream>>>(hmsg, NN * HID);
    gemm_kan<64, 4><<<dim3(HID / 64, MB64, 4), 256, 0, stream>>>(t1, B2h, B2l, hmsg, NN, FFNH, HID);
    ln128<<<NN, 64, 0, stream>>>(h, hmsg, nullptr, ln2g + l * HID, ln2b + l * HID, h_hi, h_lo);
  }

  // ---- readout (atomic-free pooling) ----
  pool_part<<<NCHUNK, 128, 0, stream>>>(h, batch, psum, pmax, pcnt);
  pool_final2<<<NG, 256, 0, stream>>>(psum, pmax, pcnt, rog, rob, gvec);
  expand_f32<<<((NG * 256) + 255) / 256, 256, 0, stream>>>(gvec, uhead, 256, NG);
  {
    int npairs = NG * HEADH;  // 4096 waves
    kan_head_w<<<(npairs + 3) / 4, 256, 0, stream>>>(uhead, h1_base, h1_spl, h1_sc, thead, 256, HEADH, npairs);
  }
  expand_f32<<<((NG * HEADH) + 255) / 256, 256, 0, stream>>>(thead, uhead, HEADH, NG);
  {
    int npairs = NG * NCLS;   // 320 waves
    kan_head_w<<<(npairs + 3) / 4, 256, 0, stream>>>(uhead, h2_base, h2_spl, h2_sc, (float*)d_out, HEADH, NCLS, npairs);
  }
}

// Round 14
// 1472.589 us; speedup vs baseline: 3.0252x; 1.0130x over previous
//
#include <hip/hip_runtime.h>
#include <cstdint>
#include <cstddef>

// ---------------- static problem config ----------------
#define NN      10000   // nodes
#define NE      120000  // edges
#define NG      32      // graphs
#define FNODE   64
#define FEDGE   16
#define HID     128
#define NHEADS  4
#define NL      3
#define NR      4
#define IDDIM   32
#define RELDIM  8
#define FFNH    256
#define HEADH   128
#define NCLS    10

#define NCHUNK  128     // pooling stage-1 blocks
#define SCTOT   (NN * NR)            // 40000 scan entries
#define SCBLK   ((SCTOT + 255) / 256)  // 157 scan blocks

typedef __attribute__((ext_vector_type(8))) short short8;
typedef __attribute__((ext_vector_type(4))) float floatx4;

// ---------------- helpers ----------------
__device__ __forceinline__ float silu_f(float x) { return x / (1.f + expf(-x)); }
__device__ __forceinline__ ushort f2bf(float f) {   // round-to-nearest-even bf16
  unsigned u = __float_as_uint(f);
  return (ushort)((u + 0x7FFFu + ((u >> 16) & 1u)) >> 16);
}
__device__ __forceinline__ float bf2f(ushort h) { return __uint_as_float((unsigned)h << 16); }

// Cox–de Boor cubic bases on grid t_j = (j-3)*0.4 - 1 (GRID_SIZE=5, ORDER=3) -> 8 bases
__device__ __forceinline__ void kan_bases(float x, float* out8) {
  float bb[11];
#pragma unroll
  for (int j = 0; j < 11; ++j) {
    float t0 = (j - 3) * 0.4f - 1.f;
    float t1 = (j - 2) * 0.4f - 1.f;
    bb[j] = (x >= t0 && x < t1) ? 1.f : 0.f;
  }
  {
    const float inv = 1.f / 0.4f;
#pragma unroll
    for (int j = 0; j < 10; ++j) {
      float tj = (j - 3) * 0.4f - 1.f, tjp1 = (j - 1) * 0.4f - 1.f;
      bb[j] = ((x - tj) * bb[j] + (tjp1 - x) * bb[j + 1]) * inv;
    }
  }
  {
    const float inv = 1.f / 0.8f;
#pragma unroll
    for (int j = 0; j < 9; ++j) {
      float tj = (j - 3) * 0.4f - 1.f, tjp1 = (j) * 0.4f - 1.f;
      bb[j] = ((x - tj) * bb[j] + (tjp1 - x) * bb[j + 1]) * inv;
    }
  }
  {
    const float inv = 1.f / 1.2000001f;
#pragma unroll
    for (int j = 0; j < 8; ++j) {
      float tj = (j - 3) * 0.4f - 1.f, tjp1 = (j + 1) * 0.4f - 1.f;
      bb[j] = ((x - tj) * bb[j] + (tjp1 - x) * bb[j + 1]) * inv;
    }
  }
#pragma unroll
  for (int j = 0; j < 8; ++j) out8[j] = bb[j];
}

// ---------------- 3-term MFMA GEMM, operands pre-split bf16 hi/lo ----------------
__global__ __launch_bounds__(256) void gemm_bf3(
    const ushort* __restrict__ Ahg, const ushort* __restrict__ Alg,
    const ushort* __restrict__ Bhg, const ushort* __restrict__ Blg,
    const float* __restrict__ bias, float* __restrict__ C,
    int M, int K, int N) {
  constexpr int LDA = 68;
  __shared__ __align__(16) ushort Ah[128 * LDA];
  __shared__ __align__(16) ushort Al[128 * LDA];
  __shared__ __align__(16) ushort Bh[64 * LDA];
  __shared__ __align__(16) ushort Bl[64 * LDA];
  const int tid = threadIdx.x;
  const int lane = tid & 63, wave = tid >> 6;
  const int lrow = lane & 15, quad = lane >> 4;
  const int bm = blockIdx.y * 128, bn = blockIdx.x * 64;
  floatx4 acc[2][4] = {};
  for (int k0 = 0; k0 < K; k0 += 64) {
#pragma unroll
    for (int i = 0; i < 4; ++i) {
      int c = tid + i * 256;
      int row = c >> 3, col8 = c & 7;
      int gr = bm + row;
      uint4 vh = make_uint4(0, 0, 0, 0), vl = make_uint4(0, 0, 0, 0);
      if (gr < M) {
        vh = *(const uint4*)(Ahg + (size_t)gr * K + k0 + col8 * 8);
        vl = *(const uint4*)(Alg + (size_t)gr * K + k0 + col8 * 8);
      }
      *(uint4*)&Ah[row * LDA + col8 * 8] = vh;
      *(uint4*)&Al[row * LDA + col8 * 8] = vl;
    }
#pragma unroll
    for (int i = 0; i < 2; ++i) {
      int c = tid + i * 256;
      int row = c >> 3, col8 = c & 7;
      *(uint4*)&Bh[row * LDA + col8 * 8] = *(const uint4*)(Bhg + (size_t)(bn + row) * K + k0 + col8 * 8);
      *(uint4*)&Bl[row * LDA + col8 * 8] = *(const uint4*)(Blg + (size_t)(bn + row) * K + k0 + col8 * 8);
    }
    __syncthreads();
#pragma unroll
    for (int kk = 0; kk < 64; kk += 32) {
      int kof = kk + quad * 8;
      const int ra0 = (wave * 32 + lrow) * LDA + kof;
      const int ra1 = (wave * 32 + 16 + lrow) * LDA + kof;
      short8 ah0 = *(const short8*)&Ah[ra0];
      short8 ah1 = *(const short8*)&Ah[ra1];
      short8 al0 = *(const short8*)&Al[ra0];
      short8 al1 = *(const short8*)&Al[ra1];
      short8 bh[4], blo[4];
#pragma unroll
      for (int nt = 0; nt < 4; ++nt) {
        int rb = (nt * 16 + lrow) * LDA + kof;
        bh[nt]  = *(const short8*)&Bh[rb];
        blo[nt] = *(const short8*)&Bl[rb];
      }
#pragma unroll
      for (int nt = 0; nt < 4; ++nt) {
        acc[0][nt] = __builtin_amdgcn_mfma_f32_16x16x32_bf16(ah0, bh[nt],  acc[0][nt], 0, 0, 0);
        acc[1][nt] = __builtin_amdgcn_mfma_f32_16x16x32_bf16(ah1, bh[nt],  acc[1][nt], 0, 0, 0);
        acc[0][nt] = __builtin_amdgcn_mfma_f32_16x16x32_bf16(al0, bh[nt],  acc[0][nt], 0, 0, 0);
        acc[1][nt] = __builtin_amdgcn_mfma_f32_16x16x32_bf16(al1, bh[nt],  acc[1][nt], 0, 0, 0);
        acc[0][nt] = __builtin_amdgcn_mfma_f32_16x16x32_bf16(ah0, blo[nt], acc[0][nt], 0, 0, 0);
        acc[1][nt] = __builtin_amdgcn_mfma_f32_16x16x32_bf16(ah1, blo[nt], acc[1][nt], 0, 0, 0);
      }
    }
    __syncthreads();
  }
#pragma unroll
  for (int mt = 0; mt < 2; ++mt) {
#pragma unroll
    for (int nt = 0; nt < 4; ++nt) {
#pragma unroll
      for (int reg = 0; reg < 4; ++reg) {
        int row = bm + wave * 32 + mt * 16 + quad * 4 + reg;
        int col = bn + nt * 16 + lrow;
        if (row < M) {
          float v = acc[mt][nt][reg];
          if (bias) v += bias[col];
          C[(size_t)row * N + col] = v;
        }
      }
    }
  }
}

// ---------------- fused KAN GEMM, BM=64, BN=NT*16, split-K: C += expand(A) @ BT^T ------
// A: fp32 [M,In]; expansion (silu | 8 cubic bases) + hi/lo split during staging, all 256
// threads active. B pre-split bf16 hi/lo [N, In*9]. Grid (N/BN, M/64, SPLIT).
template<int NT, int SPLIT>
__global__ __launch_bounds__(256) void gemm_kan(
    const float* __restrict__ A, const ushort* __restrict__ Bhg, const ushort* __restrict__ Blg,
    float* __restrict__ C, int M, int In, int N) {
  const int K = In * 9;
  const int ntiles = K >> 6;
  const int per = (ntiles + SPLIT - 1) / SPLIT;
  const int kt0 = blockIdx.z * per;
  const int kt1 = (kt0 + per < ntiles) ? (kt0 + per) : ntiles;
  constexpr int LDA = 68;
  constexpr int BN = NT * 16;
  __shared__ __align__(16) ushort Ah[64 * LDA];
  __shared__ __align__(16) ushort Al[64 * LDA];
  __shared__ __align__(16) ushort Bh[BN * LDA];
  __shared__ __align__(16) ushort Bl[BN * LDA];
  const int tid = threadIdx.x;
  const int lane = tid & 63, wave = tid >> 6;
  const int lrow = lane & 15, quad = lane >> 4;
  const int bm = blockIdx.y * 64, bn = blockIdx.x * BN;
  floatx4 acc[NT] = {};
  for (int kt = kt0; kt < kt1; ++kt) {
    int k0 = kt << 6;
    if (k0 < In) {
      // silu region: 64 rows x 64 cols
#pragma unroll
      for (int i = 0; i < 4; ++i) {
        int c = tid + i * 256;
        int row = c >> 4, col4 = c & 15;
        int gr = bm + row;
        float4 v = make_float4(0.f, 0.f, 0.f, 0.f);
        if (gr < M) v = *(const float4*)(A + (size_t)gr * In + k0 + col4 * 4);
        float vv[4] = {silu_f(v.x), silu_f(v.y), silu_f(v.z), silu_f(v.w)};
        ushort h0 = f2bf(vv[0]), h1 = f2bf(vv[1]), h2 = f2bf(vv[2]), h3 = f2bf(vv[3]);
        ushort l0 = f2bf(vv[0] - bf2f(h0)), l1 = f2bf(vv[1] - bf2f(h1));
        ushort l2 = f2bf(vv[2] - bf2f(h2)), l3 = f2bf(vv[3] - bf2f(h3));
        *(uint2*)&Ah[row * LDA + col4 * 4] =
          make_uint2((unsigned)h0 | ((unsigned)h1 << 16), (unsigned)h2 | ((unsigned)h3 << 16));
        *(uint2*)&Al[row * LDA + col4 * 4] =
          make_uint2((unsigned)l0 | ((unsigned)l1 << 16), (unsigned)l2 | ((unsigned)l3 << 16));
      }
    } else {
      // spline region: 64 rows x 8 input cols, all 256 threads (2 kan_bases each)
      int i0 = (k0 - In) >> 3;
      int row = tid >> 2, q = tid & 3;
      int gr = bm + row;
      float2 v = make_float2(0.f, 0.f);
      if (gr < M) v = *(const float2*)(A + (size_t)gr * In + i0 + q * 2);
      float vv[2] = {v.x, v.y};
#pragma unroll
      for (int jj = 0; jj < 2; ++jj) {
        float b8[8];
        kan_bases(vv[jj], b8);
        unsigned hu[4], lu[4];
#pragma unroll
        for (int p = 0; p < 4; ++p) {
          ushort ha = f2bf(b8[2 * p]), hb = f2bf(b8[2 * p + 1]);
          ushort la = f2bf(b8[2 * p] - bf2f(ha)), lb = f2bf(b8[2 * p + 1] - bf2f(hb));
          hu[p] = (unsigned)ha | ((unsigned)hb << 16);
          lu[p] = (unsigned)la | ((unsigned)lb << 16);
        }
        int cbase = (q * 2 + jj) * 8;
        *(uint4*)&Ah[row * LDA + cbase] = make_uint4(hu[0], hu[1], hu[2], hu[3]);
        *(uint4*)&Al[row * LDA + cbase] = make_uint4(lu[0], lu[1], lu[2], lu[3]);
      }
    }
    // stage B hi/lo: BN rows x 64 cols
#pragma unroll
    for (int i = 0; i < NT / 2; ++i) {
      int c = tid + i * 256;
      int row = c >> 3, col8 = c & 7;
      *(uint4*)&Bh[row * LDA + col8 * 8] = *(const uint4*)(Bhg + (size_t)(bn + row) * K + k0 + col8 * 8);
      *(uint4*)&Bl[row * LDA + col8 * 8] = *(const uint4*)(Blg + (size_t)(bn + row) * K + k0 + col8 * 8);
    }
    __syncthreads();
#pragma unroll
    for (int kk = 0; kk < 64; kk += 32) {
      int kof = kk + quad * 8;
      int ra = (wave * 16 + lrow) * LDA + kof;
      short8 ah = *(const short8*)&Ah[ra];
      short8 al = *(const short8*)&Al[ra];
#pragma unroll
      for (int nt = 0; nt < NT; ++nt) {
        int rb = (nt * 16 + lrow) * LDA + kof;
        short8 bh  = *(const short8*)&Bh[rb];
        short8 blo = *(const short8*)&Bl[rb];
        acc[nt] = __builtin_amdgcn_mfma_f32_16x16x32_bf16(ah, bh,  acc[nt], 0, 0, 0);
        acc[nt] = __builtin_amdgcn_mfma_f32_16x16x32_bf16(al, bh,  acc[nt], 0, 0, 0);
        acc[nt] = __builtin_amdgcn_mfma_f32_16x16x32_bf16(ah, blo, acc[nt], 0, 0, 0);
      }
    }
    __syncthreads();
  }
#pragma unroll
  for (int nt = 0; nt < NT; ++nt) {
#pragma unroll
    for (int reg = 0; reg < 4; ++reg) {
      int row = bm + wave * 16 + quad * 4 + reg;
      int col = bn + nt * 16 + lrow;
      if (row < M) atomicAdd(&C[(size_t)row * N + col], acc[nt][reg]);
    }
  }
}

// ---------------- weight transpose+split: relation pairs -> [L*2][2048][128] ----------------
__global__ void conv_wT2(const float* __restrict__ Wl, const float* __restrict__ Wr,
                         const float* __restrict__ bl, const float* __restrict__ br,
                         ushort* __restrict__ WTh, ushort* __restrict__ WTl,
                         float* __restrict__ bout, int total) {
  int i = blockIdx.x * 256 + threadIdx.x;
  if (i >= total) return;
  int g2 = i / (2048 * 128), rem = i % (2048 * 128);
  int n = rem >> 7, k = rem & 127;
  int l = g2 >> 1, pair = g2 & 1;
  int r = pair * 2 + (n >> 10);          // relation within layer
  int nsub = n & 1023;                   // 0..1023 within [Wl|Wr]
  int nn = nsub & 511;
  int g = l * NR + r;
  const float* W = (nsub < 512) ? Wl : Wr;
  float v = W[(size_t)g * 65536 + (size_t)k * 512 + nn];
  ushort hi = f2bf(v);
  WTh[i] = hi;
  WTl[i] = f2bf(v - bf2f(hi));
  if (k == 0) bout[g2 * 2048 + n] = ((nsub < 512) ? bl : br)[g * 512 + nn];
}

// ---------------- build expanded KAN weight, transposed + split ----------------
__global__ void build_kan_wT(const float* __restrict__ base_w, const float* __restrict__ spline_w,
                             const float* __restrict__ scaler,
                             ushort* __restrict__ BTh, ushort* __restrict__ BTl,
                             int In, int Out) {
  int i = blockIdx.x * 256 + threadIdx.x;
  if (i >= In * 9 * Out) return;
  int o = i / (In * 9), k = i % (In * 9);
  float v;
  if (k < In) v = base_w[(size_t)o * In + k];
  else {
    int q = k - In, ii = q >> 3, gq = q & 7;
    v = spline_w[((size_t)o * In + ii) * 8 + gq] * scaler[(size_t)o * In + ii];
  }
  ushort hi = f2bf(v);
  BTh[i] = hi;
  BTl[i] = f2bf(v - bf2f(hi));
}

// ---------------- input projection (fp32 h + hi/lo bf16) ----------------
__global__ __launch_bounds__(128) void input_proj(
    const float* __restrict__ x, const float* __restrict__ id_emb,
    const int* __restrict__ id_token, const float* __restrict__ inW,
    const float* __restrict__ inb, float* __restrict__ h,
    ushort* __restrict__ hh, ushort* __restrict__ hl) {
  int n = blockIdx.x, j = threadIdx.x;
  __shared__ float s[FNODE + IDDIM];
  if (j < FNODE) s[j] = x[(size_t)n * FNODE + j];
  else if (j < FNODE + IDDIM) s[j] = id_emb[(size_t)id_token[n] * IDDIM + (j - FNODE)];
  __syncthreads();
  float acc = inb[j];
#pragma unroll
  for (int k = 0; k < FNODE + IDDIM; ++k) acc = fmaf(s[k], inW[k * HID + j], acc);
  float v = silu_f(acc);
  h[(size_t)n * HID + j] = v;
  ushort hi = f2bf(v);
  hh[(size_t)n * HID + j] = hi;
  hl[(size_t)n * HID + j] = f2bf(v - bf2f(hi));
}

// ---------------- per-layer prep ----------------
__global__ __launch_bounds__(512) void layer_prep(
    const float* __restrict__ rel_gate, const float* __restrict__ gat_bias,
    const float* __restrict__ rel_emb, const float* __restrict__ We, int l,
    float* __restrict__ gates, float* __restrict__ msg_bias, float* __restrict__ erel) {
  int j = threadIdx.x;
  float g[NR]; float mx = -1e30f;
  for (int r = 0; r < NR; ++r) { g[r] = rel_gate[l * NR + r]; mx = fmaxf(mx, g[r]); }
  float s = 0.f;
  for (int r = 0; r < NR; ++r) { g[r] = expf(g[r] - mx); s += g[r]; }
  for (int r = 0; r < NR; ++r) g[r] /= s;
  if (j < NR) gates[j] = g[j];
  if (j < HID) {
    float b = 0.f;
    for (int r = 0; r < NR; ++r) b = fmaf(g[r], gat_bias[((size_t)(l * NR + r)) * HID + j], b);
    msg_bias[j] = b;
  }
  for (int r = 0; r < NR; ++r) {
    const float* Wer = We + ((size_t)(l * NR + r)) * 24 * 512;
    const float* re  = rel_emb + (l * NR + r) * RELDIM;
    float acc = 0.f;
#pragma unroll
    for (int q = 0; q < RELDIM; ++q) acc = fmaf(re[q], Wer[(FEDGE + q) * 512 + j], acc);
    erel[r * 512 + j] = acc;
  }
}

// ---------------- fills ----------------
__global__ void fill_zero(float* __restrict__ p, int n) {
  int i = blockIdx.x * 256 + threadIdx.x;
  if (i < n) p[i] = 0.f;
}
__global__ void fill_zero_i(int* __restrict__ p, int n) {
  int i = blockIdx.x * 256 + threadIdx.x;
  if (i < n) p[i] = 0;
}

// ---------------- relation-sorted CSR build: bins (target, relation) ----------------
__global__ void csr_count2(const int* __restrict__ eidx, const int* __restrict__ etype,
                           int* __restrict__ deg2) {
  int e = blockIdx.x * 256 + threadIdx.x;
  if (e < NE) atomicAdd(&deg2[eidx[NE + e] * NR + etype[e]], 1);
}

// ---- parallel 3-pass scan over deg2[SCTOT] ----
__global__ __launch_bounds__(256) void scan_p1(const int* __restrict__ deg2,
                                               int* __restrict__ tmp_incl, int* __restrict__ bsum) {
  __shared__ int ps[256];
  int t = threadIdx.x, blk = blockIdx.x;
  int i = blk * 256 + t;
  int v = (i < SCTOT) ? deg2[i] : 0;
  ps[t] = v;
  __syncthreads();
  for (int o = 1; o < 256; o <<= 1) {
    int u = (t >= o) ? ps[t - o] : 0;
    __syncthreads();
    ps[t] += u;
    __syncthreads();
  }
  if (i < SCTOT) tmp_incl[i] = ps[t];
  if (t == 255) bsum[blk] = ps[255];
}
__global__ __launch_bounds__(256) void scan_p2(const int* __restrict__ bsum, int* __restrict__ boff) {
  __shared__ int ps[256];
  int t = threadIdx.x;
  int v = (t < SCBLK) ? bsum[t] : 0;
  ps[t] = v;
  __syncthreads();
  for (int o = 1; o < 256; o <<= 1) {
    int u = (t >= o) ? ps[t - o] : 0;
    __syncthreads();
    ps[t] += u;
    __syncthreads();
  }
  if (t < SCBLK) boff[t] = ps[t] - v;   // exclusive
}
__global__ __launch_bounds__(256) void scan_p3(const int* __restrict__ deg2,
                                               const int* __restrict__ tmp_incl,
                                               const int* __restrict__ boff,
                                               int* __restrict__ in_off2, int* __restrict__ cursor2) {
  int t = threadIdx.x, blk = blockIdx.x;
  int i = blk * 256 + t;
  if (i < SCTOT) {
    int excl = boff[blk] + tmp_incl[i] - deg2[i];
    in_off2[i] = excl;
    cursor2[i] = excl;
  }
  if (i == 0) in_off2[SCTOT] = NE;
}

__global__ void csr_scatter2(const int* __restrict__ eidx, const int* __restrict__ etype,
                             int* __restrict__ cursor2,
                             int* __restrict__ in_e2, int* __restrict__ in_s2) {
  int e = blockIdx.x * 256 + threadIdx.x;
  if (e < NE) {
    int pos = atomicAdd(&cursor2[eidx[NE + e] * NR + etype[e]], 1);
    in_e2[pos] = e;
    in_s2[pos] = eidx[e];
  }
}

// ---------------- node-centric GAT, float4 column ownership ----------------
__global__ __launch_bounds__(256) void gat_node6(
    const int* __restrict__ in_off2, const int* __restrict__ in_e2, const int* __restrict__ in_s2,
    const float* __restrict__ eattr, const float* __restrict__ xlr,
    const float* __restrict__ We_base, const float* __restrict__ erel_base,
    const float* __restrict__ att_base, const float* __restrict__ gates,
    int rbase, float* __restrict__ hmsg) {
  __shared__ __align__(16) float WeL[16 * 512];
  __shared__ __align__(16) float sAgg[4][512];
  int tid = threadIdx.x;
  int rs = blockIdx.y;
  int r = rbase + rs;
  const float* We_r = We_base + (size_t)rs * 24 * 512;
  for (int i = tid; i < 16 * 512 / 4; i += 256)
    *(float4*)&WeL[i * 4] = *(const float4*)&We_r[i * 4];
  __syncthreads();
  float gr = gates[r] * 0.25f;
  int lane = tid & 63, wave = tid >> 6;
  int n = blockIdx.x * 4 + wave;
  if (n >= NN) return;
  int roff = rs * 1024;
  const int cA = lane * 4;         // head hA = lane>>5
  const int cB = 256 + lane * 4;   // head 2 + hA
  const float* xrb = xlr + (size_t)n * 2048 + roff + 512;
  float4 xrA = *(const float4*)(xrb + cA);
  float4 xrB = *(const float4*)(xrb + cB);
  float4 attA = *(const float4*)(att_base + rs * 512 + cA);
  float4 attB = *(const float4*)(att_base + rs * 512 + cB);
  float4 erA  = *(const float4*)(erel_base + rs * 512 + cA);
  float4 erB  = *(const float4*)(erel_base + rs * 512 + cB);
  float mA = -1e30f, mB = -1e30f, lsA = 0.f, lsB = 0.f;
  float4 accA = make_float4(0.f, 0.f, 0.f, 0.f);
  float4 accB = make_float4(0.f, 0.f, 0.f, 0.f);
  int e0 = in_off2[n * NR + r];
  int cnt = in_off2[n * NR + r + 1] - e0;
  float4 pxA, pxB, pe0, pe1, pe2, pe3;
  int eN = 0, sN = 0;
  if (cnt > 0) {
    int eC = in_e2[e0], sC = in_s2[e0];
    if (cnt > 1) { eN = in_e2[e0 + 1]; sN = in_s2[e0 + 1]; }
    const float* xls = xlr + (size_t)sC * 2048 + roff;
    pxA = *(const float4*)(xls + cA);
    pxB = *(const float4*)(xls + cB);
    const float4* eap = (const float4*)(eattr + (size_t)eC * 16);
    pe0 = eap[0]; pe1 = eap[1]; pe2 = eap[2]; pe3 = eap[3];
  }
  for (int j = 0; j < cnt; ++j) {
    float4 xA = pxA, xB = pxB;
    float ea[16] = {pe0.x, pe0.y, pe0.z, pe0.w, pe1.x, pe1.y, pe1.z, pe1.w,
                    pe2.x, pe2.y, pe2.z, pe2.w, pe3.x, pe3.y, pe3.z, pe3.w};
    if (j + 1 < cnt) {
      int eC = eN, sC = sN;
      if (j + 2 < cnt) { eN = in_e2[e0 + j + 2]; sN = in_s2[e0 + j + 2]; }
      const float* xls = xlr + (size_t)sC * 2048 + roff;
      pxA = *(const float4*)(xls + cA);
      pxB = *(const float4*)(xls + cB);
      const float4* eap = (const float4*)(eattr + (size_t)eC * 16);
      pe0 = eap[0]; pe1 = eap[1]; pe2 = eap[2]; pe3 = eap[3];
    }
    float4 etA = erA, etB = erB;
#pragma unroll
    for (int k = 0; k < 16; ++k) {
      float4 wA = *(const float4*)&WeL[k * 512 + cA];
      float4 wB = *(const float4*)&WeL[k * 512 + cB];
      etA.x = fmaf(ea[k], wA.x, etA.x); etA.y = fmaf(ea[k], wA.y, etA.y);
      etA.z = fmaf(ea[k], wA.z, etA.z); etA.w = fmaf(ea[k], wA.w, etA.w);
      etB.x = fmaf(ea[k], wB.x, etB.x); etB.y = fmaf(ea[k], wB.y, etB.y);
      etB.z = fmaf(ea[k], wB.z, etB.z); etB.w = fmaf(ea[k], wB.w, etB.w);
    }
    float sA, sB;
    {
      float z0 = xA.x + xrA.x + etA.x; z0 = (z0 > 0.f) ? z0 : 0.2f * z0;
      float z1 = xA.y + xrA.y + etA.y; z1 = (z1 > 0.f) ? z1 : 0.2f * z1;
      float z2 = xA.z + xrA.z + etA.z; z2 = (z2 > 0.f) ? z2 : 0.2f * z2;
      float z3 = xA.w + xrA.w + etA.w; z3 = (z3 > 0.f) ? z3 : 0.2f * z3;
      sA = z0 * attA.x + z1 * attA.y + z2 * attA.z + z3 * attA.w;
      z0 = xB.x + xrB.x + etB.x; z0 = (z0 > 0.f) ? z0 : 0.2f * z0;
      z1 = xB.y + xrB.y + etB.y; z1 = (z1 > 0.f) ? z1 : 0.2f * z1;
      z2 = xB.z + xrB.z + etB.z; z2 = (z2 > 0.f) ? z2 : 0.2f * z2;
      z3 = xB.w + xrB.w + etB.w; z3 = (z3 > 0.f) ? z3 : 0.2f * z3;
      sB = z0 * attB.x + z1 * attB.y + z2 * attB.z + z3 * attB.w;
    }
#pragma unroll
    for (int o = 1; o <= 16; o <<= 1) {
      sA += __shfl_xor(sA, o, 64);
      sB += __shfl_xor(sB, o, 64);
    }
    {
      float mn = fmaxf(mA, sA);
      float sc = expf(mA - mn), we = expf(sA - mn);
      mA = mn; lsA = lsA * sc + we;
      accA.x = accA.x * sc + we * xA.x; accA.y = accA.y * sc + we * xA.y;
      accA.z = accA.z * sc + we * xA.z; accA.w = accA.w * sc + we * xA.w;
    }
    {
      float mn = fmaxf(mB, sB);
      float sc = expf(mB - mn), we = expf(sB - mn);
      mB = mn; lsB = lsB * sc + we;
      accB.x = accB.x * sc + we * xB.x; accB.y = accB.y * sc + we * xB.y;
      accB.z = accB.z * sc + we * xB.z; accB.w = accB.w * sc + we * xB.w;
    }
  }
  float invA = 1.f / fmaxf(lsA, 1e-16f);
  float invB = 1.f / fmaxf(lsB, 1e-16f);
  *(float4*)&sAgg[wave][cA] = make_float4(accA.x * invA, accA.y * invA, accA.z * invA, accA.w * invA);
  *(float4*)&sAgg[wave][cB] = make_float4(accB.x * invB, accB.y * invB, accB.z * invB, accB.w * invB);
  float o0 = sAgg[wave][lane]       + sAgg[wave][128 + lane]
           + sAgg[wave][256 + lane] + sAgg[wave][384 + lane];
  float o1 = sAgg[wave][64 + lane]  + sAgg[wave][192 + lane]
           + sAgg[wave][320 + lane] + sAgg[wave][448 + lane];
  size_t base = (size_t)n * HID;
  atomicAdd(&hmsg[base + lane],      gr * o0);
  atomicAdd(&hmsg[base + 64 + lane], gr * o1);
}

// ---------------- LayerNorm over 128 dims (optionally emits hi/lo bf16) ----------------
__global__ __launch_bounds__(64) void ln128(
    float* __restrict__ h, const float* __restrict__ add, const float* __restrict__ bvec,
    const float* __restrict__ g, const float* __restrict__ b,
    ushort* __restrict__ hh, ushort* __restrict__ hl) {
  int n = blockIdx.x, lane = threadIdx.x;
  size_t base = (size_t)n * HID;
  float x0 = h[base + lane] + add[base + lane];
  float x1 = h[base + 64 + lane] + add[base + 64 + lane];
  if (bvec) { x0 += bvec[lane]; x1 += bvec[64 + lane]; }
  float s = x0 + x1;
#pragma unroll
  for (int m = 32; m > 0; m >>= 1) s += __shfl_xor(s, m, 64);
  float mu = s * (1.f / 128.f);
  float d0 = x0 - mu, d1 = x1 - mu;
  float q = d0 * d0 + d1 * d1;
#pragma unroll
  for (int m = 32; m > 0; m >>= 1) q += __shfl_xor(q, m, 64);
  float inv = 1.f / sqrtf(q * (1.f / 128.f) + 1e-5f);
  float o0 = d0 * inv * g[lane] + b[lane];
  float o1 = d1 * inv * g[64 + lane] + b[64 + lane];
  h[base + lane]      = o0;
  h[base + 64 + lane] = o1;
  if (hh) {
    ushort i0 = f2bf(o0), i1 = f2bf(o1);
    hh[base + lane] = i0;        hh[base + 64 + lane] = i1;
    hl[base + lane] = f2bf(o0 - bf2f(i0));
    hl[base + 64 + lane] = f2bf(o1 - bf2f(i1));
  }
}

// ---------------- KAN expansion (fp32) — tiny readout head only ----------------
__global__ void expand_f32(const float* __restrict__ v, float* __restrict__ u, int In, int rows) {
  int i = blockIdx.x * 256 + threadIdx.x;
  if (i >= rows * In) return;
  int n = i / In, c = i % In;
  float x = v[(size_t)n * In + c];
  size_t base = (size_t)n * In * 9;
  u[base + c] = silu_f(x);
  float b8[8];
  kan_bases(x, b8);
  float* ub = u + base + In + (size_t)c * 8;
#pragma unroll
  for (int gq = 0; gq < 8; ++gq) ub[gq] = b8[gq];
}

// ---------------- atomic-free pooling, stage 1: per-chunk partials ----------------
__global__ __launch_bounds__(128) void pool_part(
    const float* __restrict__ h, const int* __restrict__ batch,
    float* __restrict__ psum, float* __restrict__ pmax, float* __restrict__ pcnt) {
  __shared__ float sS[NG][HID];
  __shared__ float sM[NG][HID];
  __shared__ int sC[NG];
  int d = threadIdx.x, blk = blockIdx.x;
  const float NEGINF = __uint_as_float(0xff800000u);  // -inf
  for (int i = d; i < NG * HID; i += 128) {
    ((float*)sS)[i] = 0.f;
    ((float*)sM)[i] = NEGINF;
  }
  if (d < NG) sC[d] = 0;
  __syncthreads();
  const int CH = (NN + NCHUNK - 1) / NCHUNK;  // 79
  int n0 = blk * CH, n1 = (n0 + CH < NN) ? n0 + CH : NN;
  for (int n = n0; n < n1; ++n) {
    int g = batch[n];
    float v = h[(size_t)n * HID + d];
    sS[g][d] += v;
    sM[g][d] = fmaxf(sM[g][d], v);
    if (d == 0) sC[g]++;
  }
  __syncthreads();
  for (int i = d; i < NG * HID; i += 128) {
    psum[(size_t)blk * NG * HID + i] = ((float*)sS)[i];
    pmax[(size_t)blk * NG * HID + i] = ((float*)sM)[i];
  }
  if (d < NG) pcnt[blk * NG + d] = (float)sC[d];
}

// ---------------- pooling stage 2 + readout LN ----------------
__global__ __launch_bounds__(256) void pool_final2(
    const float* __restrict__ psum, const float* __restrict__ pmax,
    const float* __restrict__ pcnt, const float* __restrict__ rog,
    const float* __restrict__ rob, float* __restrict__ gvec) {
  int g = blockIdx.x, j = threadIdx.x;
  __shared__ float rb[256];
  float x;
  if (j < HID) {
    float s = 0.f, cn = 0.f;
    for (int c = 0; c < NCHUNK; ++c) {
      s += psum[(size_t)c * NG * HID + g * HID + j];
      cn += pcnt[c * NG + g];
    }
    x = s / fmaxf(cn, 1.f);
  } else {
    float mx = __uint_as_float(0xff800000u);
    for (int c = 0; c < NCHUNK; ++c)
      mx = fmaxf(mx, pmax[(size_t)c * NG * HID + g * HID + (j - HID)]);
    x = (mx > -1e38f) ? mx : 0.f;  // where(isfinite, ., 0)
  }
  rb[j] = x; __syncthreads();
  for (int st = 128; st > 0; st >>= 1) { if (j < st) rb[j] += rb[j + st]; __syncthreads(); }
  float mu = rb[0] * (1.f / 256.f); __syncthreads();
  float d = x - mu;
  rb[j] = d * d; __syncthreads();
  for (int st = 128; st > 0; st >>= 1) { if (j < st) rb[j] += rb[j + st]; __syncthreads(); }
  float var = rb[0] * (1.f / 256.f);
  float inv = 1.f / sqrtf(var + 1e-5f);
  gvec[(size_t)g * 256 + j] = d * inv * rog[j] + rob[j];
}

// ---------------- wave-parallel KAN head: one wave per (graph, output) ----------------
__global__ __launch_bounds__(256) void kan_head_w(
    const float* __restrict__ u, const float* __restrict__ base_w,
    const float* __restrict__ spline_w, const float* __restrict__ scaler,
    float* __restrict__ out, int In, int Out, int npairs) {
  int wid = blockIdx.x * 4 + (threadIdx.x >> 6);
  if (wid >= npairs) return;
  int g = wid / Out, o = wid % Out;
  int lane = threadIdx.x & 63;
  const float* ug = u + (size_t)g * In * 9;
  const float* bw = base_w + (size_t)o * In;
  const float* sp = spline_w + (size_t)o * In * 8;
  const float* sc = scaler + (size_t)o * In;
  float acc = 0.f;
  for (int i = lane; i < In; i += 64) acc = fmaf(ug[i], bw[i], acc);
  const float* us = ug + In;
  for (int k = lane; k < In * 8; k += 64) {
    int i = k >> 3;
    acc = fmaf(us[k], sp[k] * sc[i], acc);
  }
#pragma unroll
  for (int off2 = 32; off2 > 0; off2 >>= 1) acc += __shfl_xor(acc, off2, 64);
  if (lane == 0) out[(size_t)g * Out + o] = acc;
}

// ---------------- launch ----------------
extern "C" void kernel_launch(void* const* d_in, const int* in_sizes, int n_in,
                              void* d_out, int out_size, void* d_ws, size_t ws_size,
                              hipStream_t stream) {
  const float* x         = (const float*)d_in[0];
  const float* edge_attr = (const float*)d_in[1];
  const int*   id_token  = (const int*)  d_in[2];
  const int*   edge_index= (const int*)  d_in[3];
  const int*   edge_type = (const int*)  d_in[4];
  const int*   batch     = (const int*)  d_in[5];
  const float* id_emb    = (const float*)d_in[6];
  const float* inW       = (const float*)d_in[7];
  const float* inb       = (const float*)d_in[8];
  const float* Wl        = (const float*)d_in[9];
  const float* bl        = (const float*)d_in[10];
  const float* Wr        = (const float*)d_in[11];
  const float* br        = (const float*)d_in[12];
  const float* We        = (const float*)d_in[13];
  const float* att       = (const float*)d_in[14];
  const float* gat_bias  = (const float*)d_in[15];
  const float* rel_gate  = (const float*)d_in[16];
  const float* rel_emb   = (const float*)d_in[17];
  const float* ln1g      = (const float*)d_in[18];
  const float* ln1b      = (const float*)d_in[19];
  const float* ln2g      = (const float*)d_in[20];
  const float* ln2b      = (const float*)d_in[21];
  const float* ffn1_base = (const float*)d_in[22];
  const float* ffn1_spl  = (const float*)d_in[23];
  const float* ffn1_sc   = (const float*)d_in[24];
  const float* ffn2_base = (const float*)d_in[25];
  const float* ffn2_spl  = (const float*)d_in[26];
  const float* ffn2_sc   = (const float*)d_in[27];
  const float* rog       = (const float*)d_in[28];
  const float* rob       = (const float*)d_in[29];
  const float* h1_base   = (const float*)d_in[30];
  const float* h1_spl    = (const float*)d_in[31];
  const float* h1_sc     = (const float*)d_in[32];
  const float* h2_base   = (const float*)d_in[33];
  const float* h2_spl    = (const float*)d_in[34];
  const float* h2_sc     = (const float*)d_in[35];
  (void)in_sizes; (void)n_in; (void)out_size; (void)ws_size;

  // ---- workspace carve (256B aligned) ----
  char* wsp = (char*)d_ws;
  size_t off = 0;
  auto carve = [&](size_t bytes) { char* p = wsp + off; off = (off + bytes + 255) & ~(size_t)255; return p; };
  float*    h     = (float*)   carve((size_t)NN * HID * 4);
  ushort*   h_hi  = (ushort*)  carve((size_t)NN * HID * 2);
  ushort*   h_lo  = (ushort*)  carve((size_t)NN * HID * 2);
  float*    hmsg  = (float*)   carve((size_t)NN * HID * 4);
  float*    t1    = (float*)   carve((size_t)NN * FFNH * 4);
  float*    gates = (float*)   carve(NR * 4);
  float*    msgb  = (float*)   carve(HID * 4);
  float*    erel  = (float*)   carve(NR * 512 * 4);
  ushort*   WTh   = (ushort*)  carve((size_t)NL * 2 * 2048 * HID * 2);
  ushort*   WTl   = (ushort*)  carve((size_t)NL * 2 * 2048 * HID * 2);
  float*    blr   = (float*)   carve((size_t)NL * 2 * 2048 * 4);
  ushort*   B1h   = (ushort*)  carve((size_t)FFNH * HID * 9 * 2);
  ushort*   B1l   = (ushort*)  carve((size_t)FFNH * HID * 9 * 2);
  ushort*   B2h   = (ushort*)  carve((size_t)HID * FFNH * 9 * 2);
  ushort*   B2l   = (ushort*)  carve((size_t)HID * FFNH * 9 * 2);
  float*    psum  = (float*)   carve((size_t)NCHUNK * NG * HID * 4);
  float*    pmax  = (float*)   carve((size_t)NCHUNK * NG * HID * 4);
  float*    pcnt  = (float*)   carve((size_t)NCHUNK * NG * 4);
  float*    gvec  = (float*)   carve((size_t)NG * 256 * 4);
  float*    uhead = (float*)   carve((size_t)NG * 256 * 9 * 4);
  float*    thead = (float*)   carve((size_t)NG * HEADH * 4);
  float*    xlr   = (float*)   carve((size_t)NN * 2048 * 4);        // 82 MB
  int*      deg2  = (int*)     carve((size_t)SCTOT * 4);
  int*      in_off2=(int*)     carve((size_t)(SCTOT + 1) * 4);
  int*      cursor2=(int*)     carve((size_t)SCTOT * 4);
  int*      tmp_incl=(int*)    carve((size_t)SCTOT * 4);
  int*      bsum  = (int*)     carve((size_t)SCBLK * 4);
  int*      boff  = (int*)     carve((size_t)SCBLK * 4);
  int*      in_e2 = (int*)     carve((size_t)NE * 4);
  int*      in_s2 = (int*)     carve((size_t)NE * 4);

  // ---- relation-sorted CSR build (once; graph static across layers) ----
  fill_zero_i<<<(SCTOT + 255) / 256, 256, 0, stream>>>(deg2, SCTOT);
  csr_count2<<<(NE + 255) / 256, 256, 0, stream>>>(edge_index, edge_type, deg2);
  scan_p1<<<SCBLK, 256, 0, stream>>>(deg2, tmp_incl, bsum);
  scan_p2<<<1, 256, 0, stream>>>(bsum, boff);
  scan_p3<<<SCBLK, 256, 0, stream>>>(deg2, tmp_incl, boff, in_off2, cursor2);
  csr_scatter2<<<(NE + 255) / 256, 256, 0, stream>>>(edge_index, edge_type, cursor2, in_e2, in_s2);

  // ---- weight transpose + split (once per launch) ----
  {
    int total = NL * 2 * 2048 * 128;
    conv_wT2<<<(total + 255) / 256, 256, 0, stream>>>(Wl, Wr, bl, br, WTh, WTl, blr, total);
  }

  // ---- input projection ----
  input_proj<<<NN, 128, 0, stream>>>(x, id_emb, id_token, inW, inb, h, h_hi, h_lo);

  const int MB128 = (NN + 127) / 128;  // 79
  const int MB64  = (NN + 63) / 64;    // 157
  for (int l = 0; l < NL; ++l) {
    layer_prep<<<1, 512, 0, stream>>>(rel_gate, gat_bias, rel_emb, We, l, gates, msgb, erel);
    fill_zero<<<(NN * HID + 255) / 256, 256, 0, stream>>>(hmsg, NN * HID);
    for (int pair = 0; pair < 2; ++pair) {
      int g2 = l * 2 + pair;
      const ushort* WThp = WTh + (size_t)g2 * 2048 * HID;
      const ushort* WTlp = WTl + (size_t)g2 * 2048 * HID;
      const float* blp   = blr + (size_t)g2 * 2048;
      int rbase = pair * 2;
      gemm_bf3<<<dim3(2048 / 64, MB128), 256, 0, stream>>>(h_hi, h_lo, WThp, WTlp, blp, xlr, NN, HID, 2048);
      gat_node6<<<dim3((NN + 3) / 4, 2), 256, 0, stream>>>(
          in_off2, in_e2, in_s2, edge_attr, xlr,
          We + ((size_t)(l * NR + rbase)) * 24 * 512, erel + rbase * 512,
          att + (size_t)(l * NR + rbase) * 512, gates, rbase, hmsg);
    }
    ln128<<<NN, 64, 0, stream>>>(h, hmsg, msgb, ln1g + l * HID, ln1b + l * HID, nullptr, nullptr);

    // ---- KAN FFN1: 128 -> 256 (K = 1152), fused expansion, BN=128, split-K 3 ----
    build_kan_wT<<<((HID * 9 * FFNH) + 255) / 256, 256, 0, stream>>>(
        ffn1_base + (size_t)l * FFNH * HID, ffn1_spl + (size_t)l * FFNH * HID * 8,
        ffn1_sc + (size_t)l * FFNH * HID, B1h, B1l, HID, FFNH);
    fill_zero<<<(NN * FFNH + 255) / 256, 256, 0, stream>>>(t1, NN * FFNH);
    gemm_kan<8, 3><<<dim3(FFNH / 128, MB64, 3), 256, 0, stream>>>(h, B1h, B1l, t1, NN, HID, FFNH);
    // ---- KAN FFN2: 256 -> 128 (K = 2304), fused expansion, BN=128, split-K 4 ----
    build_kan_wT<<<((FFNH * 9 * HID) + 255) / 256, 256, 0, stream>>>(
        ffn2_base + (size_t)l * HID * FFNH, ffn2_spl + (size_t)l * HID * FFNH * 8,
        ffn2_sc + (size_t)l * HID * FFNH, B2h, B2l, FFNH, HID);
    fill_zero<<<(NN * HID + 255) / 256, 256, 0, stream>>>(hmsg, NN * HID);
    gemm_kan<8, 4><<<dim3(HID / 128, MB64, 4), 256, 0, stream>>>(t1, B2h, B2l, hmsg, NN, FFNH, HID);
    ln128<<<NN, 64, 0, stream>>>(h, hmsg, nullptr, ln2g + l * HID, ln2b + l * HID, h_hi, h_lo);
  }

  // ---- readout (atomic-free pooling) ----
  pool_part<<<NCHUNK, 128, 0, stream>>>(h, batch, psum, pmax, pcnt);
  pool_final2<<<NG, 256, 0, stream>>>(psum, pmax, pcnt, rog, rob, gvec);
  expand_f32<<<((NG * 256) + 255) / 256, 256, 0, stream>>>(gvec, uhead, 256, NG);
  {
    int npairs = NG * HEADH;  // 4096 waves
    kan_head_w<<<(npairs + 3) / 4, 256, 0, stream>>>(uhead, h1_base, h1_spl, h1_sc, thead, 256, HEADH, npairs);
  }
  expand_f32<<<((NG * HEADH) + 255) / 256, 256, 0, stream>>>(thead, uhead, HEADH, NG);
  {
    int npairs = NG * NCLS;   // 320 waves
    kan_head_w<<<(npairs + 3) / 4, 256, 0, stream>>>(uhead, h2_base, h2_spl, h2_sc, (float*)d_out, HEADH, NCLS, npairs);
  }
}

// Round 15
// 1434.792 us; speedup vs baseline: 3.1049x; 1.0263x over previous
//
#include <hip/hip_runtime.h>
#include <hip/hip_fp16.h>
#include <cstdint>
#include <cstddef>

// ---------------- static problem config ----------------
#define NN      10000   // nodes
#define NE      120000  // edges
#define NG      32      // graphs
#define FNODE   64
#define FEDGE   16
#define HID     128
#define NHEADS  4
#define NL      3
#define NR      4
#define IDDIM   32
#define RELDIM  8
#define FFNH    256
#define HEADH   128
#define NCLS    10

#define NCHUNK  128     // pooling stage-1 blocks
#define SCTOT   (NN * NR)            // 40000 scan entries
#define SCBLK   ((SCTOT + 255) / 256)  // 157 scan blocks

typedef __attribute__((ext_vector_type(8))) short short8;
typedef __attribute__((ext_vector_type(4))) float floatx4;

// ---------------- helpers ----------------
__device__ __forceinline__ float silu_f(float x) { return x / (1.f + expf(-x)); }
__device__ __forceinline__ ushort f2bf(float f) {   // round-to-nearest-even bf16
  unsigned u = __float_as_uint(f);
  return (ushort)((u + 0x7FFFu + ((u >> 16) & 1u)) >> 16);
}
__device__ __forceinline__ float bf2f(ushort h) { return __uint_as_float((unsigned)h << 16); }
__device__ __forceinline__ float4 ld_h4(const __half* p) {   // 4 consecutive halves -> float4
  __half2 a = *(const __half2*)p;
  __half2 b = *(const __half2*)(p + 2);
  float2 fa = __half22float2(a), fb = __half22float2(b);
  return make_float4(fa.x, fa.y, fb.x, fb.y);
}

// Cox–de Boor cubic bases on grid t_j = (j-3)*0.4 - 1 (GRID_SIZE=5, ORDER=3) -> 8 bases
__device__ __forceinline__ void kan_bases(float x, float* out8) {
  float bb[11];
#pragma unroll
  for (int j = 0; j < 11; ++j) {
    float t0 = (j - 3) * 0.4f - 1.f;
    float t1 = (j - 2) * 0.4f - 1.f;
    bb[j] = (x >= t0 && x < t1) ? 1.f : 0.f;
  }
  {
    const float inv = 1.f / 0.4f;
#pragma unroll
    for (int j = 0; j < 10; ++j) {
      float tj = (j - 3) * 0.4f - 1.f, tjp1 = (j - 1) * 0.4f - 1.f;
      bb[j] = ((x - tj) * bb[j] + (tjp1 - x) * bb[j + 1]) * inv;
    }
  }
  {
    const float inv = 1.f / 0.8f;
#pragma unroll
    for (int j = 0; j < 9; ++j) {
      float tj = (j - 3) * 0.4f - 1.f, tjp1 = (j) * 0.4f - 1.f;
      bb[j] = ((x - tj) * bb[j] + (tjp1 - x) * bb[j + 1]) * inv;
    }
  }
  {
    const float inv = 1.f / 1.2000001f;
#pragma unroll
    for (int j = 0; j < 8; ++j) {
      float tj = (j - 3) * 0.4f - 1.f, tjp1 = (j + 1) * 0.4f - 1.f;
      bb[j] = ((x - tj) * bb[j] + (tjp1 - x) * bb[j + 1]) * inv;
    }
  }
#pragma unroll
  for (int j = 0; j < 8; ++j) out8[j] = bb[j];
}

// ---------------- 3-term MFMA GEMM, pre-split bf16 hi/lo, fp16 output ----------------
__global__ __launch_bounds__(256) void gemm_bf3(
    const ushort* __restrict__ Ahg, const ushort* __restrict__ Alg,
    const ushort* __restrict__ Bhg, const ushort* __restrict__ Blg,
    const float* __restrict__ bias, __half* __restrict__ C,
    int M, int K, int N) {
  constexpr int LDA = 68;
  __shared__ __align__(16) ushort Ah[128 * LDA];
  __shared__ __align__(16) ushort Al[128 * LDA];
  __shared__ __align__(16) ushort Bh[64 * LDA];
  __shared__ __align__(16) ushort Bl[64 * LDA];
  const int tid = threadIdx.x;
  const int lane = tid & 63, wave = tid >> 6;
  const int lrow = lane & 15, quad = lane >> 4;
  const int bm = blockIdx.y * 128, bn = blockIdx.x * 64;
  floatx4 acc[2][4] = {};
  for (int k0 = 0; k0 < K; k0 += 64) {
#pragma unroll
    for (int i = 0; i < 4; ++i) {
      int c = tid + i * 256;
      int row = c >> 3, col8 = c & 7;
      int gr = bm + row;
      uint4 vh = make_uint4(0, 0, 0, 0), vl = make_uint4(0, 0, 0, 0);
      if (gr < M) {
        vh = *(const uint4*)(Ahg + (size_t)gr * K + k0 + col8 * 8);
        vl = *(const uint4*)(Alg + (size_t)gr * K + k0 + col8 * 8);
      }
      *(uint4*)&Ah[row * LDA + col8 * 8] = vh;
      *(uint4*)&Al[row * LDA + col8 * 8] = vl;
    }
#pragma unroll
    for (int i = 0; i < 2; ++i) {
      int c = tid + i * 256;
      int row = c >> 3, col8 = c & 7;
      *(uint4*)&Bh[row * LDA + col8 * 8] = *(const uint4*)(Bhg + (size_t)(bn + row) * K + k0 + col8 * 8);
      *(uint4*)&Bl[row * LDA + col8 * 8] = *(const uint4*)(Blg + (size_t)(bn + row) * K + k0 + col8 * 8);
    }
    __syncthreads();
#pragma unroll
    for (int kk = 0; kk < 64; kk += 32) {
      int kof = kk + quad * 8;
      const int ra0 = (wave * 32 + lrow) * LDA + kof;
      const int ra1 = (wave * 32 + 16 + lrow) * LDA + kof;
      short8 ah0 = *(const short8*)&Ah[ra0];
      short8 ah1 = *(const short8*)&Ah[ra1];
      short8 al0 = *(const short8*)&Al[ra0];
      short8 al1 = *(const short8*)&Al[ra1];
      short8 bh[4], blo[4];
#pragma unroll
      for (int nt = 0; nt < 4; ++nt) {
        int rb = (nt * 16 + lrow) * LDA + kof;
        bh[nt]  = *(const short8*)&Bh[rb];
        blo[nt] = *(const short8*)&Bl[rb];
      }
#pragma unroll
      for (int nt = 0; nt < 4; ++nt) {
        acc[0][nt] = __builtin_amdgcn_mfma_f32_16x16x32_bf16(ah0, bh[nt],  acc[0][nt], 0, 0, 0);
        acc[1][nt] = __builtin_amdgcn_mfma_f32_16x16x32_bf16(ah1, bh[nt],  acc[1][nt], 0, 0, 0);
        acc[0][nt] = __builtin_amdgcn_mfma_f32_16x16x32_bf16(al0, bh[nt],  acc[0][nt], 0, 0, 0);
        acc[1][nt] = __builtin_amdgcn_mfma_f32_16x16x32_bf16(al1, bh[nt],  acc[1][nt], 0, 0, 0);
        acc[0][nt] = __builtin_amdgcn_mfma_f32_16x16x32_bf16(ah0, blo[nt], acc[0][nt], 0, 0, 0);
        acc[1][nt] = __builtin_amdgcn_mfma_f32_16x16x32_bf16(ah1, blo[nt], acc[1][nt], 0, 0, 0);
      }
    }
    __syncthreads();
  }
#pragma unroll
  for (int mt = 0; mt < 2; ++mt) {
#pragma unroll
    for (int nt = 0; nt < 4; ++nt) {
#pragma unroll
      for (int reg = 0; reg < 4; ++reg) {
        int row = bm + wave * 32 + mt * 16 + quad * 4 + reg;
        int col = bn + nt * 16 + lrow;
        if (row < M) {
          float v = acc[mt][nt][reg];
          if (bias) v += bias[col];
          C[(size_t)row * N + col] = __float2half(v);
        }
      }
    }
  }
}

// ---------------- fused KAN GEMM, BM=64, BN=NT*16, split-K: C += expand(A) @ BT^T ------
template<int NT, int SPLIT>
__global__ __launch_bounds__(256) void gemm_kan(
    const float* __restrict__ A, const ushort* __restrict__ Bhg, const ushort* __restrict__ Blg,
    float* __restrict__ C, int M, int In, int N) {
  const int K = In * 9;
  const int ntiles = K >> 6;
  const int per = (ntiles + SPLIT - 1) / SPLIT;
  const int kt0 = blockIdx.z * per;
  const int kt1 = (kt0 + per < ntiles) ? (kt0 + per) : ntiles;
  constexpr int LDA = 68;
  constexpr int BN = NT * 16;
  __shared__ __align__(16) ushort Ah[64 * LDA];
  __shared__ __align__(16) ushort Al[64 * LDA];
  __shared__ __align__(16) ushort Bh[BN * LDA];
  __shared__ __align__(16) ushort Bl[BN * LDA];
  const int tid = threadIdx.x;
  const int lane = tid & 63, wave = tid >> 6;
  const int lrow = lane & 15, quad = lane >> 4;
  const int bm = blockIdx.y * 64, bn = blockIdx.x * BN;
  floatx4 acc[NT] = {};
  for (int kt = kt0; kt < kt1; ++kt) {
    int k0 = kt << 6;
    if (k0 < In) {
#pragma unroll
      for (int i = 0; i < 4; ++i) {
        int c = tid + i * 256;
        int row = c >> 4, col4 = c & 15;
        int gr = bm + row;
        float4 v = make_float4(0.f, 0.f, 0.f, 0.f);
        if (gr < M) v = *(const float4*)(A + (size_t)gr * In + k0 + col4 * 4);
        float vv[4] = {silu_f(v.x), silu_f(v.y), silu_f(v.z), silu_f(v.w)};
        ushort h0 = f2bf(vv[0]), h1 = f2bf(vv[1]), h2 = f2bf(vv[2]), h3 = f2bf(vv[3]);
        ushort l0 = f2bf(vv[0] - bf2f(h0)), l1 = f2bf(vv[1] - bf2f(h1));
        ushort l2 = f2bf(vv[2] - bf2f(h2)), l3 = f2bf(vv[3] - bf2f(h3));
        *(uint2*)&Ah[row * LDA + col4 * 4] =
          make_uint2((unsigned)h0 | ((unsigned)h1 << 16), (unsigned)h2 | ((unsigned)h3 << 16));
        *(uint2*)&Al[row * LDA + col4 * 4] =
          make_uint2((unsigned)l0 | ((unsigned)l1 << 16), (unsigned)l2 | ((unsigned)l3 << 16));
      }
    } else {
      int i0 = (k0 - In) >> 3;
      int row = tid >> 2, q = tid & 3;
      int gr = bm + row;
      float2 v = make_float2(0.f, 0.f);
      if (gr < M) v = *(const float2*)(A + (size_t)gr * In + i0 + q * 2);
      float vv[2] = {v.x, v.y};
#pragma unroll
      for (int jj = 0; jj < 2; ++jj) {
        float b8[8];
        kan_bases(vv[jj], b8);
        unsigned hu[4], lu[4];
#pragma unroll
        for (int p = 0; p < 4; ++p) {
          ushort ha = f2bf(b8[2 * p]), hb = f2bf(b8[2 * p + 1]);
          ushort la = f2bf(b8[2 * p] - bf2f(ha)), lb = f2bf(b8[2 * p + 1] - bf2f(hb));
          hu[p] = (unsigned)ha | ((unsigned)hb << 16);
          lu[p] = (unsigned)la | ((unsigned)lb << 16);
        }
        int cbase = (q * 2 + jj) * 8;
        *(uint4*)&Ah[row * LDA + cbase] = make_uint4(hu[0], hu[1], hu[2], hu[3]);
        *(uint4*)&Al[row * LDA + cbase] = make_uint4(lu[0], lu[1], lu[2], lu[3]);
      }
    }
#pragma unroll
    for (int i = 0; i < NT / 2; ++i) {
      int c = tid + i * 256;
      int row = c >> 3, col8 = c & 7;
      *(uint4*)&Bh[row * LDA + col8 * 8] = *(const uint4*)(Bhg + (size_t)(bn + row) * K + k0 + col8 * 8);
      *(uint4*)&Bl[row * LDA + col8 * 8] = *(const uint4*)(Blg + (size_t)(bn + row) * K + k0 + col8 * 8);
    }
    __syncthreads();
#pragma unroll
    for (int kk = 0; kk < 64; kk += 32) {
      int kof = kk + quad * 8;
      int ra = (wave * 16 + lrow) * LDA + kof;
      short8 ah = *(const short8*)&Ah[ra];
      short8 al = *(const short8*)&Al[ra];
#pragma unroll
      for (int nt = 0; nt < NT; ++nt) {
        int rb = (nt * 16 + lrow) * LDA + kof;
        short8 bh  = *(const short8*)&Bh[rb];
        short8 blo = *(const short8*)&Bl[rb];
        acc[nt] = __builtin_amdgcn_mfma_f32_16x16x32_bf16(ah, bh,  acc[nt], 0, 0, 0);
        acc[nt] = __builtin_amdgcn_mfma_f32_16x16x32_bf16(al, bh,  acc[nt], 0, 0, 0);
        acc[nt] = __builtin_amdgcn_mfma_f32_16x16x32_bf16(ah, blo, acc[nt], 0, 0, 0);
      }
    }
    __syncthreads();
  }
#pragma unroll
  for (int nt = 0; nt < NT; ++nt) {
#pragma unroll
    for (int reg = 0; reg < 4; ++reg) {
      int row = bm + wave * 16 + quad * 4 + reg;
      int col = bn + nt * 16 + lrow;
      if (row < M) atomicAdd(&C[(size_t)row * N + col], acc[nt][reg]);
    }
  }
}

// ---------------- weight transpose+split: all 4 relations -> [L][4096][128] ----------------
__global__ void conv_wT2(const float* __restrict__ Wl, const float* __restrict__ Wr,
                         const float* __restrict__ bl, const float* __restrict__ br,
                         ushort* __restrict__ WTh, ushort* __restrict__ WTl,
                         float* __restrict__ bout, int total) {
  int i = blockIdx.x * 256 + threadIdx.x;
  if (i >= total) return;
  int l = i / (4096 * 128), rem = i % (4096 * 128);
  int n = rem >> 7, k = rem & 127;
  int r = n >> 10;                       // relation within layer
  int nsub = n & 1023;                   // 0..1023 within [Wl|Wr]
  int nn = nsub & 511;
  int g = l * NR + r;
  const float* W = (nsub < 512) ? Wl : Wr;
  float v = W[(size_t)g * 65536 + (size_t)k * 512 + nn];
  ushort hi = f2bf(v);
  WTh[i] = hi;
  WTl[i] = f2bf(v - bf2f(hi));
  if (k == 0) bout[l * 4096 + n] = ((nsub < 512) ? bl : br)[g * 512 + nn];
}

// ---------------- build expanded KAN weight, transposed + split ----------------
__global__ void build_kan_wT(const float* __restrict__ base_w, const float* __restrict__ spline_w,
                             const float* __restrict__ scaler,
                             ushort* __restrict__ BTh, ushort* __restrict__ BTl,
                             int In, int Out) {
  int i = blockIdx.x * 256 + threadIdx.x;
  if (i >= In * 9 * Out) return;
  int o = i / (In * 9), k = i % (In * 9);
  float v;
  if (k < In) v = base_w[(size_t)o * In + k];
  else {
    int q = k - In, ii = q >> 3, gq = q & 7;
    v = spline_w[((size_t)o * In + ii) * 8 + gq] * scaler[(size_t)o * In + ii];
  }
  ushort hi = f2bf(v);
  BTh[i] = hi;
  BTl[i] = f2bf(v - bf2f(hi));
}

// ---------------- input projection (fp32 h + hi/lo bf16) ----------------
__global__ __launch_bounds__(128) void input_proj(
    const float* __restrict__ x, const float* __restrict__ id_emb,
    const int* __restrict__ id_token, const float* __restrict__ inW,
    const float* __restrict__ inb, float* __restrict__ h,
    ushort* __restrict__ hh, ushort* __restrict__ hl) {
  int n = blockIdx.x, j = threadIdx.x;
  __shared__ float s[FNODE + IDDIM];
  if (j < FNODE) s[j] = x[(size_t)n * FNODE + j];
  else if (j < FNODE + IDDIM) s[j] = id_emb[(size_t)id_token[n] * IDDIM + (j - FNODE)];
  __syncthreads();
  float acc = inb[j];
#pragma unroll
  for (int k = 0; k < FNODE + IDDIM; ++k) acc = fmaf(s[k], inW[k * HID + j], acc);
  float v = silu_f(acc);
  h[(size_t)n * HID + j] = v;
  ushort hi = f2bf(v);
  hh[(size_t)n * HID + j] = hi;
  hl[(size_t)n * HID + j] = f2bf(v - bf2f(hi));
}

// ---------------- per-layer prep ----------------
__global__ __launch_bounds__(512) void layer_prep(
    const float* __restrict__ rel_gate, const float* __restrict__ gat_bias,
    const float* __restrict__ rel_emb, const float* __restrict__ We, int l,
    float* __restrict__ gates, float* __restrict__ msg_bias, float* __restrict__ erel) {
  int j = threadIdx.x;
  float g[NR]; float mx = -1e30f;
  for (int r = 0; r < NR; ++r) { g[r] = rel_gate[l * NR + r]; mx = fmaxf(mx, g[r]); }
  float s = 0.f;
  for (int r = 0; r < NR; ++r) { g[r] = expf(g[r] - mx); s += g[r]; }
  for (int r = 0; r < NR; ++r) g[r] /= s;
  if (j < NR) gates[j] = g[j];
  if (j < HID) {
    float b = 0.f;
    for (int r = 0; r < NR; ++r) b = fmaf(g[r], gat_bias[((size_t)(l * NR + r)) * HID + j], b);
    msg_bias[j] = b;
  }
  for (int r = 0; r < NR; ++r) {
    const float* Wer = We + ((size_t)(l * NR + r)) * 24 * 512;
    const float* re  = rel_emb + (l * NR + r) * RELDIM;
    float acc = 0.f;
#pragma unroll
    for (int q = 0; q < RELDIM; ++q) acc = fmaf(re[q], Wer[(FEDGE + q) * 512 + j], acc);
    erel[r * 512 + j] = acc;
  }
}

// ---------------- fills ----------------
__global__ void fill_zero(float* __restrict__ p, int n) {
  int i = blockIdx.x * 256 + threadIdx.x;
  if (i < n) p[i] = 0.f;
}
__global__ void fill_zero_i(int* __restrict__ p, int n) {
  int i = blockIdx.x * 256 + threadIdx.x;
  if (i < n) p[i] = 0;
}

// ---------------- relation-sorted CSR build: bins (target, relation) ----------------
__global__ void csr_count2(const int* __restrict__ eidx, const int* __restrict__ etype,
                           int* __restrict__ deg2) {
  int e = blockIdx.x * 256 + threadIdx.x;
  if (e < NE) atomicAdd(&deg2[eidx[NE + e] * NR + etype[e]], 1);
}

// ---- parallel 3-pass scan over deg2[SCTOT] ----
__global__ __launch_bounds__(256) void scan_p1(const int* __restrict__ deg2,
                                               int* __restrict__ tmp_incl, int* __restrict__ bsum) {
  __shared__ int ps[256];
  int t = threadIdx.x, blk = blockIdx.x;
  int i = blk * 256 + t;
  int v = (i < SCTOT) ? deg2[i] : 0;
  ps[t] = v;
  __syncthreads();
  for (int o = 1; o < 256; o <<= 1) {
    int u = (t >= o) ? ps[t - o] : 0;
    __syncthreads();
    ps[t] += u;
    __syncthreads();
  }
  if (i < SCTOT) tmp_incl[i] = ps[t];
  if (t == 255) bsum[blk] = ps[255];
}
__global__ __launch_bounds__(256) void scan_p2(const int* __restrict__ bsum, int* __restrict__ boff) {
  __shared__ int ps[256];
  int t = threadIdx.x;
  int v = (t < SCBLK) ? bsum[t] : 0;
  ps[t] = v;
  __syncthreads();
  for (int o = 1; o < 256; o <<= 1) {
    int u = (t >= o) ? ps[t - o] : 0;
    __syncthreads();
    ps[t] += u;
    __syncthreads();
  }
  if (t < SCBLK) boff[t] = ps[t] - v;   // exclusive
}
__global__ __launch_bounds__(256) void scan_p3(const int* __restrict__ deg2,
                                               const int* __restrict__ tmp_incl,
                                               const int* __restrict__ boff,
                                               int* __restrict__ in_off2, int* __restrict__ cursor2) {
  int t = threadIdx.x, blk = blockIdx.x;
  int i = blk * 256 + t;
  if (i < SCTOT) {
    int excl = boff[blk] + tmp_incl[i] - deg2[i];
    in_off2[i] = excl;
    cursor2[i] = excl;
  }
  if (i == 0) in_off2[SCTOT] = NE;
}

__global__ void csr_scatter2(const int* __restrict__ eidx, const int* __restrict__ etype,
                             int* __restrict__ cursor2,
                             int* __restrict__ in_e2, int* __restrict__ in_s2) {
  int e = blockIdx.x * 256 + threadIdx.x;
  if (e < NE) {
    int pos = atomicAdd(&cursor2[eidx[NE + e] * NR + etype[e]], 1);
    in_e2[pos] = e;
    in_s2[pos] = eidx[e];
  }
}

// ---------------- node-centric GAT, fp16 xlr, 4 relations via blockIdx.y ----------------
// xlr fp16 [NN][4096]: rel rs: xl at [rs*1024,+512), xr at [rs*1024+512,+512).
// Lane owns cols [lane*4,+4) and [256+lane*4,+4). hmsg += gates[rs]*0.25*agg (atomic).
__global__ __launch_bounds__(256) void gat_node7(
    const int* __restrict__ in_off2, const int* __restrict__ in_e2, const int* __restrict__ in_s2,
    const float* __restrict__ eattr, const __half* __restrict__ xlr,
    const float* __restrict__ We_base, const float* __restrict__ erel_base,
    const float* __restrict__ att_base, const float* __restrict__ gates,
    float* __restrict__ hmsg) {
  __shared__ __align__(16) float WeL[16 * 512];
  __shared__ __align__(16) float sAgg[4][512];
  int tid = threadIdx.x;
  int rs = blockIdx.y;
  const float* We_r = We_base + (size_t)rs * 24 * 512;
  for (int i = tid; i < 16 * 512 / 4; i += 256)
    *(float4*)&WeL[i * 4] = *(const float4*)&We_r[i * 4];
  __syncthreads();
  float gr = gates[rs] * 0.25f;
  int lane = tid & 63, wave = tid >> 6;
  int n = blockIdx.x * 4 + wave;
  if (n >= NN) return;
  int roff = rs * 1024;
  const int cA = lane * 4;         // head hA = lane>>5
  const int cB = 256 + lane * 4;   // head 2 + hA
  const __half* xrb = xlr + (size_t)n * 4096 + roff + 512;
  float4 xrA = ld_h4(xrb + cA);
  float4 xrB = ld_h4(xrb + cB);
  float4 attA = *(const float4*)(att_base + rs * 512 + cA);
  float4 attB = *(const float4*)(att_base + rs * 512 + cB);
  float4 erA  = *(const float4*)(erel_base + rs * 512 + cA);
  float4 erB  = *(const float4*)(erel_base + rs * 512 + cB);
  float mA = -1e30f, mB = -1e30f, lsA = 0.f, lsB = 0.f;
  float4 accA = make_float4(0.f, 0.f, 0.f, 0.f);
  float4 accB = make_float4(0.f, 0.f, 0.f, 0.f);
  int e0 = in_off2[n * NR + rs];
  int cnt = in_off2[n * NR + rs + 1] - e0;
  float4 pxA, pxB, pe0, pe1, pe2, pe3;
  int eN = 0, sN = 0;
  if (cnt > 0) {
    int eC = in_e2[e0], sC = in_s2[e0];
    if (cnt > 1) { eN = in_e2[e0 + 1]; sN = in_s2[e0 + 1]; }
    const __half* xls = xlr + (size_t)sC * 4096 + roff;
    pxA = ld_h4(xls + cA);
    pxB = ld_h4(xls + cB);
    const float4* eap = (const float4*)(eattr + (size_t)eC * 16);
    pe0 = eap[0]; pe1 = eap[1]; pe2 = eap[2]; pe3 = eap[3];
  }
  for (int j = 0; j < cnt; ++j) {
    float4 xA = pxA, xB = pxB;
    float ea[16] = {pe0.x, pe0.y, pe0.z, pe0.w, pe1.x, pe1.y, pe1.z, pe1.w,
                    pe2.x, pe2.y, pe2.z, pe2.w, pe3.x, pe3.y, pe3.z, pe3.w};
    if (j + 1 < cnt) {
      int eC = eN, sC = sN;
      if (j + 2 < cnt) { eN = in_e2[e0 + j + 2]; sN = in_s2[e0 + j + 2]; }
      const __half* xls = xlr + (size_t)sC * 4096 + roff;
      pxA = ld_h4(xls + cA);
      pxB = ld_h4(xls + cB);
      const float4* eap = (const float4*)(eattr + (size_t)eC * 16);
      pe0 = eap[0]; pe1 = eap[1]; pe2 = eap[2]; pe3 = eap[3];
    }
    float4 etA = erA, etB = erB;
#pragma unroll
    for (int k = 0; k < 16; ++k) {
      float4 wA = *(const float4*)&WeL[k * 512 + cA];
      float4 wB = *(const float4*)&WeL[k * 512 + cB];
      etA.x = fmaf(ea[k], wA.x, etA.x); etA.y = fmaf(ea[k], wA.y, etA.y);
      etA.z = fmaf(ea[k], wA.z, etA.z); etA.w = fmaf(ea[k], wA.w, etA.w);
      etB.x = fmaf(ea[k], wB.x, etB.x); etB.y = fmaf(ea[k], wB.y, etB.y);
      etB.z = fmaf(ea[k], wB.z, etB.z); etB.w = fmaf(ea[k], wB.w, etB.w);
    }
    float sA, sB;
    {
      float z0 = xA.x + xrA.x + etA.x; z0 = (z0 > 0.f) ? z0 : 0.2f * z0;
      float z1 = xA.y + xrA.y + etA.y; z1 = (z1 > 0.f) ? z1 : 0.2f * z1;
      float z2 = xA.z + xrA.z + etA.z; z2 = (z2 > 0.f) ? z2 : 0.2f * z2;
      float z3 = xA.w + xrA.w + etA.w; z3 = (z3 > 0.f) ? z3 : 0.2f * z3;
      sA = z0 * attA.x + z1 * attA.y + z2 * attA.z + z3 * attA.w;
      z0 = xB.x + xrB.x + etB.x; z0 = (z0 > 0.f) ? z0 : 0.2f * z0;
      z1 = xB.y + xrB.y + etB.y; z1 = (z1 > 0.f) ? z1 : 0.2f * z1;
      z2 = xB.z + xrB.z + etB.z; z2 = (z2 > 0.f) ? z2 : 0.2f * z2;
      z3 = xB.w + xrB.w + etB.w; z3 = (z3 > 0.f) ? z3 : 0.2f * z3;
      sB = z0 * attB.x + z1 * attB.y + z2 * attB.z + z3 * attB.w;
    }
#pragma unroll
    for (int o = 1; o <= 16; o <<= 1) {
      sA += __shfl_xor(sA, o, 64);
      sB += __shfl_xor(sB, o, 64);
    }
    {
      float mn = fmaxf(mA, sA);
      float sc = expf(mA - mn), we = expf(sA - mn);
      mA = mn; lsA = lsA * sc + we;
      accA.x = accA.x * sc + we * xA.x; accA.y = accA.y * sc + we * xA.y;
      accA.z = accA.z * sc + we * xA.z; accA.w = accA.w * sc + we * xA.w;
    }
    {
      float mn = fmaxf(mB, sB);
      float sc = expf(mB - mn), we = expf(sB - mn);
      mB = mn; lsB = lsB * sc + we;
      accB.x = accB.x * sc + we * xB.x; accB.y = accB.y * sc + we * xB.y;
      accB.z = accB.z * sc + we * xB.z; accB.w = accB.w * sc + we * xB.w;
    }
  }
  float invA = 1.f / fmaxf(lsA, 1e-16f);
  float invB = 1.f / fmaxf(lsB, 1e-16f);
  *(float4*)&sAgg[wave][cA] = make_float4(accA.x * invA, accA.y * invA, accA.z * invA, accA.w * invA);
  *(float4*)&sAgg[wave][cB] = make_float4(accB.x * invB, accB.y * invB, accB.z * invB, accB.w * invB);
  float o0 = sAgg[wave][lane]       + sAgg[wave][128 + lane]
           + sAgg[wave][256 + lane] + sAgg[wave][384 + lane];
  float o1 = sAgg[wave][64 + lane]  + sAgg[wave][192 + lane]
           + sAgg[wave][320 + lane] + sAgg[wave][448 + lane];
  size_t base = (size_t)n * HID;
  atomicAdd(&hmsg[base + lane],      gr * o0);
  atomicAdd(&hmsg[base + 64 + lane], gr * o1);
}

// ---------------- LayerNorm over 128 dims (optionally emits hi/lo bf16) ----------------
__global__ __launch_bounds__(64) void ln128(
    float* __restrict__ h, const float* __restrict__ add, const float* __restrict__ bvec,
    const float* __restrict__ g, const float* __restrict__ b,
    ushort* __restrict__ hh, ushort* __restrict__ hl) {
  int n = blockIdx.x, lane = threadIdx.x;
  size_t base = (size_t)n * HID;
  float x0 = h[base + lane] + add[base + lane];
  float x1 = h[base + 64 + lane] + add[base + 64 + lane];
  if (bvec) { x0 += bvec[lane]; x1 += bvec[64 + lane]; }
  float s = x0 + x1;
#pragma unroll
  for (int m = 32; m > 0; m >>= 1) s += __shfl_xor(s, m, 64);
  float mu = s * (1.f / 128.f);
  float d0 = x0 - mu, d1 = x1 - mu;
  float q = d0 * d0 + d1 * d1;
#pragma unroll
  for (int m = 32; m > 0; m >>= 1) q += __shfl_xor(q, m, 64);
  float inv = 1.f / sqrtf(q * (1.f / 128.f) + 1e-5f);
  float o0 = d0 * inv * g[lane] + b[lane];
  float o1 = d1 * inv * g[64 + lane] + b[64 + lane];
  h[base + lane]      = o0;
  h[base + 64 + lane] = o1;
  if (hh) {
    ushort i0 = f2bf(o0), i1 = f2bf(o1);
    hh[base + lane] = i0;        hh[base + 64 + lane] = i1;
    hl[base + lane] = f2bf(o0 - bf2f(i0));
    hl[base + 64 + lane] = f2bf(o1 - bf2f(i1));
  }
}

// ---------------- KAN expansion (fp32) — tiny readout head only ----------------
__global__ void expand_f32(const float* __restrict__ v, float* __restrict__ u, int In, int rows) {
  int i = blockIdx.x * 256 + threadIdx.x;
  if (i >= rows * In) return;
  int n = i / In, c = i % In;
  float x = v[(size_t)n * In + c];
  size_t base = (size_t)n * In * 9;
  u[base + c] = silu_f(x);
  float b8[8];
  kan_bases(x, b8);
  float* ub = u + base + In + (size_t)c * 8;
#pragma unroll
  for (int gq = 0; gq < 8; ++gq) ub[gq] = b8[gq];
}

// ---------------- atomic-free pooling, stage 1: per-chunk partials ----------------
__global__ __launch_bounds__(128) void pool_part(
    const float* __restrict__ h, const int* __restrict__ batch,
    float* __restrict__ psum, float* __restrict__ pmax, float* __restrict__ pcnt) {
  __shared__ float sS[NG][HID];
  __shared__ float sM[NG][HID];
  __shared__ int sC[NG];
  int d = threadIdx.x, blk = blockIdx.x;
  const float NEGINF = __uint_as_float(0xff800000u);  // -inf
  for (int i = d; i < NG * HID; i += 128) {
    ((float*)sS)[i] = 0.f;
    ((float*)sM)[i] = NEGINF;
  }
  if (d < NG) sC[d] = 0;
  __syncthreads();
  const int CH = (NN + NCHUNK - 1) / NCHUNK;  // 79
  int n0 = blk * CH, n1 = (n0 + CH < NN) ? n0 + CH : NN;
  for (int n = n0; n < n1; ++n) {
    int g = batch[n];
    float v = h[(size_t)n * HID + d];
    sS[g][d] += v;
    sM[g][d] = fmaxf(sM[g][d], v);
    if (d == 0) sC[g]++;
  }
  __syncthreads();
  for (int i = d; i < NG * HID; i += 128) {
    psum[(size_t)blk * NG * HID + i] = ((float*)sS)[i];
    pmax[(size_t)blk * NG * HID + i] = ((float*)sM)[i];
  }
  if (d < NG) pcnt[blk * NG + d] = (float)sC[d];
}

// ---------------- pooling stage 2 + readout LN ----------------
__global__ __launch_bounds__(256) void pool_final2(
    const float* __restrict__ psum, const float* __restrict__ pmax,
    const float* __restrict__ pcnt, const float* __restrict__ rog,
    const float* __restrict__ rob, float* __restrict__ gvec) {
  int g = blockIdx.x, j = threadIdx.x;
  __shared__ float rb[256];
  float x;
  if (j < HID) {
    float s = 0.f, cn = 0.f;
    for (int c = 0; c < NCHUNK; ++c) {
      s += psum[(size_t)c * NG * HID + g * HID + j];
      cn += pcnt[c * NG + g];
    }
    x = s / fmaxf(cn, 1.f);
  } else {
    float mx = __uint_as_float(0xff800000u);
    for (int c = 0; c < NCHUNK; ++c)
      mx = fmaxf(mx, pmax[(size_t)c * NG * HID + g * HID + (j - HID)]);
    x = (mx > -1e38f) ? mx : 0.f;  // where(isfinite, ., 0)
  }
  rb[j] = x; __syncthreads();
  for (int st = 128; st > 0; st >>= 1) { if (j < st) rb[j] += rb[j + st]; __syncthreads(); }
  float mu = rb[0] * (1.f / 256.f); __syncthreads();
  float d = x - mu;
  rb[j] = d * d; __syncthreads();
  for (int st = 128; st > 0; st >>= 1) { if (j < st) rb[j] += rb[j + st]; __syncthreads(); }
  float var = rb[0] * (1.f / 256.f);
  float inv = 1.f / sqrtf(var + 1e-5f);
  gvec[(size_t)g * 256 + j] = d * inv * rog[j] + rob[j];
}

// ---------------- wave-parallel KAN head: one wave per (graph, output) ----------------
__global__ __launch_bounds__(256) void kan_head_w(
    const float* __restrict__ u, const float* __restrict__ base_w,
    const float* __restrict__ spline_w, const float* __restrict__ scaler,
    float* __restrict__ out, int In, int Out, int npairs) {
  int wid = blockIdx.x * 4 + (threadIdx.x >> 6);
  if (wid >= npairs) return;
  int g = wid / Out, o = wid % Out;
  int lane = threadIdx.x & 63;
  const float* ug = u + (size_t)g * In * 9;
  const float* bw = base_w + (size_t)o * In;
  const float* sp = spline_w + (size_t)o * In * 8;
  const float* sc = scaler + (size_t)o * In;
  float acc = 0.f;
  for (int i = lane; i < In; i += 64) acc = fmaf(ug[i], bw[i], acc);
  const float* us = ug + In;
  for (int k = lane; k < In * 8; k += 64) {
    int i = k >> 3;
    acc = fmaf(us[k], sp[k] * sc[i], acc);
  }
#pragma unroll
  for (int off2 = 32; off2 > 0; off2 >>= 1) acc += __shfl_xor(acc, off2, 64);
  if (lane == 0) out[(size_t)g * Out + o] = acc;
}

// ---------------- launch ----------------
extern "C" void kernel_launch(void* const* d_in, const int* in_sizes, int n_in,
                              void* d_out, int out_size, void* d_ws, size_t ws_size,
                              hipStream_t stream) {
  const float* x         = (const float*)d_in[0];
  const float* edge_attr = (const float*)d_in[1];
  const int*   id_token  = (const int*)  d_in[2];
  const int*   edge_index= (const int*)  d_in[3];
  const int*   edge_type = (const int*)  d_in[4];
  const int*   batch     = (const int*)  d_in[5];
  const float* id_emb    = (const float*)d_in[6];
  const float* inW       = (const float*)d_in[7];
  const float* inb       = (const float*)d_in[8];
  const float* Wl        = (const float*)d_in[9];
  const float* bl        = (const float*)d_in[10];
  const float* Wr        = (const float*)d_in[11];
  const float* br        = (const float*)d_in[12];
  const float* We        = (const float*)d_in[13];
  const float* att       = (const float*)d_in[14];
  const float* gat_bias  = (const float*)d_in[15];
  const float* rel_gate  = (const float*)d_in[16];
  const float* rel_emb   = (const float*)d_in[17];
  const float* ln1g      = (const float*)d_in[18];
  const float* ln1b      = (const float*)d_in[19];
  const float* ln2g      = (const float*)d_in[20];
  const float* ln2b      = (const float*)d_in[21];
  const float* ffn1_base = (const float*)d_in[22];
  const float* ffn1_spl  = (const float*)d_in[23];
  const float* ffn1_sc   = (const float*)d_in[24];
  const float* ffn2_base = (const float*)d_in[25];
  const float* ffn2_spl  = (const float*)d_in[26];
  const float* ffn2_sc   = (const float*)d_in[27];
  const float* rog       = (const float*)d_in[28];
  const float* rob       = (const float*)d_in[29];
  const float* h1_base   = (const float*)d_in[30];
  const float* h1_spl    = (const float*)d_in[31];
  const float* h1_sc     = (const float*)d_in[32];
  const float* h2_base   = (const float*)d_in[33];
  const float* h2_spl    = (const float*)d_in[34];
  const float* h2_sc     = (const float*)d_in[35];
  (void)in_sizes; (void)n_in; (void)out_size; (void)ws_size;

  // ---- workspace carve (256B aligned) ----
  char* wsp = (char*)d_ws;
  size_t off = 0;
  auto carve = [&](size_t bytes) { char* p = wsp + off; off = (off + bytes + 255) & ~(size_t)255; return p; };
  float*    h     = (float*)   carve((size_t)NN * HID * 4);
  ushort*   h_hi  = (ushort*)  carve((size_t)NN * HID * 2);
  ushort*   h_lo  = (ushort*)  carve((size_t)NN * HID * 2);
  float*    hmsg  = (float*)   carve((size_t)NN * HID * 4);
  float*    t1    = (float*)   carve((size_t)NN * FFNH * 4);
  float*    gates = (float*)   carve(NR * 4);
  float*    msgb  = (float*)   carve(HID * 4);
  float*    erel  = (float*)   carve(NR * 512 * 4);
  ushort*   WTh   = (ushort*)  carve((size_t)NL * 4096 * HID * 2);
  ushort*   WTl   = (ushort*)  carve((size_t)NL * 4096 * HID * 2);
  float*    blr   = (float*)   carve((size_t)NL * 4096 * 4);
  ushort*   B1h   = (ushort*)  carve((size_t)FFNH * HID * 9 * 2);
  ushort*   B1l   = (ushort*)  carve((size_t)FFNH * HID * 9 * 2);
  ushort*   B2h   = (ushort*)  carve((size_t)HID * FFNH * 9 * 2);
  ushort*   B2l   = (ushort*)  carve((size_t)HID * FFNH * 9 * 2);
  float*    psum  = (float*)   carve((size_t)NCHUNK * NG * HID * 4);
  float*    pmax  = (float*)   carve((size_t)NCHUNK * NG * HID * 4);
  float*    pcnt  = (float*)   carve((size_t)NCHUNK * NG * 4);
  float*    gvec  = (float*)   carve((size_t)NG * 256 * 4);
  float*    uhead = (float*)   carve((size_t)NG * 256 * 9 * 4);
  float*    thead = (float*)   carve((size_t)NG * HEADH * 4);
  __half*   xlr   = (__half*)  carve((size_t)NN * 4096 * 2);        // 82 MB fp16
  int*      deg2  = (int*)     carve((size_t)SCTOT * 4);
  int*      in_off2=(int*)     carve((size_t)(SCTOT + 1) * 4);
  int*      cursor2=(int*)     carve((size_t)SCTOT * 4);
  int*      tmp_incl=(int*)    carve((size_t)SCTOT * 4);
  int*      bsum  = (int*)     carve((size_t)SCBLK * 4);
  int*      boff  = (int*)     carve((size_t)SCBLK * 4);
  int*      in_e2 = (int*)     carve((size_t)NE * 4);
  int*      in_s2 = (int*)     carve((size_t)NE * 4);

  // ---- relation-sorted CSR build (once; graph static across layers) ----
  fill_zero_i<<<(SCTOT + 255) / 256, 256, 0, stream>>>(deg2, SCTOT);
  csr_count2<<<(NE + 255) / 256, 256, 0, stream>>>(edge_index, edge_type, deg2);
  scan_p1<<<SCBLK, 256, 0, stream>>>(deg2, tmp_incl, bsum);
  scan_p2<<<1, 256, 0, stream>>>(bsum, boff);
  scan_p3<<<SCBLK, 256, 0, stream>>>(deg2, tmp_incl, boff, in_off2, cursor2);
  csr_scatter2<<<(NE + 255) / 256, 256, 0, stream>>>(edge_index, edge_type, cursor2, in_e2, in_s2);

  // ---- weight transpose + split (once per launch) ----
  {
    int total = NL * 4096 * 128;
    conv_wT2<<<(total + 255) / 256, 256, 0, stream>>>(Wl, Wr, bl, br, WTh, WTl, blr, total);
  }

  // ---- input projection ----
  input_proj<<<NN, 128, 0, stream>>>(x, id_emb, id_token, inW, inb, h, h_hi, h_lo);

  const int MB128 = (NN + 127) / 128;  // 79
  const int MB64  = (NN + 63) / 64;    // 157
  for (int l = 0; l < NL; ++l) {
    layer_prep<<<1, 512, 0, stream>>>(rel_gate, gat_bias, rel_emb, We, l, gates, msgb, erel);
    fill_zero<<<(NN * HID + 255) / 256, 256, 0, stream>>>(hmsg, NN * HID);
    // one projection GEMM for all 4 relations (N = 4096), fp16 output
    gemm_bf3<<<dim3(4096 / 64, MB128), 256, 0, stream>>>(
        h_hi, h_lo, WTh + (size_t)l * 4096 * HID, WTl + (size_t)l * 4096 * HID,
        blr + (size_t)l * 4096, xlr, NN, HID, 4096);
    // one gat dispatch covering all 4 relations
    gat_node7<<<dim3((NN + 3) / 4, 4), 256, 0, stream>>>(
        in_off2, in_e2, in_s2, edge_attr, xlr,
        We + ((size_t)(l * NR)) * 24 * 512, erel, att + (size_t)(l * NR) * 512,
        gates, hmsg);
    ln128<<<NN, 64, 0, stream>>>(h, hmsg, msgb, ln1g + l * HID, ln1b + l * HID, nullptr, nullptr);

    // ---- KAN FFN1: 128 -> 256 (K = 1152), fused expansion, BN=128, split-K 3 ----
    build_kan_wT<<<((HID * 9 * FFNH) + 255) / 256, 256, 0, stream>>>(
        ffn1_base + (size_t)l * FFNH * HID, ffn1_spl + (size_t)l * FFNH * HID * 8,
        ffn1_sc + (size_t)l * FFNH * HID, B1h, B1l, HID, FFNH);
    fill_zero<<<(NN * FFNH + 255) / 256, 256, 0, stream>>>(t1, NN * FFNH);
    gemm_kan<8, 3><<<dim3(FFNH / 128, MB64, 3), 256, 0, stream>>>(h, B1h, B1l, t1, NN, HID, FFNH);
    // ---- KAN FFN2: 256 -> 128 (K = 2304), fused expansion, BN=128, split-K 4 ----
    build_kan_wT<<<((FFNH * 9 * HID) + 255) / 256, 256, 0, stream>>>(
        ffn2_base + (size_t)l * HID * FFNH, ffn2_spl + (size_t)l * HID * FFNH * 8,
        ffn2_sc + (size_t)l * HID * FFNH, B2h, B2l, FFNH, HID);
    fill_zero<<<(NN * HID + 255) / 256, 256, 0, stream>>>(hmsg, NN * HID);
    gemm_kan<8, 4><<<dim3(HID / 128, MB64, 4), 256, 0, stream>>>(t1, B2h, B2l, hmsg, NN, FFNH, HID);
    ln128<<<NN, 64, 0, stream>>>(h, hmsg, nullptr, ln2g + l * HID, ln2b + l * HID, h_hi, h_lo);
  }

  // ---- readout (atomic-free pooling) ----
  pool_part<<<NCHUNK, 128, 0, stream>>>(h, batch, psum, pmax, pcnt);
  pool_final2<<<NG, 256, 0, stream>>>(psum, pmax, pcnt, rog, rob, gvec);
  expand_f32<<<((NG * 256) + 255) / 256, 256, 0, stream>>>(gvec, uhead, 256, NG);
  {
    int npairs = NG * HEADH;  // 4096 waves
    kan_head_w<<<(npairs + 3) / 4, 256, 0, stream>>>(uhead, h1_base, h1_spl, h1_sc, thead, 256, HEADH, npairs);
  }
  expand_f32<<<((NG * HEADH) + 255) / 256, 256, 0, stream>>>(thead, uhead, HEADH, NG);
  {
    int npairs = NG * NCLS;   // 320 waves
    kan_head_w<<<(npairs + 3) / 4, 256, 0, stream>>>(uhead, h2_base, h2_spl, h2_sc, (float*)d_out, HEADH, NCLS, npairs);
  }
}

// Round 16
// 1336.923 us; speedup vs baseline: 3.3322x; 1.0732x over previous
//
#include <hip/hip_runtime.h>
#include <hip/hip_fp16.h>
#include <cstdint>
#include <cstddef>

// ---------------- static problem config ----------------
#define NN      10000   // nodes
#define NE      120000  // edges
#define NG      32      // graphs
#define FNODE   64
#define FEDGE   16
#define HID     128
#define NHEADS  4
#define NL      3
#define NR      4
#define IDDIM   32
#define RELDIM  8
#define FFNH    256
#define HEADH   128
#define NCLS    10

#define NCHUNK  128     // pooling stage-1 blocks
#define SCTOT   (NN * NR)            // 40000 scan entries
#define SCBLK   ((SCTOT + 255) / 256)  // 157 scan blocks

typedef __attribute__((ext_vector_type(8))) short short8;
typedef __attribute__((ext_vector_type(4))) float floatx4;

// ---------------- helpers ----------------
__device__ __forceinline__ float silu_f(float x) { return x / (1.f + expf(-x)); }
__device__ __forceinline__ ushort f2bf(float f) {   // round-to-nearest-even bf16
  unsigned u = __float_as_uint(f);
  return (ushort)((u + 0x7FFFu + ((u >> 16) & 1u)) >> 16);
}
__device__ __forceinline__ float bf2f(ushort h) { return __uint_as_float((unsigned)h << 16); }
__device__ __forceinline__ float4 ld_h4(const __half* p) {   // 4 consecutive halves -> float4
  __half2 a = *(const __half2*)p;
  __half2 b = *(const __half2*)(p + 2);
  float2 fa = __half22float2(a), fb = __half22float2(b);
  return make_float4(fa.x, fa.y, fb.x, fb.y);
}

// Cox–de Boor cubic bases on grid t_j = (j-3)*0.4 - 1 (GRID_SIZE=5, ORDER=3) -> 8 bases
__device__ __forceinline__ void kan_bases(float x, float* out8) {
  float bb[11];
#pragma unroll
  for (int j = 0; j < 11; ++j) {
    float t0 = (j - 3) * 0.4f - 1.f;
    float t1 = (j - 2) * 0.4f - 1.f;
    bb[j] = (x >= t0 && x < t1) ? 1.f : 0.f;
  }
  {
    const float inv = 1.f / 0.4f;
#pragma unroll
    for (int j = 0; j < 10; ++j) {
      float tj = (j - 3) * 0.4f - 1.f, tjp1 = (j - 1) * 0.4f - 1.f;
      bb[j] = ((x - tj) * bb[j] + (tjp1 - x) * bb[j + 1]) * inv;
    }
  }
  {
    const float inv = 1.f / 0.8f;
#pragma unroll
    for (int j = 0; j < 9; ++j) {
      float tj = (j - 3) * 0.4f - 1.f, tjp1 = (j) * 0.4f - 1.f;
      bb[j] = ((x - tj) * bb[j] + (tjp1 - x) * bb[j + 1]) * inv;
    }
  }
  {
    const float inv = 1.f / 1.2000001f;
#pragma unroll
    for (int j = 0; j < 8; ++j) {
      float tj = (j - 3) * 0.4f - 1.f, tjp1 = (j + 1) * 0.4f - 1.f;
      bb[j] = ((x - tj) * bb[j] + (tjp1 - x) * bb[j + 1]) * inv;
    }
  }
#pragma unroll
  for (int j = 0; j < 8; ++j) out8[j] = bb[j];
}

// ---------------- 3-term MFMA GEMM, pre-split bf16 hi/lo, fp16 output ----------------
__global__ __launch_bounds__(256) void gemm_bf3(
    const ushort* __restrict__ Ahg, const ushort* __restrict__ Alg,
    const ushort* __restrict__ Bhg, const ushort* __restrict__ Blg,
    const float* __restrict__ bias, __half* __restrict__ C,
    int M, int K, int N) {
  constexpr int LDA = 68;
  __shared__ __align__(16) ushort Ah[128 * LDA];
  __shared__ __align__(16) ushort Al[128 * LDA];
  __shared__ __align__(16) ushort Bh[64 * LDA];
  __shared__ __align__(16) ushort Bl[64 * LDA];
  const int tid = threadIdx.x;
  const int lane = tid & 63, wave = tid >> 6;
  const int lrow = lane & 15, quad = lane >> 4;
  const int bm = blockIdx.y * 128, bn = blockIdx.x * 64;
  floatx4 acc[2][4] = {};
  for (int k0 = 0; k0 < K; k0 += 64) {
#pragma unroll
    for (int i = 0; i < 4; ++i) {
      int c = tid + i * 256;
      int row = c >> 3, col8 = c & 7;
      int gr = bm + row;
      uint4 vh = make_uint4(0, 0, 0, 0), vl = make_uint4(0, 0, 0, 0);
      if (gr < M) {
        vh = *(const uint4*)(Ahg + (size_t)gr * K + k0 + col8 * 8);
        vl = *(const uint4*)(Alg + (size_t)gr * K + k0 + col8 * 8);
      }
      *(uint4*)&Ah[row * LDA + col8 * 8] = vh;
      *(uint4*)&Al[row * LDA + col8 * 8] = vl;
    }
#pragma unroll
    for (int i = 0; i < 2; ++i) {
      int c = tid + i * 256;
      int row = c >> 3, col8 = c & 7;
      *(uint4*)&Bh[row * LDA + col8 * 8] = *(const uint4*)(Bhg + (size_t)(bn + row) * K + k0 + col8 * 8);
      *(uint4*)&Bl[row * LDA + col8 * 8] = *(const uint4*)(Blg + (size_t)(bn + row) * K + k0 + col8 * 8);
    }
    __syncthreads();
#pragma unroll
    for (int kk = 0; kk < 64; kk += 32) {
      int kof = kk + quad * 8;
      const int ra0 = (wave * 32 + lrow) * LDA + kof;
      const int ra1 = (wave * 32 + 16 + lrow) * LDA + kof;
      short8 ah0 = *(const short8*)&Ah[ra0];
      short8 ah1 = *(const short8*)&Ah[ra1];
      short8 al0 = *(const short8*)&Al[ra0];
      short8 al1 = *(const short8*)&Al[ra1];
      short8 bh[4], blo[4];
#pragma unroll
      for (int nt = 0; nt < 4; ++nt) {
        int rb = (nt * 16 + lrow) * LDA + kof;
        bh[nt]  = *(const short8*)&Bh[rb];
        blo[nt] = *(const short8*)&Bl[rb];
      }
#pragma unroll
      for (int nt = 0; nt < 4; ++nt) {
        acc[0][nt] = __builtin_amdgcn_mfma_f32_16x16x32_bf16(ah0, bh[nt],  acc[0][nt], 0, 0, 0);
        acc[1][nt] = __builtin_amdgcn_mfma_f32_16x16x32_bf16(ah1, bh[nt],  acc[1][nt], 0, 0, 0);
        acc[0][nt] = __builtin_amdgcn_mfma_f32_16x16x32_bf16(al0, bh[nt],  acc[0][nt], 0, 0, 0);
        acc[1][nt] = __builtin_amdgcn_mfma_f32_16x16x32_bf16(al1, bh[nt],  acc[1][nt], 0, 0, 0);
        acc[0][nt] = __builtin_amdgcn_mfma_f32_16x16x32_bf16(ah0, blo[nt], acc[0][nt], 0, 0, 0);
        acc[1][nt] = __builtin_amdgcn_mfma_f32_16x16x32_bf16(ah1, blo[nt], acc[1][nt], 0, 0, 0);
      }
    }
    __syncthreads();
  }
#pragma unroll
  for (int mt = 0; mt < 2; ++mt) {
#pragma unroll
    for (int nt = 0; nt < 4; ++nt) {
#pragma unroll
      for (int reg = 0; reg < 4; ++reg) {
        int row = bm + wave * 32 + mt * 16 + quad * 4 + reg;
        int col = bn + nt * 16 + lrow;
        if (row < M) {
          float v = acc[mt][nt][reg];
          if (bias) v += bias[col];
          C[(size_t)row * N + col] = __float2half(v);
        }
      }
    }
  }
}

// ---------------- fused KAN GEMM, BM=64, BN=NT*16, split-K: C += expand(A) @ BT^T ------
template<int NT, int SPLIT>
__global__ __launch_bounds__(256) void gemm_kan(
    const float* __restrict__ A, const ushort* __restrict__ Bhg, const ushort* __restrict__ Blg,
    float* __restrict__ C, int M, int In, int N) {
  const int K = In * 9;
  const int ntiles = K >> 6;
  const int per = (ntiles + SPLIT - 1) / SPLIT;
  const int kt0 = blockIdx.z * per;
  const int kt1 = (kt0 + per < ntiles) ? (kt0 + per) : ntiles;
  constexpr int LDA = 68;
  constexpr int BN = NT * 16;
  __shared__ __align__(16) ushort Ah[64 * LDA];
  __shared__ __align__(16) ushort Al[64 * LDA];
  __shared__ __align__(16) ushort Bh[BN * LDA];
  __shared__ __align__(16) ushort Bl[BN * LDA];
  const int tid = threadIdx.x;
  const int lane = tid & 63, wave = tid >> 6;
  const int lrow = lane & 15, quad = lane >> 4;
  const int bm = blockIdx.y * 64, bn = blockIdx.x * BN;
  floatx4 acc[NT] = {};
  for (int kt = kt0; kt < kt1; ++kt) {
    int k0 = kt << 6;
    if (k0 < In) {
#pragma unroll
      for (int i = 0; i < 4; ++i) {
        int c = tid + i * 256;
        int row = c >> 4, col4 = c & 15;
        int gr = bm + row;
        float4 v = make_float4(0.f, 0.f, 0.f, 0.f);
        if (gr < M) v = *(const float4*)(A + (size_t)gr * In + k0 + col4 * 4);
        float vv[4] = {silu_f(v.x), silu_f(v.y), silu_f(v.z), silu_f(v.w)};
        ushort h0 = f2bf(vv[0]), h1 = f2bf(vv[1]), h2 = f2bf(vv[2]), h3 = f2bf(vv[3]);
        ushort l0 = f2bf(vv[0] - bf2f(h0)), l1 = f2bf(vv[1] - bf2f(h1));
        ushort l2 = f2bf(vv[2] - bf2f(h2)), l3 = f2bf(vv[3] - bf2f(h3));
        *(uint2*)&Ah[row * LDA + col4 * 4] =
          make_uint2((unsigned)h0 | ((unsigned)h1 << 16), (unsigned)h2 | ((unsigned)h3 << 16));
        *(uint2*)&Al[row * LDA + col4 * 4] =
          make_uint2((unsigned)l0 | ((unsigned)l1 << 16), (unsigned)l2 | ((unsigned)l3 << 16));
      }
    } else {
      int i0 = (k0 - In) >> 3;
      int row = tid >> 2, q = tid & 3;
      int gr = bm + row;
      float2 v = make_float2(0.f, 0.f);
      if (gr < M) v = *(const float2*)(A + (size_t)gr * In + i0 + q * 2);
      float vv[2] = {v.x, v.y};
#pragma unroll
      for (int jj = 0; jj < 2; ++jj) {
        float b8[8];
        kan_bases(vv[jj], b8);
        unsigned hu[4], lu[4];
#pragma unroll
        for (int p = 0; p < 4; ++p) {
          ushort ha = f2bf(b8[2 * p]), hb = f2bf(b8[2 * p + 1]);
          ushort la = f2bf(b8[2 * p] - bf2f(ha)), lb = f2bf(b8[2 * p + 1] - bf2f(hb));
          hu[p] = (unsigned)ha | ((unsigned)hb << 16);
          lu[p] = (unsigned)la | ((unsigned)lb << 16);
        }
        int cbase = (q * 2 + jj) * 8;
        *(uint4*)&Ah[row * LDA + cbase] = make_uint4(hu[0], hu[1], hu[2], hu[3]);
        *(uint4*)&Al[row * LDA + cbase] = make_uint4(lu[0], lu[1], lu[2], lu[3]);
      }
    }
#pragma unroll
    for (int i = 0; i < NT / 2; ++i) {
      int c = tid + i * 256;
      int row = c >> 3, col8 = c & 7;
      *(uint4*)&Bh[row * LDA + col8 * 8] = *(const uint4*)(Bhg + (size_t)(bn + row) * K + k0 + col8 * 8);
      *(uint4*)&Bl[row * LDA + col8 * 8] = *(const uint4*)(Blg + (size_t)(bn + row) * K + k0 + col8 * 8);
    }
    __syncthreads();
#pragma unroll
    for (int kk = 0; kk < 64; kk += 32) {
      int kof = kk + quad * 8;
      int ra = (wave * 16 + lrow) * LDA + kof;
      short8 ah = *(const short8*)&Ah[ra];
      short8 al = *(const short8*)&Al[ra];
#pragma unroll
      for (int nt = 0; nt < NT; ++nt) {
        int rb = (nt * 16 + lrow) * LDA + kof;
        short8 bh  = *(const short8*)&Bh[rb];
        short8 blo = *(const short8*)&Bl[rb];
        acc[nt] = __builtin_amdgcn_mfma_f32_16x16x32_bf16(ah, bh,  acc[nt], 0, 0, 0);
        acc[nt] = __builtin_amdgcn_mfma_f32_16x16x32_bf16(al, bh,  acc[nt], 0, 0, 0);
        acc[nt] = __builtin_amdgcn_mfma_f32_16x16x32_bf16(ah, blo, acc[nt], 0, 0, 0);
      }
    }
    __syncthreads();
  }
#pragma unroll
  for (int nt = 0; nt < NT; ++nt) {
#pragma unroll
    for (int reg = 0; reg < 4; ++reg) {
      int row = bm + wave * 16 + quad * 4 + reg;
      int col = bn + nt * 16 + lrow;
      if (row < M) atomicAdd(&C[(size_t)row * N + col], acc[nt][reg]);
    }
  }
}

// ---------------- weight transpose+split: all 4 relations -> [L][4096][128] ----------------
__global__ void conv_wT2(const float* __restrict__ Wl, const float* __restrict__ Wr,
                         const float* __restrict__ bl, const float* __restrict__ br,
                         ushort* __restrict__ WTh, ushort* __restrict__ WTl,
                         float* __restrict__ bout, int total) {
  int i = blockIdx.x * 256 + threadIdx.x;
  if (i >= total) return;
  int l = i / (4096 * 128), rem = i % (4096 * 128);
  int n = rem >> 7, k = rem & 127;
  int r = n >> 10;                       // relation within layer
  int nsub = n & 1023;                   // 0..1023 within [Wl|Wr]
  int nn = nsub & 511;
  int g = l * NR + r;
  const float* W = (nsub < 512) ? Wl : Wr;
  float v = W[(size_t)g * 65536 + (size_t)k * 512 + nn];
  ushort hi = f2bf(v);
  WTh[i] = hi;
  WTl[i] = f2bf(v - bf2f(hi));
  if (k == 0) bout[l * 4096 + n] = ((nsub < 512) ? bl : br)[g * 512 + nn];
}

// ---------------- build expanded KAN weight, transposed + split ----------------
__global__ void build_kan_wT(const float* __restrict__ base_w, const float* __restrict__ spline_w,
                             const float* __restrict__ scaler,
                             ushort* __restrict__ BTh, ushort* __restrict__ BTl,
                             int In, int Out) {
  int i = blockIdx.x * 256 + threadIdx.x;
  if (i >= In * 9 * Out) return;
  int o = i / (In * 9), k = i % (In * 9);
  float v;
  if (k < In) v = base_w[(size_t)o * In + k];
  else {
    int q = k - In, ii = q >> 3, gq = q & 7;
    v = spline_w[((size_t)o * In + ii) * 8 + gq] * scaler[(size_t)o * In + ii];
  }
  ushort hi = f2bf(v);
  BTh[i] = hi;
  BTl[i] = f2bf(v - bf2f(hi));
}

// ---------------- input projection (fp32 h + hi/lo bf16) ----------------
__global__ __launch_bounds__(128) void input_proj(
    const float* __restrict__ x, const float* __restrict__ id_emb,
    const int* __restrict__ id_token, const float* __restrict__ inW,
    const float* __restrict__ inb, float* __restrict__ h,
    ushort* __restrict__ hh, ushort* __restrict__ hl) {
  int n = blockIdx.x, j = threadIdx.x;
  __shared__ float s[FNODE + IDDIM];
  if (j < FNODE) s[j] = x[(size_t)n * FNODE + j];
  else if (j < FNODE + IDDIM) s[j] = id_emb[(size_t)id_token[n] * IDDIM + (j - FNODE)];
  __syncthreads();
  float acc = inb[j];
#pragma unroll
  for (int k = 0; k < FNODE + IDDIM; ++k) acc = fmaf(s[k], inW[k * HID + j], acc);
  float v = silu_f(acc);
  h[(size_t)n * HID + j] = v;
  ushort hi = f2bf(v);
  hh[(size_t)n * HID + j] = hi;
  hl[(size_t)n * HID + j] = f2bf(v - bf2f(hi));
}

// ---------------- per-layer prep ----------------
__global__ __launch_bounds__(512) void layer_prep(
    const float* __restrict__ rel_gate, const float* __restrict__ gat_bias,
    const float* __restrict__ rel_emb, const float* __restrict__ We, int l,
    float* __restrict__ gates, float* __restrict__ msg_bias, float* __restrict__ erel) {
  int j = threadIdx.x;
  float g[NR]; float mx = -1e30f;
  for (int r = 0; r < NR; ++r) { g[r] = rel_gate[l * NR + r]; mx = fmaxf(mx, g[r]); }
  float s = 0.f;
  for (int r = 0; r < NR; ++r) { g[r] = expf(g[r] - mx); s += g[r]; }
  for (int r = 0; r < NR; ++r) g[r] /= s;
  if (j < NR) gates[j] = g[j];
  if (j < HID) {
    float b = 0.f;
    for (int r = 0; r < NR; ++r) b = fmaf(g[r], gat_bias[((size_t)(l * NR + r)) * HID + j], b);
    msg_bias[j] = b;
  }
  for (int r = 0; r < NR; ++r) {
    const float* Wer = We + ((size_t)(l * NR + r)) * 24 * 512;
    const float* re  = rel_emb + (l * NR + r) * RELDIM;
    float acc = 0.f;
#pragma unroll
    for (int q = 0; q < RELDIM; ++q) acc = fmaf(re[q], Wer[(FEDGE + q) * 512 + j], acc);
    erel[r * 512 + j] = acc;
  }
}

// ---------------- fills ----------------
__global__ void fill_zero(float* __restrict__ p, int n) {
  int i = blockIdx.x * 256 + threadIdx.x;
  if (i < n) p[i] = 0.f;
}
__global__ void fill_zero_i(int* __restrict__ p, int n) {
  int i = blockIdx.x * 256 + threadIdx.x;
  if (i < n) p[i] = 0;
}

// ---------------- relation-sorted CSR build: bins (target, relation) ----------------
__global__ void csr_count2(const int* __restrict__ eidx, const int* __restrict__ etype,
                           int* __restrict__ deg2) {
  int e = blockIdx.x * 256 + threadIdx.x;
  if (e < NE) atomicAdd(&deg2[eidx[NE + e] * NR + etype[e]], 1);
}

// ---- parallel 3-pass scan over deg2[SCTOT] ----
__global__ __launch_bounds__(256) void scan_p1(const int* __restrict__ deg2,
                                               int* __restrict__ tmp_incl, int* __restrict__ bsum) {
  __shared__ int ps[256];
  int t = threadIdx.x, blk = blockIdx.x;
  int i = blk * 256 + t;
  int v = (i < SCTOT) ? deg2[i] : 0;
  ps[t] = v;
  __syncthreads();
  for (int o = 1; o < 256; o <<= 1) {
    int u = (t >= o) ? ps[t - o] : 0;
    __syncthreads();
    ps[t] += u;
    __syncthreads();
  }
  if (i < SCTOT) tmp_incl[i] = ps[t];
  if (t == 255) bsum[blk] = ps[255];
}
__global__ __launch_bounds__(256) void scan_p2(const int* __restrict__ bsum, int* __restrict__ boff) {
  __shared__ int ps[256];
  int t = threadIdx.x;
  int v = (t < SCBLK) ? bsum[t] : 0;
  ps[t] = v;
  __syncthreads();
  for (int o = 1; o < 256; o <<= 1) {
    int u = (t >= o) ? ps[t - o] : 0;
    __syncthreads();
    ps[t] += u;
    __syncthreads();
  }
  if (t < SCBLK) boff[t] = ps[t] - v;   // exclusive
}
__global__ __launch_bounds__(256) void scan_p3(const int* __restrict__ deg2,
                                               const int* __restrict__ tmp_incl,
                                               const int* __restrict__ boff,
                                               int* __restrict__ in_off2, int* __restrict__ cursor2) {
  int t = threadIdx.x, blk = blockIdx.x;
  int i = blk * 256 + t;
  if (i < SCTOT) {
    int excl = boff[blk] + tmp_incl[i] - deg2[i];
    in_off2[i] = excl;
    cursor2[i] = excl;
  }
  if (i == 0) in_off2[SCTOT] = NE;
}

__global__ void csr_scatter2(const int* __restrict__ eidx, const int* __restrict__ etype,
                             int* __restrict__ cursor2,
                             int* __restrict__ in_e2, int* __restrict__ in_s2) {
  int e = blockIdx.x * 256 + threadIdx.x;
  if (e < NE) {
    int pos = atomicAdd(&cursor2[eidx[NE + e] * NR + etype[e]], 1);
    in_e2[pos] = e;
    in_s2[pos] = eidx[e];
  }
}

// ---------------- node-centric GAT, fp16 xlr, 16 nodes/block via node-loop ----------------
// Grid ((NN+15)/16, NR). We staged once per block, then 4 node-iterations of 4 nodes/wave.
// xlr fp16 [NN][4096]: rel rs: xl at [rs*1024,+512), xr at [rs*1024+512,+512).
// Lane owns cols [lane*4,+4) and [256+lane*4,+4). hmsg += gates[rs]*0.25*agg (atomic).
__global__ __launch_bounds__(256) void gat_node8(
    const int* __restrict__ in_off2, const int* __restrict__ in_e2, const int* __restrict__ in_s2,
    const float* __restrict__ eattr, const __half* __restrict__ xlr,
    const float* __restrict__ We_base, const float* __restrict__ erel_base,
    const float* __restrict__ att_base, const float* __restrict__ gates,
    float* __restrict__ hmsg) {
  __shared__ __align__(16) float WeL[16 * 512];
  __shared__ __align__(16) float sAgg[4][512];
  int tid = threadIdx.x;
  int rs = blockIdx.y;
  const float* We_r = We_base + (size_t)rs * 24 * 512;
  for (int i = tid; i < 16 * 512 / 4; i += 256)
    *(float4*)&WeL[i * 4] = *(const float4*)&We_r[i * 4];
  __syncthreads();
  float gr = gates[rs] * 0.25f;
  int lane = tid & 63, wave = tid >> 6;
  int roff = rs * 1024;
  const int cA = lane * 4;         // head hA = lane>>5
  const int cB = 256 + lane * 4;   // head 2 + hA
  float4 attA = *(const float4*)(att_base + rs * 512 + cA);
  float4 attB = *(const float4*)(att_base + rs * 512 + cB);
  float4 erA  = *(const float4*)(erel_base + rs * 512 + cA);
  float4 erB  = *(const float4*)(erel_base + rs * 512 + cB);
  for (int ii = 0; ii < 4; ++ii) {
    int n = blockIdx.x * 16 + ii * 4 + wave;
    if (n >= NN) continue;
    const __half* xrb = xlr + (size_t)n * 4096 + roff + 512;
    float4 xrA = ld_h4(xrb + cA);
    float4 xrB = ld_h4(xrb + cB);
    float mA = -1e30f, mB = -1e30f, lsA = 0.f, lsB = 0.f;
    float4 accA = make_float4(0.f, 0.f, 0.f, 0.f);
    float4 accB = make_float4(0.f, 0.f, 0.f, 0.f);
    int e0 = in_off2[n * NR + rs];
    int cnt = in_off2[n * NR + rs + 1] - e0;
    float4 pxA, pxB, pe0, pe1, pe2, pe3;
    int eN = 0, sN = 0;
    if (cnt > 0) {
      int eC = in_e2[e0], sC = in_s2[e0];
      if (cnt > 1) { eN = in_e2[e0 + 1]; sN = in_s2[e0 + 1]; }
      const __half* xls = xlr + (size_t)sC * 4096 + roff;
      pxA = ld_h4(xls + cA);
      pxB = ld_h4(xls + cB);
      const float4* eap = (const float4*)(eattr + (size_t)eC * 16);
      pe0 = eap[0]; pe1 = eap[1]; pe2 = eap[2]; pe3 = eap[3];
    }
    for (int j = 0; j < cnt; ++j) {
      float4 xA = pxA, xB = pxB;
      float ea[16] = {pe0.x, pe0.y, pe0.z, pe0.w, pe1.x, pe1.y, pe1.z, pe1.w,
                      pe2.x, pe2.y, pe2.z, pe2.w, pe3.x, pe3.y, pe3.z, pe3.w};
      if (j + 1 < cnt) {
        int eC = eN, sC = sN;
        if (j + 2 < cnt) { eN = in_e2[e0 + j + 2]; sN = in_s2[e0 + j + 2]; }
        const __half* xls = xlr + (size_t)sC * 4096 + roff;
        pxA = ld_h4(xls + cA);
        pxB = ld_h4(xls + cB);
        const float4* eap = (const float4*)(eattr + (size_t)eC * 16);
        pe0 = eap[0]; pe1 = eap[1]; pe2 = eap[2]; pe3 = eap[3];
      }
      float4 etA = erA, etB = erB;
#pragma unroll
      for (int k = 0; k < 16; ++k) {
        float4 wA = *(const float4*)&WeL[k * 512 + cA];
        float4 wB = *(const float4*)&WeL[k * 512 + cB];
        etA.x = fmaf(ea[k], wA.x, etA.x); etA.y = fmaf(ea[k], wA.y, etA.y);
        etA.z = fmaf(ea[k], wA.z, etA.z); etA.w = fmaf(ea[k], wA.w, etA.w);
        etB.x = fmaf(ea[k], wB.x, etB.x); etB.y = fmaf(ea[k], wB.y, etB.y);
        etB.z = fmaf(ea[k], wB.z, etB.z); etB.w = fmaf(ea[k], wB.w, etB.w);
      }
      float sA, sB;
      {
        float z0 = xA.x + xrA.x + etA.x; z0 = (z0 > 0.f) ? z0 : 0.2f * z0;
        float z1 = xA.y + xrA.y + etA.y; z1 = (z1 > 0.f) ? z1 : 0.2f * z1;
        float z2 = xA.z + xrA.z + etA.z; z2 = (z2 > 0.f) ? z2 : 0.2f * z2;
        float z3 = xA.w + xrA.w + etA.w; z3 = (z3 > 0.f) ? z3 : 0.2f * z3;
        sA = z0 * attA.x + z1 * attA.y + z2 * attA.z + z3 * attA.w;
        z0 = xB.x + xrB.x + etB.x; z0 = (z0 > 0.f) ? z0 : 0.2f * z0;
        z1 = xB.y + xrB.y + etB.y; z1 = (z1 > 0.f) ? z1 : 0.2f * z1;
        z2 = xB.z + xrB.z + etB.z; z2 = (z2 > 0.f) ? z2 : 0.2f * z2;
        z3 = xB.w + xrB.w + etB.w; z3 = (z3 > 0.f) ? z3 : 0.2f * z3;
        sB = z0 * attB.x + z1 * attB.y + z2 * attB.z + z3 * attB.w;
      }
#pragma unroll
      for (int o = 1; o <= 16; o <<= 1) {
        sA += __shfl_xor(sA, o, 64);
        sB += __shfl_xor(sB, o, 64);
      }
      {
        float mn = fmaxf(mA, sA);
        float sc = expf(mA - mn), we = expf(sA - mn);
        mA = mn; lsA = lsA * sc + we;
        accA.x = accA.x * sc + we * xA.x; accA.y = accA.y * sc + we * xA.y;
        accA.z = accA.z * sc + we * xA.z; accA.w = accA.w * sc + we * xA.w;
      }
      {
        float mn = fmaxf(mB, sB);
        float sc = expf(mB - mn), we = expf(sB - mn);
        mB = mn; lsB = lsB * sc + we;
        accB.x = accB.x * sc + we * xB.x; accB.y = accB.y * sc + we * xB.y;
        accB.z = accB.z * sc + we * xB.z; accB.w = accB.w * sc + we * xB.w;
      }
    }
    float invA = 1.f / fmaxf(lsA, 1e-16f);
    float invB = 1.f / fmaxf(lsB, 1e-16f);
    *(float4*)&sAgg[wave][cA] = make_float4(accA.x * invA, accA.y * invA, accA.z * invA, accA.w * invA);
    *(float4*)&sAgg[wave][cB] = make_float4(accB.x * invB, accB.y * invB, accB.z * invB, accB.w * invB);
    // wave-local LDS transpose for head-mean (same-wave ordering via lgkmcnt)
    float o0 = sAgg[wave][lane]       + sAgg[wave][128 + lane]
             + sAgg[wave][256 + lane] + sAgg[wave][384 + lane];
    float o1 = sAgg[wave][64 + lane]  + sAgg[wave][192 + lane]
             + sAgg[wave][320 + lane] + sAgg[wave][448 + lane];
    size_t base = (size_t)n * HID;
    atomicAdd(&hmsg[base + lane],      gr * o0);
    atomicAdd(&hmsg[base + 64 + lane], gr * o1);
  }
}

// ---------------- LayerNorm over 128 dims (optionally emits hi/lo bf16) ----------------
__global__ __launch_bounds__(64) void ln128(
    float* __restrict__ h, const float* __restrict__ add, const float* __restrict__ bvec,
    const float* __restrict__ g, const float* __restrict__ b,
    ushort* __restrict__ hh, ushort* __restrict__ hl) {
  int n = blockIdx.x, lane = threadIdx.x;
  size_t base = (size_t)n * HID;
  float x0 = h[base + lane] + add[base + lane];
  float x1 = h[base + 64 + lane] + add[base + 64 + lane];
  if (bvec) { x0 += bvec[lane]; x1 += bvec[64 + lane]; }
  float s = x0 + x1;
#pragma unroll
  for (int m = 32; m > 0; m >>= 1) s += __shfl_xor(s, m, 64);
  float mu = s * (1.f / 128.f);
  float d0 = x0 - mu, d1 = x1 - mu;
  float q = d0 * d0 + d1 * d1;
#pragma unroll
  for (int m = 32; m > 0; m >>= 1) q += __shfl_xor(q, m, 64);
  float inv = 1.f / sqrtf(q * (1.f / 128.f) + 1e-5f);
  float o0 = d0 * inv * g[lane] + b[lane];
  float o1 = d1 * inv * g[64 + lane] + b[64 + lane];
  h[base + lane]      = o0;
  h[base + 64 + lane] = o1;
  if (hh) {
    ushort i0 = f2bf(o0), i1 = f2bf(o1);
    hh[base + lane] = i0;        hh[base + 64 + lane] = i1;
    hl[base + lane] = f2bf(o0 - bf2f(i0));
    hl[base + 64 + lane] = f2bf(o1 - bf2f(i1));
  }
}

// ---------------- KAN expansion (fp32) — tiny readout head only ----------------
__global__ void expand_f32(const float* __restrict__ v, float* __restrict__ u, int In, int rows) {
  int i = blockIdx.x * 256 + threadIdx.x;
  if (i >= rows * In) return;
  int n = i / In, c = i % In;
  float x = v[(size_t)n * In + c];
  size_t base = (size_t)n * In * 9;
  u[base + c] = silu_f(x);
  float b8[8];
  kan_bases(x, b8);
  float* ub = u + base + In + (size_t)c * 8;
#pragma unroll
  for (int gq = 0; gq < 8; ++gq) ub[gq] = b8[gq];
}

// ---------------- atomic-free pooling, stage 1: per-chunk partials ----------------
__global__ __launch_bounds__(128) void pool_part(
    const float* __restrict__ h, const int* __restrict__ batch,
    float* __restrict__ psum, float* __restrict__ pmax, float* __restrict__ pcnt) {
  __shared__ float sS[NG][HID];
  __shared__ float sM[NG][HID];
  __shared__ int sC[NG];
  int d = threadIdx.x, blk = blockIdx.x;
  const float NEGINF = __uint_as_float(0xff800000u);  // -inf
  for (int i = d; i < NG * HID; i += 128) {
    ((float*)sS)[i] = 0.f;
    ((float*)sM)[i] = NEGINF;
  }
  if (d < NG) sC[d] = 0;
  __syncthreads();
  const int CH = (NN + NCHUNK - 1) / NCHUNK;  // 79
  int n0 = blk * CH, n1 = (n0 + CH < NN) ? n0 + CH : NN;
  for (int n = n0; n < n1; ++n) {
    int g = batch[n];
    float v = h[(size_t)n * HID + d];
    sS[g][d] += v;
    sM[g][d] = fmaxf(sM[g][d], v);
    if (d == 0) sC[g]++;
  }
  __syncthreads();
  for (int i = d; i < NG * HID; i += 128) {
    psum[(size_t)blk * NG * HID + i] = ((float*)sS)[i];
    pmax[(size_t)blk * NG * HID + i] = ((float*)sM)[i];
  }
  if (d < NG) pcnt[blk * NG + d] = (float)sC[d];
}

// ---------------- pooling stage 2 + readout LN ----------------
__global__ __launch_bounds__(256) void pool_final2(
    const float* __restrict__ psum, const float* __restrict__ pmax,
    const float* __restrict__ pcnt, const float* __restrict__ rog,
    const float* __restrict__ rob, float* __restrict__ gvec) {
  int g = blockIdx.x, j = threadIdx.x;
  __shared__ float rb[256];
  float x;
  if (j < HID) {
    float s = 0.f, cn = 0.f;
    for (int c = 0; c < NCHUNK; ++c) {
      s += psum[(size_t)c * NG * HID + g * HID + j];
      cn += pcnt[c * NG + g];
    }
    x = s / fmaxf(cn, 1.f);
  } else {
    float mx = __uint_as_float(0xff800000u);
    for (int c = 0; c < NCHUNK; ++c)
      mx = fmaxf(mx, pmax[(size_t)c * NG * HID + g * HID + (j - HID)]);
    x = (mx > -1e38f) ? mx : 0.f;  // where(isfinite, ., 0)
  }
  rb[j] = x; __syncthreads();
  for (int st = 128; st > 0; st >>= 1) { if (j < st) rb[j] += rb[j + st]; __syncthreads(); }
  float mu = rb[0] * (1.f / 256.f); __syncthreads();
  float d = x - mu;
  rb[j] = d * d; __syncthreads();
  for (int st = 128; st > 0; st >>= 1) { if (j < st) rb[j] += rb[j + st]; __syncthreads(); }
  float var = rb[0] * (1.f / 256.f);
  float inv = 1.f / sqrtf(var + 1e-5f);
  gvec[(size_t)g * 256 + j] = d * inv * rog[j] + rob[j];
}

// ---------------- wave-parallel KAN head: one wave per (graph, output) ----------------
__global__ __launch_bounds__(256) void kan_head_w(
    const float* __restrict__ u, const float* __restrict__ base_w,
    const float* __restrict__ spline_w, const float* __restrict__ scaler,
    float* __restrict__ out, int In, int Out, int npairs) {
  int wid = blockIdx.x * 4 + (threadIdx.x >> 6);
  if (wid >= npairs) return;
  int g = wid / Out, o = wid % Out;
  int lane = threadIdx.x & 63;
  const float* ug = u + (size_t)g * In * 9;
  const float* bw = base_w + (size_t)o * In;
  const float* sp = spline_w + (size_t)o * In * 8;
  const float* sc = scaler + (size_t)o * In;
  float acc = 0.f;
  for (int i = lane; i < In; i += 64) acc = fmaf(ug[i], bw[i], acc);
  const float* us = ug + In;
  for (int k = lane; k < In * 8; k += 64) {
    int i = k >> 3;
    acc = fmaf(us[k], sp[k] * sc[i], acc);
  }
#pragma unroll
  for (int off2 = 32; off2 > 0; off2 >>= 1) acc += __shfl_xor(acc, off2, 64);
  if (lane == 0) out[(size_t)g * Out + o] = acc;
}

// ---------------- launch ----------------
extern "C" void kernel_launch(void* const* d_in, const int* in_sizes, int n_in,
                              void* d_out, int out_size, void* d_ws, size_t ws_size,
                              hipStream_t stream) {
  const float* x         = (const float*)d_in[0];
  const float* edge_attr = (const float*)d_in[1];
  const int*   id_token  = (const int*)  d_in[2];
  const int*   edge_index= (const int*)  d_in[3];
  const int*   edge_type = (const int*)  d_in[4];
  const int*   batch     = (const int*)  d_in[5];
  const float* id_emb    = (const float*)d_in[6];
  const float* inW       = (const float*)d_in[7];
  const float* inb       = (const float*)d_in[8];
  const float* Wl        = (const float*)d_in[9];
  const float* bl        = (const float*)d_in[10];
  const float* Wr        = (const float*)d_in[11];
  const float* br        = (const float*)d_in[12];
  const float* We        = (const float*)d_in[13];
  const float* att       = (const float*)d_in[14];
  const float* gat_bias  = (const float*)d_in[15];
  const float* rel_gate  = (const float*)d_in[16];
  const float* rel_emb   = (const float*)d_in[17];
  const float* ln1g      = (const float*)d_in[18];
  const float* ln1b      = (const float*)d_in[19];
  const float* ln2g      = (const float*)d_in[20];
  const float* ln2b      = (const float*)d_in[21];
  const float* ffn1_base = (const float*)d_in[22];
  const float* ffn1_spl  = (const float*)d_in[23];
  const float* ffn1_sc   = (const float*)d_in[24];
  const float* ffn2_base = (const float*)d_in[25];
  const float* ffn2_spl  = (const float*)d_in[26];
  const float* ffn2_sc   = (const float*)d_in[27];
  const float* rog       = (const float*)d_in[28];
  const float* rob       = (const float*)d_in[29];
  const float* h1_base   = (const float*)d_in[30];
  const float* h1_spl    = (const float*)d_in[31];
  const float* h1_sc     = (const float*)d_in[32];
  const float* h2_base   = (const float*)d_in[33];
  const float* h2_spl    = (const float*)d_in[34];
  const float* h2_sc     = (const float*)d_in[35];
  (void)in_sizes; (void)n_in; (void)out_size; (void)ws_size;

  // ---- workspace carve (256B aligned) ----
  char* wsp = (char*)d_ws;
  size_t off = 0;
  auto carve = [&](size_t bytes) { char* p = wsp + off; off = (off + bytes + 255) & ~(size_t)255; return p; };
  float*    h     = (float*)   carve((size_t)NN * HID * 4);
  ushort*   h_hi  = (ushort*)  carve((size_t)NN * HID * 2);
  ushort*   h_lo  = (ushort*)  carve((size_t)NN * HID * 2);
  float*    hmsg  = (float*)   carve((size_t)NN * HID * 4);
  float*    t1    = (float*)   carve((size_t)NN * FFNH * 4);
  float*    gates = (float*)   carve(NR * 4);
  float*    msgb  = (float*)   carve(HID * 4);
  float*    erel  = (float*)   carve(NR * 512 * 4);
  ushort*   WTh   = (ushort*)  carve((size_t)NL * 4096 * HID * 2);
  ushort*   WTl   = (ushort*)  carve((size_t)NL * 4096 * HID * 2);
  float*    blr   = (float*)   carve((size_t)NL * 4096 * 4);
  ushort*   B1h   = (ushort*)  carve((size_t)FFNH * HID * 9 * 2);
  ushort*   B1l   = (ushort*)  carve((size_t)FFNH * HID * 9 * 2);
  ushort*   B2h   = (ushort*)  carve((size_t)HID * FFNH * 9 * 2);
  ushort*   B2l   = (ushort*)  carve((size_t)HID * FFNH * 9 * 2);
  float*    psum  = (float*)   carve((size_t)NCHUNK * NG * HID * 4);
  float*    pmax  = (float*)   carve((size_t)NCHUNK * NG * HID * 4);
  float*    pcnt  = (float*)   carve((size_t)NCHUNK * NG * 4);
  float*    gvec  = (float*)   carve((size_t)NG * 256 * 4);
  float*    uhead = (float*)   carve((size_t)NG * 256 * 9 * 4);
  float*    thead = (float*)   carve((size_t)NG * HEADH * 4);
  __half*   xlr   = (__half*)  carve((size_t)NN * 4096 * 2);        // 82 MB fp16
  int*      deg2  = (int*)     carve((size_t)SCTOT * 4);
  int*      in_off2=(int*)     carve((size_t)(SCTOT + 1) * 4);
  int*      cursor2=(int*)     carve((size_t)SCTOT * 4);
  int*      tmp_incl=(int*)    carve((size_t)SCTOT * 4);
  int*      bsum  = (int*)     carve((size_t)SCBLK * 4);
  int*      boff  = (int*)     carve((size_t)SCBLK * 4);
  int*      in_e2 = (int*)     carve((size_t)NE * 4);
  int*      in_s2 = (int*)     carve((size_t)NE * 4);

  // ---- relation-sorted CSR build (once; graph static across layers) ----
  fill_zero_i<<<(SCTOT + 255) / 256, 256, 0, stream>>>(deg2, SCTOT);
  csr_count2<<<(NE + 255) / 256, 256, 0, stream>>>(edge_index, edge_type, deg2);
  scan_p1<<<SCBLK, 256, 0, stream>>>(deg2, tmp_incl, bsum);
  scan_p2<<<1, 256, 0, stream>>>(bsum, boff);
  scan_p3<<<SCBLK, 256, 0, stream>>>(deg2, tmp_incl, boff, in_off2, cursor2);
  csr_scatter2<<<(NE + 255) / 256, 256, 0, stream>>>(edge_index, edge_type, cursor2, in_e2, in_s2);

  // ---- weight transpose + split (once per launch) ----
  {
    int total = NL * 4096 * 128;
    conv_wT2<<<(total + 255) / 256, 256, 0, stream>>>(Wl, Wr, bl, br, WTh, WTl, blr, total);
  }

  // ---- input projection ----
  input_proj<<<NN, 128, 0, stream>>>(x, id_emb, id_token, inW, inb, h, h_hi, h_lo);

  const int MB128 = (NN + 127) / 128;  // 79
  const int MB64  = (NN + 63) / 64;    // 157
  for (int l = 0; l < NL; ++l) {
    layer_prep<<<1, 512, 0, stream>>>(rel_gate, gat_bias, rel_emb, We, l, gates, msgb, erel);
    fill_zero<<<(NN * HID + 255) / 256, 256, 0, stream>>>(hmsg, NN * HID);
    // one projection GEMM for all 4 relations (N = 4096), fp16 output
    gemm_bf3<<<dim3(4096 / 64, MB128), 256, 0, stream>>>(
        h_hi, h_lo, WTh + (size_t)l * 4096 * HID, WTl + (size_t)l * 4096 * HID,
        blr + (size_t)l * 4096, xlr, NN, HID, 4096);
    // one gat dispatch, 16 nodes/block (We staging amortized 4x)
    gat_node8<<<dim3((NN + 15) / 16, 4), 256, 0, stream>>>(
        in_off2, in_e2, in_s2, edge_attr, xlr,
        We + ((size_t)(l * NR)) * 24 * 512, erel, att + (size_t)(l * NR) * 512,
        gates, hmsg);
    ln128<<<NN, 64, 0, stream>>>(h, hmsg, msgb, ln1g + l * HID, ln1b + l * HID, nullptr, nullptr);

    // ---- KAN FFN1: 128 -> 256 (K = 1152), fused expansion, BN=128, split-K 3 ----
    build_kan_wT<<<((HID * 9 * FFNH) + 255) / 256, 256, 0, stream>>>(
        ffn1_base + (size_t)l * FFNH * HID, ffn1_spl + (size_t)l * FFNH * HID * 8,
        ffn1_sc + (size_t)l * FFNH * HID, B1h, B1l, HID, FFNH);
    fill_zero<<<(NN * FFNH + 255) / 256, 256, 0, stream>>>(t1, NN * FFNH);
    gemm_kan<8, 3><<<dim3(FFNH / 128, MB64, 3), 256, 0, stream>>>(h, B1h, B1l, t1, NN, HID, FFNH);
    // ---- KAN FFN2: 256 -> 128 (K = 2304), fused expansion, BN=128, split-K 4 ----
    build_kan_wT<<<((FFNH * 9 * HID) + 255) / 256, 256, 0, stream>>>(
        ffn2_base + (size_t)l * HID * FFNH, ffn2_spl + (size_t)l * HID * FFNH * 8,
        ffn2_sc + (size_t)l * HID * FFNH, B2h, B2l, FFNH, HID);
    fill_zero<<<(NN * HID + 255) / 256, 256, 0, stream>>>(hmsg, NN * HID);
    gemm_kan<8, 4><<<dim3(HID / 128, MB64, 4), 256, 0, stream>>>(t1, B2h, B2l, hmsg, NN, FFNH, HID);
    ln128<<<NN, 64, 0, stream>>>(h, hmsg, nullptr, ln2g + l * HID, ln2b + l * HID, h_hi, h_lo);
  }

  // ---- readout (atomic-free pooling) ----
  pool_part<<<NCHUNK, 128, 0, stream>>>(h, batch, psum, pmax, pcnt);
  pool_final2<<<NG, 256, 0, stream>>>(psum, pmax, pcnt, rog, rob, gvec);
  expand_f32<<<((NG * 256) + 255) / 256, 256, 0, stream>>>(gvec, uhead, 256, NG);
  {
    int npairs = NG * HEADH;  // 4096 waves
    kan_head_w<<<(npairs + 3) / 4, 256, 0, stream>>>(uhead, h1_base, h1_spl, h1_sc, thead, 256, HEADH, npairs);
  }
  expand_f32<<<((NG * HEADH) + 255) / 256, 256, 0, stream>>>(thead, uhead, HEADH, NG);
  {
    int npairs = NG * NCLS;   // 320 waves
    kan_head_w<<<(npairs + 3) / 4, 256, 0, stream>>>(uhead, h2_base, h2_spl, h2_sc, (float*)d_out, HEADH, NCLS, npairs);
  }
}